// Round 6
// baseline (876.701 us; speedup 1.0000x reference)
//
#include <hip/hip_runtime.h>
#include <math.h>

#define TOK 16384
#define DIMC 512
#define FFI 1365
#define CH1 683
#define YSLD 1376         // YS row stride (bf16 elements, 16B aligned)
#define KVPAD 1056        // padded key count for spatial attn (mult of 8)
#define BSTRIDE 1152      // BIASX row stride (cols: 0=null, 1..1024=keys, rest=mask)
#define MASKB (-30000.f)  // softmax mask bias (bf16-safe, no near-inf)
#define LOG2E 1.4426950408889634f

typedef unsigned int u32;
typedef unsigned short ushort_t;
typedef __attribute__((ext_vector_type(8))) short bf16x8;
typedef __attribute__((ext_vector_type(4))) float f32x4;

__device__ inline ushort_t f2b(float x) {
    u32 u = __float_as_uint(x);
    u32 r = (u + 0x7fffu + ((u >> 16) & 1u)) >> 16;
    return (ushort_t)r;
}
__device__ inline float b2f(ushort_t u) { return __uint_as_float(((u32)u) << 16); }

__device__ inline float exp2_fast(float x) {
    float r;
    asm("v_exp_f32 %0, %1" : "=v"(r) : "v"(x));
    return r;
}

// pack two f32 -> {bf16(hi)<<16 | bf16(lo)}  (RTNE, gfx950)
__device__ inline u32 cvt_pk_bf16(float lo, float hi) {
    u32 r;
    asm("v_cvt_pk_bf16_f32 %0, %1, %2" : "=v"(r) : "v"(lo), "v"(hi));
    return r;
}

__device__ inline void gload_lds16(const void* g, void* l) {
    __builtin_amdgcn_global_load_lds(
        (const __attribute__((address_space(1))) u32*)g,
        (__attribute__((address_space(3))) u32*)l, 16, 0, 0);
}

__device__ inline float gelu_exact(float x) {
    return 0.5f * x * (1.f + erff(x * 0.70710678118654752f));
}

// counted-vmcnt helpers (immediates must be literals in the asm string)
__device__ inline void waitcnt_vm4() {
    asm volatile("s_waitcnt vmcnt(4)" ::: "memory");
    __builtin_amdgcn_sched_barrier(0);
}
__device__ inline void waitcnt_vm0() {
    asm volatile("s_waitcnt vmcnt(0)" ::: "memory");
    __builtin_amdgcn_sched_barrier(0);
}

// ---------------------------------------------------------------- CPB MLP
// ROUND-15: 16 rows per block (w1 re-read traffic 1 GB -> 62 MB).
// FP order preserved: acc seeded with b1 (b1-first like original),
// k ascending; phase-3 seeded with b2, k ascending.
__global__ __launch_bounds__(256) void cpb_kernel(
    const float* __restrict__ w0, const float* __restrict__ b0,
    const float* __restrict__ w1, const float* __restrict__ b1,
    const float* __restrict__ w2, const float* __restrict__ b2,
    float* __restrict__ table, int mode, int nrows)
{
    __shared__ float t0[16][256];
    __shared__ float t1[16][256];
    int r0 = blockIdx.x * 16;
    int t = threadIdx.x;
    float w0t = w0[t], b0t = b0[t];
    float w0t2 = (mode == 0) ? w0[256 + t] : 0.f;
    #pragma unroll
    for (int rr = 0; rr < 16; ++rr) {
        int r = r0 + rr; if (r >= nrows) r = nrows - 1;
        float c0, c1;
        if (mode == 0) { c0 = (float)(r / 63 - 31); c1 = (float)(r % 63 - 31); }
        else           { c0 = (float)(r - 15);      c1 = 0.f; }
        float a = c0 * w0t + b0t;
        if (mode == 0) a += c1 * w0t2;
        t0[rr][t] = a / (1.f + __expf(-a));
    }
    __syncthreads();
    float b1t = b1[t];
    float acc[16];
    #pragma unroll
    for (int rr = 0; rr < 16; ++rr) acc[rr] = b1t;
    for (int k = 0; k < 256; ++k) {
        float w = w1[k * 256 + t];
        #pragma unroll
        for (int rr = 0; rr < 16; ++rr) acc[rr] += t0[rr][k] * w;
    }
    #pragma unroll
    for (int rr = 0; rr < 16; ++rr) {
        float s = acc[rr];
        t1[rr][t] = s / (1.f + __expf(-s));
    }
    __syncthreads();
    if (t < 128) {
        int rr = t >> 3, oo = t & 7;
        int r = r0 + rr;
        if (r < nrows) {
            float o = b2[oo];
            for (int k = 0; k < 256; ++k) o += t1[rr][k] * w2[k * 8 + oo];
            table[r * 8 + oo] = o;
        }
    }
}

// ------------------------------- materialize spatial bias bf16, padded layout
// NOTE: bias is pre-scaled by LOG2E (softmax uses exp2)
__global__ __launch_bounds__(256) void bias_sp_kernel(
    const float* __restrict__ tab, const float* __restrict__ nullbias,
    ushort_t* __restrict__ out)
{
    int pi = blockIdx.x, h = blockIdx.y;
    int phi = pi >> 5, pwi = pi & 31;
    ushort_t* row = out + ((size_t)h * 1024 + pi) * BSTRIDE;
    for (int c = threadIdx.x; c < BSTRIDE; c += 256) {
        float v;
        if (c == 0) v = nullbias[h];
        else if (c <= 1024) {
            int pj = c - 1;
            int phj = pj >> 5, pwj = pj & 31;
            int idx = (phi - phj + 31) * 63 + (pwi - pwj + 31);
            v = tab[idx * 8 + h];
        } else v = MASKB;
        row[c] = f2b(v * LOG2E);
    }
}

// -------------------------------------------- KP/VT pad+null init. grid 16
__global__ __launch_bounds__(256) void kvinit_kernel(
    const float* __restrict__ nullkv, ushort_t* __restrict__ KP, ushort_t* __restrict__ VT)
{
    int f = blockIdx.x, t = threadIdx.x;
    for (int e = t; e < 32 * 64; e += 256) {
        int rr = e >> 6, d = e & 63;
        int row = (rr == 0) ? 0 : (1024 + rr);
        KP[((size_t)f * KVPAD + row) * 64 + d] = (rr == 0) ? f2b(nullkv[d]) : (ushort_t)0;
    }
    for (int e = t; e < 64 * 32; e += 256) {
        int d = e >> 5, cc = e & 31;
        int col = (cc == 0) ? 0 : (1024 + cc);
        VT[((size_t)f * 64 + d) * KVPAD + col] = (cc == 0) ? f2b(nullkv[64 + d]) : (ushort_t)0;
    }
}

// ---------------- weight convert: W[K][ldw] (col window c0) -> Bt[N][Kp] bf16
// Writes rows n < Nwrite (zeros for n >= Ncols or k >= K) — pad rows are clean.
__global__ __launch_bounds__(256) void wcvt_kernel(
    const float* __restrict__ W, int ldw, int c0,
    ushort_t* __restrict__ Bt, int Kp, int K, int Ncols,
    const float* __restrict__ gv, int Nwrite)
{
    __shared__ float tile[32][33];
    int nb = blockIdx.x * 32, kb = blockIdx.y * 32;
    int tx = threadIdx.x & 31, ty = threadIdx.x >> 5;
    #pragma unroll
    for (int it = 0; it < 4; ++it) {
        int k = kb + ty + it * 8, n = nb + tx;
        float v = (k < K && n < Ncols) ? W[(size_t)k * ldw + c0 + n] : 0.f;
        if (gv && k < K) v *= gv[k];
        tile[ty + it * 8][tx] = v;
    }
    __syncthreads();
    #pragma unroll
    for (int it = 0; it < 4; ++it) {
        int n = nb + ty + it * 8, k = kb + tx;
        if (n < Nwrite && k < Kp) Bt[(size_t)n * Kp + k] = f2b(tile[tx][ty + it * 8]);
    }
}

// ---------------------------------------------------- (C,T) -> (T,C) transpose
__global__ __launch_bounds__(256) void transpose_in_kernel(
    const float* __restrict__ x, float* __restrict__ dst)
{
    __shared__ float tile[32][33];
    int t0b = blockIdx.x * 32, c0b = blockIdx.y * 32;
    int tx = threadIdx.x & 31, ty = threadIdx.x >> 5;
    #pragma unroll
    for (int it = 0; it < 4; ++it) {
        int c = ty + it * 8;
        tile[c][tx] = x[(size_t)(c0b + c) * TOK + t0b + tx];
    }
    __syncthreads();
    #pragma unroll
    for (int it = 0; it < 4; ++it) {
        int tr = ty + it * 8;
        dst[(size_t)(t0b + tr) * DIMC + c0b + tx] = tile[tx][tr];
    }
}

// ---------------------------------------------------------------- LayerNorm → bf16
__global__ __launch_bounds__(256) void ln_bf16_kernel(
    const float* __restrict__ in, ushort_t* __restrict__ out,
    const float* __restrict__ w, const float* __restrict__ b)
{
    __shared__ float r1[4], r2[4];
    size_t base = (size_t)blockIdx.x * DIMC;
    int t = threadIdx.x;
    float x0 = in[base + t], x1 = in[base + 256 + t];
    float s = x0 + x1, s2 = x0 * x0 + x1 * x1;
    #pragma unroll
    for (int o = 32; o > 0; o >>= 1) { s += __shfl_down(s, o, 64); s2 += __shfl_down(s2, o, 64); }
    if ((t & 63) == 0) { r1[t >> 6] = s; r2[t >> 6] = s2; }
    __syncthreads();
    float mean = (r1[0] + r1[1] + r1[2] + r1[3]) * (1.f / 512.f);
    float ex2  = (r2[0] + r2[1] + r2[2] + r2[3]) * (1.f / 512.f);
    float rstd = rsqrtf(ex2 - mean * mean + 1e-5f);
    out[base + t]       = f2b((x0 - mean) * rstd * w[t] + b[t]);
    out[base + 256 + t] = f2b((x1 - mean) * rstd * w[256 + t] + b[256 + t]);
}

// LN(proj f32) + residual in place
__global__ __launch_bounds__(256) void ln_add_kernel(
    const float* __restrict__ proj, float* __restrict__ io,
    const float* __restrict__ w, const float* __restrict__ b)
{
    __shared__ float r1[4], r2[4];
    size_t base = (size_t)blockIdx.x * DIMC;
    int t = threadIdx.x;
    float x0 = proj[base + t], x1 = proj[base + 256 + t];
    float s = x0 + x1, s2 = x0 * x0 + x1 * x1;
    #pragma unroll
    for (int o = 32; o > 0; o >>= 1) { s += __shfl_down(s, o, 64); s2 += __shfl_down(s2, o, 64); }
    if ((t & 63) == 0) { r1[t >> 6] = s; r2[t >> 6] = s2; }
    __syncthreads();
    float mean = (r1[0] + r1[1] + r1[2] + r1[3]) * (1.f / 512.f);
    float ex2  = (r2[0] + r2[1] + r2[2] + r2[3]) * (1.f / 512.f);
    float rstd = rsqrtf(ex2 - mean * mean + 1e-5f);
    io[base + t]       += (x0 - mean) * rstd * w[t] + b[t];
    io[base + 256 + t] += (x1 - mean) * rstd * w[256 + t] + b[256 + t];
}

// spatial->temporal row permute (f32)
__global__ __launch_bounds__(128) void permute0_kernel(
    const float* __restrict__ src, float* __restrict__ dst)
{
    int rd = blockIdx.x;
    int rs = (rd & 15) * 1024 + (rd >> 4);
    ((float4*)(dst + (size_t)rd * DIMC))[threadIdx.x] =
        ((const float4*)(src + (size_t)rs * DIMC))[threadIdx.x];
}

// temporal->spatial permute, dual output f32 + bf16
__global__ __launch_bounds__(128) void permute1_dual_kernel(
    const float* __restrict__ src, float* __restrict__ dst, ushort_t* __restrict__ dstb)
{
    int rd = blockIdx.x;
    int rs = (rd & 1023) * 16 + (rd >> 10);
    float4 v = ((const float4*)(src + (size_t)rs * DIMC))[threadIdx.x];
    ((float4*)(dst + (size_t)rd * DIMC))[threadIdx.x] = v;
    u32 lo = (u32)f2b(v.x) | ((u32)f2b(v.y) << 16);
    u32 hi = (u32)f2b(v.z) | ((u32)f2b(v.w) << 16);
    ((uint2*)(dstb + (size_t)rd * DIMC))[threadIdx.x] = make_uint2(lo, hi);
}

// ---------------------------------------------------------------- MFMA GEMM
// 1-D grid of nx*16*8 blocks. XCD-aware swizzle: xcd = lin&7 owns m-tiles
// [xcd*16, xcd*16+16) for ALL nx n-tiles -> per-XCD L2-resident A band.
// ROUND-15: 3-buffer 1-barrier pipeline. Per iter: vmcnt(4) [own tile-t
// landed] -> s_barrier [all waves' tile-t landed + done reading buf(t+2)%3]
// -> stage(t+2) -> compute(t). Hoisted incremental global pointers.
template<int EPI>
__global__ __launch_bounds__(256) void gemm_mfma(
    const ushort_t* __restrict__ A, int lda,
    const ushort_t* __restrict__ Bt, int Kp,
    float* __restrict__ C, ushort_t* __restrict__ Cb, int ldc,
    int M, int N, int K, float scale, int nx,
    const float* __restrict__ stats, const float* __restrict__ g,
    const float* __restrict__ resid, float* __restrict__ outT,
    ushort_t* __restrict__ KPo, ushort_t* __restrict__ VTo)
{
    __shared__ __align__(16) ushort_t As[3][4 * 128 * 8];
    __shared__ __align__(16) ushort_t Bs[3][4 * 128 * 8];
    int lin = blockIdx.x;
    int xcd = lin & 7, idx = lin >> 3;
    int m0 = (xcd * 16 + (idx & 15)) * 128;
    int n0 = (idx >> 4) * 128;
    int tid = threadIdx.x, lane = tid & 63, wid = tid >> 6;
    int wy = wid >> 1, wx = wid & 1, quad = lane >> 4, l16 = lane & 15;
    bool bfull = (n0 + 128 <= N);
    f32x4 acc[4][4];
    #pragma unroll
    for (int i = 0; i < 4; ++i)
        #pragma unroll
        for (int j = 0; j < 4; ++j) { acc[i][j][0]=0.f; acc[i][j][1]=0.f; acc[i][j][2]=0.f; acc[i][j][3]=0.f; }

    if (bfull) {
        int NT = K >> 5;
        int c0 = wid * 128 + lane, c1 = wid * 128 + 64 + lane;
        const ushort_t* gA0 = A + (size_t)(m0 + (c0 & 127)) * lda + (c0 >> 7) * 8;
        const ushort_t* gA1 = A + (size_t)(m0 + (c1 & 127)) * lda + (c1 >> 7) * 8;
        const ushort_t* gB0 = Bt + (size_t)(n0 + (c0 & 127)) * Kp + (c0 >> 7) * 8;
        const ushort_t* gB1 = Bt + (size_t)(n0 + (c1 & 127)) * Kp + (c1 >> 7) * 8;
        const int lo0 = (wid * 128) * 8, lo1 = (wid * 128 + 64) * 8;
        auto stage = [&](int buf) {
            gload_lds16(gA0, &As[buf][lo0]);
            gload_lds16(gA1, &As[buf][lo1]);
            gload_lds16(gB0, &Bs[buf][lo0]);
            gload_lds16(gB1, &Bs[buf][lo1]);
            gA0 += 32; gA1 += 32; gB0 += 32; gB1 += 32;
        };
        stage(0);
        if (NT > 1) stage(1);
        int cur = 0, nxt = 2;
        for (int t = 0; t < NT; ++t) {
            if (t + 1 < NT) waitcnt_vm4(); else waitcnt_vm0();
            __builtin_amdgcn_s_barrier();
            if (t + 2 < NT) { stage(nxt); nxt = (nxt == 2) ? 0 : nxt + 1; }
            bf16x8 af[4], bfr[4];
            #pragma unroll
            for (int i = 0; i < 4; ++i) af[i] = *(bf16x8*)&As[cur][(quad * 128 + wy * 64 + i * 16 + l16) * 8];
            #pragma unroll
            for (int j = 0; j < 4; ++j) bfr[j] = *(bf16x8*)&Bs[cur][(quad * 128 + wx * 64 + j * 16 + l16) * 8];
            #pragma unroll
            for (int i = 0; i < 4; ++i)
                #pragma unroll
                for (int j = 0; j < 4; ++j)
                    acc[i][j] = __builtin_amdgcn_mfma_f32_16x16x32_bf16(af[i], bfr[j], acc[i][j], 0, 0, 0);
            cur = (cur == 2) ? 0 : cur + 1;
        }
    } else {
        // conservative fallback (not taken by current launches)
        for (int k0 = 0; k0 < K; k0 += 32) {
            if (k0) __syncthreads();
            #pragma unroll
            for (int r = 0; r < 2; ++r) {
                int c = wid * 128 + r * 64 + lane;
                const ushort_t* src = A + (size_t)(m0 + (c & 127)) * lda + k0 + (c >> 7) * 8;
                gload_lds16(src, &As[0][(wid * 128 + r * 64) * 8]);
            }
            #pragma unroll
            for (int r = 0; r < 2; ++r) {
                int c = tid + r * 256;
                int kg = c >> 7, nloc = c & 127;
                bf16x8 v;
                if (n0 + nloc < N) v = *(const bf16x8*)(Bt + (size_t)(n0 + nloc) * Kp + k0 + kg * 8);
                else { for (int e = 0; e < 8; ++e) v[e] = 0; }
                *(bf16x8*)&Bs[0][c * 8] = v;
            }
            __syncthreads();
            bf16x8 af[4], bfr[4];
            #pragma unroll
            for (int i = 0; i < 4; ++i) af[i] = *(bf16x8*)&As[0][(quad * 128 + wy * 64 + i * 16 + l16) * 8];
            #pragma unroll
            for (int j = 0; j < 4; ++j) bfr[j] = *(bf16x8*)&Bs[0][(quad * 128 + wx * 64 + j * 16 + l16) * 8];
            #pragma unroll
            for (int i = 0; i < 4; ++i)
                #pragma unroll
                for (int j = 0; j < 4; ++j)
                    acc[i][j] = __builtin_amdgcn_mfma_f32_16x16x32_bf16(af[i], bfr[j], acc[i][j], 0, 0, 0);
        }
    }
    #pragma unroll
    for (int i = 0; i < 4; ++i) {
        #pragma unroll
        for (int j = 0; j < 4; ++j) {
            #pragma unroll
            for (int r = 0; r < 4; ++r) {
                int m = m0 + wy * 64 + i * 16 + quad * 4 + r;
                int n = n0 + wx * 64 + j * 16 + l16;
                if (n >= N) continue;
                float v = acc[i][j][r] * scale;
                if (EPI == 0) {
                    C[(size_t)m * ldc + n] = v;
                } else if (EPI == 3) {
                    Cb[(size_t)m * ldc + n] = f2b(v);
                } else if (EPI == 4) {
                    int frame = m >> 10, tt = m & 1023;
                    if (n < 64) KPo[((size_t)frame * KVPAD + 1 + tt) * 64 + n] = f2b(v);
                    else        VTo[((size_t)frame * 64 + (n - 64)) * KVPAD + 1 + tt] = f2b(v);
                } else if (EPI == 5) {
                    float s0 = stats[2 * m], s1 = stats[2 * m + 1];
                    outT[(size_t)n * TOK + m] = v * s1 - s0 * g[n] + resid[(size_t)m * DIMC + n];
                }
            }
        }
    }
}

// ------------------------------------------- fused FF front GEMM (a & gate)
// 128m x 64n dual-output tile -> acc = 64 AGPR/thread. B from interleaved
// BI[2816][512] via pure global_load_lds. Grid 2816 = 8 XCD x 16 m x 22 n.
// ROUND-15: 3-buffer 1-barrier pipeline, hoisted incremental pointers.
__global__ __launch_bounds__(256) void ff_gemm_fused(
    const ushort_t* __restrict__ A,
    const ushort_t* __restrict__ BI,
    ushort_t* __restrict__ YS)
{
    __shared__ __align__(16) ushort_t As[3][4 * 128 * 8];
    __shared__ __align__(16) ushort_t Bs[3][4 * 2 * 64 * 8];
    int lin = blockIdx.x;
    int xcd = lin & 7, idx = lin >> 3;
    int m0 = (xcd * 16 + (idx & 15)) * 128;
    int n0 = (idx >> 4) * 64;
    int tid = threadIdx.x, lane = tid & 63, wid = tid >> 6;
    int wy = wid >> 1, wx = wid & 1, quad = lane >> 4, l16 = lane & 15;
    f32x4 aA[4][2], aG[4][2];
    #pragma unroll
    for (int i = 0; i < 4; ++i)
        #pragma unroll
        for (int j = 0; j < 2; ++j) {
            aA[i][j][0]=0.f; aA[i][j][1]=0.f; aA[i][j][2]=0.f; aA[i][j][3]=0.f;
            aG[i][j][0]=0.f; aG[i][j][1]=0.f; aG[i][j][2]=0.f; aG[i][j][3]=0.f;
        }

    int c0 = wid * 128 + lane, c1 = wid * 128 + 64 + lane;
    const ushort_t* gA0 = A + (size_t)(m0 + (c0 & 127)) * 512 + (c0 >> 7) * 8;
    const ushort_t* gA1 = A + (size_t)(m0 + (c1 & 127)) * 512 + (c1 >> 7) * 8;
    const ushort_t* gB0 = BI + (size_t)((n0 + lane) * 2 + 0) * 512 + wid * 8;
    const ushort_t* gB1 = BI + (size_t)((n0 + lane) * 2 + 1) * 512 + wid * 8;
    const int lo0 = (wid * 128) * 8, lo1 = (wid * 128 + 64) * 8;
    auto stage = [&](int buf) {
        gload_lds16(gA0, &As[buf][lo0]);
        gload_lds16(gA1, &As[buf][lo1]);
        gload_lds16(gB0, &Bs[buf][lo0]);
        gload_lds16(gB1, &Bs[buf][lo1]);
        gA0 += 32; gA1 += 32; gB0 += 32; gB1 += 32;
    };

    stage(0); stage(1);
    int cur = 0, nxt = 2;
    for (int t = 0; t < 16; ++t) {
        if (t + 1 < 16) waitcnt_vm4(); else waitcnt_vm0();
        __builtin_amdgcn_s_barrier();
        if (t + 2 < 16) { stage(nxt); nxt = (nxt == 2) ? 0 : nxt + 1; }
        bf16x8 af[4], ba[2], bg[2];
        #pragma unroll
        for (int i = 0; i < 4; ++i) af[i] = *(bf16x8*)&As[cur][(quad * 128 + wy * 64 + i * 16 + l16) * 8];
        #pragma unroll
        for (int j = 0; j < 2; ++j) {
            int nn = wx * 32 + j * 16 + l16;
            ba[j] = *(bf16x8*)&Bs[cur][(quad * 128 + nn) * 8];
            bg[j] = *(bf16x8*)&Bs[cur][(quad * 128 + 64 + nn) * 8];
        }
        #pragma unroll
        for (int i = 0; i < 4; ++i)
            #pragma unroll
            for (int j = 0; j < 2; ++j) {
                aA[i][j] = __builtin_amdgcn_mfma_f32_16x16x32_bf16(af[i], ba[j], aA[i][j], 0, 0, 0);
                aG[i][j] = __builtin_amdgcn_mfma_f32_16x16x32_bf16(af[i], bg[j], aG[i][j], 0, 0, 0);
            }
        cur = (cur == 2) ? 0 : cur + 1;
    }
    #pragma unroll
    for (int i = 0; i < 4; ++i) {
        #pragma unroll
        for (int j = 0; j < 2; ++j) {
            #pragma unroll
            for (int r = 0; r < 4; ++r) {
                int m = m0 + wy * 64 + i * 16 + quad * 4 + r;
                int n = n0 + wx * 32 + j * 16 + l16;
                if (n >= FFI) {
                    if (n < YSLD) YS[(size_t)m * YSLD + n] = 0;   // zero pad cols
                    continue;
                }
                float v = aA[i][j][r] * gelu_exact(aG[i][j][r]);
                int dr = (n < CH1) ? m : m + 1024;
                if (dr < TOK) YS[(size_t)dr * YSLD + n] = f2b(v);
                if (n >= CH1 && m < 1024) YS[(size_t)m * YSLD + n] = 0;
            }
        }
    }
}

// --------------------------------------------------- spatial attention (MFMA flash)
// Grid remap: per XCD = q-tile band (8 qt) x ALL 16 frames (bias L2-resident).
// ROUND-12: softmax without online-max (logits bounded, base-2 domain, mask
// underflows to 0), row-sum via MFMA ones-column (zero-shuffle epilogue),
// P pack via v_cvt_pk_bf16_f32. In-register ds_bpermute transpose retained.
__global__ __launch_bounds__(256) void attn_sp_mfma(
    const ushort_t* __restrict__ Q,      // [16384][512] bf16 pre-scaled by 0.125*log2e
    const ushort_t* __restrict__ KP,     // [16][1056][64]
    const ushort_t* __restrict__ VT,     // [16][64][1056]
    const ushort_t* __restrict__ BIASX,  // [8][1024][1152], pre-scaled by log2e
    ushort_t* __restrict__ O)            // [16384][512] bf16
{
    __shared__ __align__(16) ushort_t Ks[128 * 64];
    __shared__ __align__(16) ushort_t Vs[64 * 128];
    int lin = blockIdx.x;
    int xcd = lin & 7, idx = lin >> 3;
    int qt = xcd * 8 + (idx & 7);
    int frame = idx >> 3;
    int q0 = qt * 16;
    int tid = threadIdx.x, lane = tid & 63, wid = tid >> 6;
    int quad = lane >> 4, l16 = lane & 15;

    bf16x8 aQ[2][2];
    const ushort_t* brow[2];
    #pragma unroll
    for (int i = 0; i < 2; ++i) {
        int h = wid * 2 + i;
        const ushort_t* qp = Q + (size_t)(frame * 1024 + q0 + l16) * 512 + h * 64 + quad * 8;
        aQ[i][0] = *(const bf16x8*)qp;
        aQ[i][1] = *(const bf16x8*)(qp + 32);
        brow[i] = BIASX + ((size_t)h * 1024 + q0 + l16) * BSTRIDE;
    }
    f32x4 Oc[2][4];
    f32x4 Oc4[2];   // row-sum accumulator (ones-column PV)
    #pragma unroll
    for (int i = 0; i < 2; ++i) {
        #pragma unroll
        for (int nt = 0; nt < 4; ++nt) { Oc[i][nt][0]=0.f; Oc[i][nt][1]=0.f; Oc[i][nt][2]=0.f; Oc[i][nt][3]=0.f; }
        Oc4[i][0]=0.f; Oc4[i][1]=0.f; Oc4[i][2]=0.f; Oc4[i][3]=0.f;
    }
    bf16x8 vones;
    #pragma unroll
    for (int e = 0; e < 8; ++e) vones[e] = (short)0x3F80;   // bf16 1.0

    // bpermute byte-indices for the in-register P transpose:
    // target (quad,l16) word w pulls from lane (2*(quad&1)+(w>>1))*16 + l16
    int idxA = (((quad & 1) * 32) + l16) * 4;   // w = 0,1
    int idxB = idxA + 64;                       // w = 2,3
    bool hiq = (quad >= 2);                     // selects j = 2ks+1

    for (int jt = 0; jt < 9; ++jt) {
        __syncthreads();
        #pragma unroll
        for (int r = 0; r < 4; ++r) {
            int L = wid * 256 + r * 64 + lane;
            int c = L >> 3, gp = L & 7, gg = gp ^ (c & 7);
            int jj = jt * 128 + c; if (jj > KVPAD - 1) jj = KVPAD - 1;
            gload_lds16(KP + ((size_t)frame * KVPAD + jj) * 64 + gg * 8, &Ks[(wid * 256 + r * 64) * 8]);
        }
        #pragma unroll
        for (int r = 0; r < 4; ++r) {
            int L = wid * 256 + r * 64 + lane;
            int d = L >> 4, cgp = L & 15;
            int cg = (cgp & 8) | ((cgp & 7) ^ (d & 7));
            int col = jt * 128 + cg * 8; if (col > KVPAD - 8) col = KVPAD - 8;
            gload_lds16(VT + ((size_t)frame * 64 + d) * KVPAD + col, &Vs[(wid * 256 + r * 64) * 8]);
        }
        __syncthreads();

        #pragma unroll
        for (int i = 0; i < 2; ++i) {
            // ---- QK^T for this head
            f32x4 S[8];
            #pragma unroll
            for (int j = 0; j < 8; ++j) { S[j][0]=0.f; S[j][1]=0.f; S[j][2]=0.f; S[j][3]=0.f; }
            __builtin_amdgcn_s_setprio(1);
            #pragma unroll
            for (int j = 0; j < 8; ++j) {
                int c = j * 16 + l16;
                #pragma unroll
                for (int ks = 0; ks < 2; ++ks) {
                    bf16x8 kb = *(bf16x8*)&Ks[(c * 8 + ((ks * 4 + quad) ^ (c & 7))) * 8];
                    S[j] = __builtin_amdgcn_mfma_f32_16x16x32_bf16(kb, aQ[i][ks], S[j], 0, 0, 0);
                }
            }
            __builtin_amdgcn_s_setprio(0);
            // ---- bias add + direct exp2 (no max tracking: base-2 logits are
            // small/bounded; MASKB*log2e underflows exp2 to exactly 0)
            #pragma unroll
            for (int j = 0; j < 8; ++j) {
                int kbase = jt * 128 + j * 16 + quad * 4;
                uint2 bv = *(const uint2*)(brow[i] + kbase);
                S[j][0] = exp2_fast(S[j][0] + __uint_as_float(bv.x << 16));
                S[j][1] = exp2_fast(S[j][1] + __uint_as_float(bv.x & 0xffff0000u));
                S[j][2] = exp2_fast(S[j][2] + __uint_as_float(bv.y << 16));
                S[j][3] = exp2_fast(S[j][3] + __uint_as_float(bv.y & 0xffff0000u));
            }
            // ---- pack (cvt_pk) + in-register transpose (ds_bpermute) + PV
            __builtin_amdgcn_s_setprio(1);
            #pragma unroll
            for (int ks = 0; ks < 4; ++ks) {
                int jl = 2 * ks, jh = 2 * ks + 1;
                u32 pxl = cvt_pk_bf16(S[jl][0], S[jl][1]);
                u32 pyl = cvt_pk_bf16(S[jl][2], S[jl][3]);
                u32 pxh = cvt_pk_bf16(S[jh][0], S[jh][1]);
                u32 pyh = cvt_pk_bf16(S[jh][2], S[jh][3]);
                u32 a0 = (u32)__builtin_amdgcn_ds_bpermute(idxA, (int)pxl);
                u32 a1 = (u32)__builtin_amdgcn_ds_bpermute(idxA, (int)pxh);
                u32 b0 = (u32)__builtin_amdgcn_ds_bpermute(idxA, (int)pyl);
                u32 b1 = (u32)__builtin_amdgcn_ds_bpermute(idxA, (int)pyh);
                u32 c0 = (u32)__builtin_amdgcn_ds_bpermute(idxB, (int)pxl);
                u32 c1 = (u32)__builtin_amdgcn_ds_bpermute(idxB, (int)pxh);
                u32 d0 = (u32)__builtin_amdgcn_ds_bpermute(idxB, (int)pyl);
                u32 d1 = (u32)__builtin_amdgcn_ds_bpermute(idxB, (int)pyh);
                union { u32 w[4]; bf16x8 v; } pa;
                pa.w[0] = hiq ? a1 : a0;
                pa.w[1] = hiq ? b1 : b0;
                pa.w[2] = hiq ? c1 : c0;
                pa.w[3] = hiq ? d1 : d0;
                #pragma unroll
                for (int nt = 0; nt < 4; ++nt) {
                    int d = nt * 16 + l16;
                    int cg = ks * 4 + quad;
                    int phys = (cg & 8) | ((cg & 7) ^ (d & 7));
                    bf16x8 vb = *(bf16x8*)&Vs[(d * 16 + phys) * 8];
                    Oc[i][nt] = __builtin_amdgcn_mfma_f32_16x16x32_bf16(pa.v, vb, Oc[i][nt], 0, 0, 0);
                }
                // ones-column: accumulates row-sum of P in matching layout
                Oc4[i] = __builtin_amdgcn_mfma_f32_16x16x32_bf16(pa.v, vones, Oc4[i], 0, 0, 0);
            }
            __builtin_amdgcn_s_setprio(0);
        }
    }
    #pragma unroll
    for (int i = 0; i < 2; ++i) {
        int h = wid * 2 + i;
        #pragma unroll
        for (int r = 0; r < 4; ++r) {
            float linv = 1.f / Oc4[i][r];   // same (q,row) layout as Oc — no shuffle
            int ql = quad * 4 + r;
            #pragma unroll
            for (int nt = 0; nt < 4; ++nt) {
                int d = nt * 16 + l16;
                O[(size_t)(frame * 1024 + q0 + ql) * 512 + h * 64 + d] = f2b(Oc[i][nt][r] * linv);
            }
        }
    }
}

// ---------------------------------------------------------------- temporal attention
// ROUND-15: vectorized q load (16B), float4 LDS reads in QK and PV phases.
// FP accumulation order preserved element-wise.
__global__ __launch_bounds__(256) void attn_tp_kernel(
    const ushort_t* __restrict__ q, const ushort_t* __restrict__ kv,
    const float* __restrict__ nullkv, const float* __restrict__ nullbias,
    const float* __restrict__ table, ushort_t* __restrict__ out)
{
    __shared__ float qs[16][512];
    __shared__ float ks[17][64];
    __shared__ float vs[17][64];
    __shared__ float sc[8][16][17];
    int b = blockIdx.x;
    int t = threadIdx.x;
    for (int e = t; e < 16 * 64; e += 256) {
        int f = e >> 6, c8 = e & 63;
        uint4 v = *(const uint4*)(q + (size_t)(b * 16 + f) * 512 + c8 * 8);
        float* dst = &qs[f][c8 * 8];
        dst[0] = b2f((ushort_t)(v.x & 0xffffu)); dst[1] = b2f((ushort_t)(v.x >> 16));
        dst[2] = b2f((ushort_t)(v.y & 0xffffu)); dst[3] = b2f((ushort_t)(v.y >> 16));
        dst[4] = b2f((ushort_t)(v.z & 0xffffu)); dst[5] = b2f((ushort_t)(v.z >> 16));
        dst[6] = b2f((ushort_t)(v.w & 0xffffu)); dst[7] = b2f((ushort_t)(v.w >> 16));
    }
    for (int e = t; e < 17 * 64; e += 256) {
        int j = e >> 6, d = e & 63;
        ks[j][d] = (j == 0) ? nullkv[d]      : b2f(kv[(size_t)(b * 16 + j - 1) * 128 + d]);
        vs[j][d] = (j == 0) ? nullkv[64 + d] : b2f(kv[(size_t)(b * 16 + j - 1) * 128 + 64 + d]);
    }
    __syncthreads();
    for (int e = t; e < 8 * 16 * 17; e += 256) {
        int h = e / 272, rem = e - h * 272;
        int i = rem / 17, j = rem - i * 17;
        float acc = 0.f;
        const float4* qp = (const float4*)&qs[i][h * 64];
        const float4* kp = (const float4*)&ks[j][0];
        #pragma unroll
        for (int d4 = 0; d4 < 16; ++d4) {
            float4 qv = qp[d4], kv4 = kp[d4];
            acc += qv.x * kv4.x;
            acc += qv.y * kv4.y;
            acc += qv.z * kv4.z;
            acc += qv.w * kv4.w;
        }
        float bias = ((j == 0) ? nullbias[h] : table[(i - (j - 1) + 15) * 8 + h]) * LOG2E;
        sc[h][i][j] = acc + bias;   // q pre-scaled by 0.125*log2e -> base-2 logits
    }
    __syncthreads();
    if (t < 128) {
        int h = t >> 4, i = t & 15;
        float mx = -1e30f;
        for (int j = 0; j < 17; ++j) mx = fmaxf(mx, sc[h][i][j]);
        float s = 0.f;
        for (int j = 0; j < 17; ++j) { float p = exp2_fast(sc[h][i][j] - mx); sc[h][i][j] = p; s += p; }
        float inv = 1.f / s;
        for (int j = 0; j < 17; ++j) sc[h][i][j] *= inv;
    }
    __syncthreads();
    for (int e = t; e < 16 * 128; e += 256) {
        int i = e >> 7, c4 = e & 127;
        int h = c4 >> 4, d4 = c4 & 15;
        float ax = 0.f, ay = 0.f, az = 0.f, aw = 0.f;
        #pragma unroll
        for (int j = 0; j < 17; ++j) {
            float p = sc[h][i][j];
            float4 vv = *(const float4*)&vs[j][d4 * 4];
            ax += p * vv.x; ay += p * vv.y; az += p * vv.z; aw += p * vv.w;
        }
        u32 lo = (u32)f2b(ax) | ((u32)f2b(ay) << 16);
        u32 hi = (u32)f2b(az) | ((u32)f2b(aw) << 16);
        *(uint2*)(out + (size_t)(b * 16 + i) * 512 + c4 * 4) = make_uint2(lo, hi);
    }
}

// ------------------------- FF shift-LN row stats from bf16 YS: (mean*rstd, rstd)
__global__ __launch_bounds__(256) void rowstats_bf16_kernel(
    const ushort_t* __restrict__ YS, float* __restrict__ stats)
{
    __shared__ float r1[4], r2[4];
    int r = blockIdx.x, t = threadIdx.x;
    const ushort_t* row = YS + (size_t)r * YSLD;
    float s = 0.f, s2 = 0.f;
    for (int c = t; c < FFI; c += 256) {
        float v = b2f(row[c]);
        s += v; s2 += v * v;
    }
    #pragma unroll
    for (int o = 32; o > 0; o >>= 1) { s += __shfl_down(s, o, 64); s2 += __shfl_down(s2, o, 64); }
    if ((t & 63) == 0) { r1[t >> 6] = s; r2[t >> 6] = s2; }
    __syncthreads();
    float S  = r1[0] + r1[1] + r1[2] + r1[3];
    float S2 = r2[0] + r2[1] + r2[2] + r2[3];
    float mean = S * (1.f / 1365.f);
    float var  = S2 * (1.f / 1365.f) - mean * mean;
    float rstd = rsqrtf(fmaxf(var, 1e-5f));
    if (t == 0) { stats[2 * r] = mean * rstd; stats[2 * r + 1] = rstd; }
}

// --------------------- colsum[n] = sum_k W'[n][k]  (rows of converted W')
__global__ __launch_bounds__(64) void colsum_kernel(
    const ushort_t* __restrict__ Wt, float* __restrict__ colsum)
{
    int n = blockIdx.x, t = threadIdx.x;
    const ushort_t* row = Wt + (size_t)n * YSLD;
    float s = 0.f;
    for (int k = t; k < YSLD; k += 64) s += b2f(row[k]);
    #pragma unroll
    for (int o = 32; o > 0; o >>= 1) s += __shfl_down(s, o, 64);
    if (t == 0) colsum[n] = s;
}

// ================================================================ launcher
extern "C" void kernel_launch(void* const* d_in, const int* in_sizes, int n_in,
                              void* d_out, int out_size, void* d_ws, size_t ws_size,
                              hipStream_t stream)
{
    const float* x          = (const float*)d_in[0];
    const float* sa_ln_w    = (const float*)d_in[1];
    const float* sa_ln_b    = (const float*)d_in[2];
    const float* sa_wq      = (const float*)d_in[3];
    const float* sa_wkv     = (const float*)d_in[4];
    const float* sa_null_kv = (const float*)d_in[5];
    const float* sa_null_b  = (const float*)d_in[6];
    const float* sa_wout    = (const float*)d_in[7];
    const float* sa_oln_w   = (const float*)d_in[8];
    const float* sa_oln_b   = (const float*)d_in[9];
    const float* ta_ln_w    = (const float*)d_in[10];
    const float* ta_ln_b    = (const float*)d_in[11];
    const float* ta_wq      = (const float*)d_in[12];
    const float* ta_wkv     = (const float*)d_in[13];
    const float* ta_null_kv = (const float*)d_in[14];
    const float* ta_null_b  = (const float*)d_in[15];
    const float* ta_wout    = (const float*)d_in[16];
    const float* ta_oln_w   = (const float*)d_in[17];
    const float* ta_oln_b   = (const float*)d_in[18];
    const float* sp_w0      = (const float*)d_in[19];
    const float* sp_b0      = (const float*)d_in[20];
    const float* sp_w1      = (const float*)d_in[21];
    const float* sp_b1      = (const float*)d_in[22];
    const float* sp_w2      = (const float*)d_in[23];
    const float* sp_b2      = (const float*)d_in[24];
    const float* tp_w0      = (const float*)d_in[25];
    const float* tp_b0      = (const float*)d_in[26];
    const float* tp_w1      = (const float*)d_in[27];
    const float* tp_b1      = (const float*)d_in[28];
    const float* tp_w2      = (const float*)d_in[29];
    const float* tp_b2      = (const float*)d_in[30];
    const float* ff_win     = (const float*)d_in[31];
    const float* ff_g       = (const float*)d_in[32];
    const float* ff_wout    = (const float*)d_in[33];

    char* ws = (char*)d_ws;
    // regions (bytes)
    float*    RES   = (float*)(ws + 0);                        // residual, spatial layout
    ushort_t* XN16  = (ushort_t*)(ws + 33554432);              // xn / x2 bf16
    ushort_t* Q16   = (ushort_t*)(ws + 50331648);              // spatial Q bf16 (spatial phase)
    float*    RT    = (float*)(ws + 50331648);                 // temporal residual f32 (temporal phase)
    ushort_t* YS    = (ushort_t*)(ws + 50331648);              // FF shifted act bf16 [16384][1376]
    ushort_t* WSA   = (ushort_t*)(ws + 67108864);              // spatial weights (dead by FF)
    ushort_t* KP    = (ushort_t*)(ws + 83886080);              // 16x1056x64 bf16 (spatial)
    ushort_t* VTb   = (ushort_t*)(ws + 86048768);              // 16x64x1056 bf16 (spatial)
    ushort_t* KV16  = (ushort_t*)(ws + 83886080);              // temporal KV bf16
    ushort_t* WTA   = (ushort_t*)(ws + 90439680);              // temporal weights
    ushort_t* AO16  = (ushort_t*)(ws + 92274688);              // attn out bf16 (dead by FF)
    ushort_t* BI    = (ushort_t*)(ws + 96468992);              // FF interleaved W [2816][512]
    ushort_t* WFFB  = (ushort_t*)(ws + 99352576);              // W' = (ff_wout*g)^T [512][1376]
    ushort_t* BIAS16= (ushort_t*)(ws + 109051904);             // spatial bias bf16 (PRJ region)
    float*    PRJ   = (float*)(ws + 109051904);                // proj out f32
    ushort_t* Q16t  = (ushort_t*)(ws + 109051904);             // temporal Q bf16
    float*    STATS = (float*)(ws + 142606336);                // 16384 x (mean*rstd, rstd)
    float*    SPT   = (float*)(ws + 142737408);                // spatial CPB table (spatial phase)
    float*    COLSUM= (float*)(ws + 142737408);                // colsum[512] (FF phase, dead SPT)
    float*    TPT   = (float*)(ws + 142864448);

    ushort_t* WQ_T  = WSA;                 // [512][512]
    ushort_t* WKV_T = WSA + 262144;        // [128][512]
    ushort_t* WO_T  = WSA + 327680;        // [512][512]
    ushort_t* tWQ_T  = WTA;
    ushort_t* tWKV_T = WTA + 262144;
    ushort_t* tWO_T  = WTA + 327680;

    dim3 blk(256);
    const float QSCL = 0.125f * LOG2E;   // fold log2e into Q so softmax is exp2

    // bias tables
    cpb_kernel<<<dim3(249), blk, 0, stream>>>(sp_w0, sp_b0, sp_w1, sp_b1, sp_w2, sp_b2, SPT, 0, 3969);
    cpb_kernel<<<dim3(2),   blk, 0, stream>>>(tp_w0, tp_b0, tp_w1, tp_b1, tp_w2, tp_b2, TPT, 1, 31);
    bias_sp_kernel<<<dim3(1024, 8), blk, 0, stream>>>(SPT, sa_null_b, BIAS16);
    kvinit_kernel<<<dim3(16), blk, 0, stream>>>(sa_null_kv, KP, VTb);

    // ---------------- spatial ----------------
    wcvt_kernel<<<dim3(16, 16), blk, 0, stream>>>(sa_wq, 512, 0, WQ_T, 512, 512, 512, nullptr, 512);
    wcvt_kernel<<<dim3(4, 16),  blk, 0, stream>>>(sa_wkv, 128, 0, WKV_T, 512, 512, 128, nullptr, 128);
    wcvt_kernel<<<dim3(16, 16), blk, 0, stream>>>(sa_wout, 512, 0, WO_T, 512, 512, 512, nullptr, 512);
    transpose_in_kernel<<<dim3(512, 16), blk, 0, stream>>>(x, RES);
    ln_bf16_kernel<<<dim3(TOK), blk, 0, stream>>>(RES, XN16, sa_ln_w, sa_ln_b);
    gemm_mfma<3><<<dim3(512), blk, 0, stream>>>(XN16, 512, WQ_T, 512,
        nullptr, Q16, 512, TOK, 512, 512, QSCL, 4, nullptr, nullptr, nullptr, nullptr, nullptr, nullptr);
    gemm_mfma<4><<<dim3(128), blk, 0, stream>>>(XN16, 512, WKV_T, 512,
        nullptr, nullptr, 0, TOK, 128, 512, 1.0f, 1, nullptr, nullptr, nullptr, nullptr, KP, VTb);
    attn_sp_mfma<<<dim3(1024), blk, 0, stream>>>(Q16, KP, VTb, BIAS16, AO16);
    gemm_mfma<0><<<dim3(512), blk, 0, stream>>>(AO16, 512, WO_T, 512,
        PRJ, nullptr, 512, TOK, 512, 512, 1.0f, 4, nullptr, nullptr, nullptr, nullptr, nullptr, nullptr);
    ln_add_kernel<<<dim3(TOK), blk, 0, stream>>>(PRJ, RES, sa_oln_w, sa_oln_b);

    // ---------------- temporal ----------------
    permute0_kernel<<<dim3(TOK), dim3(128), 0, stream>>>(RES, RT);
    wcvt_kernel<<<dim3(16, 16), blk, 0, stream>>>(ta_wq, 512, 0, tWQ_T, 512, 512, 512, nullptr, 512);
    wcvt_kernel<<<dim3(4, 16),  blk, 0, stream>>>(ta_wkv, 128, 0, tWKV_T, 512, 512, 128, nullptr, 128);
    wcvt_kernel<<<dim3(16, 16), blk, 0, stream>>>(ta_wout, 512, 0, tWO_T, 512, 512, 512, nullptr, 512);
    ln_bf16_kernel<<<dim3(TOK), blk, 0, stream>>>(RT, XN16, ta_ln_w, ta_ln_b);
    gemm_mfma<3><<<dim3(512), blk, 0, stream>>>(XN16, 512, tWQ_T, 512,
        nullptr, Q16t, 512, TOK, 512, 512, QSCL, 4, nullptr, nullptr, nullptr, nullptr, nullptr, nullptr);
    gemm_mfma<3><<<dim3(128), blk, 0, stream>>>(XN16, 512, tWKV_T, 512,
        nullptr, KV16, 128, TOK, 128, 512, 1.0f, 1, nullptr, nullptr, nullptr, nullptr, nullptr, nullptr);
    attn_tp_kernel<<<dim3(1024), blk, 0, stream>>>(Q16t, KV16, ta_null_kv, ta_null_b, TPT, AO16);
    gemm_mfma<0><<<dim3(512), blk, 0, stream>>>(AO16, 512, tWO_T, 512,
        PRJ, nullptr, 512, TOK, 512, 512, 1.0f, 4, nullptr, nullptr, nullptr, nullptr, nullptr, nullptr);
    ln_add_kernel<<<dim3(TOK), blk, 0, stream>>>(PRJ, RT, ta_oln_w, ta_oln_b);
    permute1_dual_kernel<<<dim3(TOK), dim3(128), 0, stream>>>(RT, RES, XN16);

    // ---------------- feed-forward ----------------
    wcvt_kernel<<<dim3(44, 16), blk, 0, stream>>>(ff_win, 2730, 0,   BI,       1024, 512, FFI, nullptr, 1408);
    wcvt_kernel<<<dim3(44, 16), blk, 0, stream>>>(ff_win, 2730, FFI, BI + 512, 1024, 512, FFI, nullptr, 1408);
    wcvt_kernel<<<dim3(16, 43), blk, 0, stream>>>(ff_wout, 512, 0, WFFB, YSLD, FFI, 512, ff_g, 512);
    colsum_kernel<<<dim3(512), dim3(64), 0, stream>>>(WFFB, COLSUM);
    ff_gemm_fused<<<dim3(2816), blk, 0, stream>>>(XN16, BI, YS);
    rowstats_bf16_kernel<<<dim3(TOK), blk, 0, stream>>>(YS, STATS);
    gemm_mfma<5><<<dim3(512), blk, 0, stream>>>(YS, YSLD, WFFB, YSLD,
        nullptr, nullptr, 0, TOK, 512, YSLD, 1.0f, 4, STATS, COLSUM, RES, (float*)d_out, nullptr, nullptr);
}

// Round 7
// 855.486 us; speedup vs baseline: 1.0248x; 1.0248x over previous
//
#include <hip/hip_runtime.h>
#include <math.h>

#define TOK 16384
#define DIMC 512
#define FFI 1365
#define CH1 683
#define YSLD 1376         // YS row stride (bf16 elements, 16B aligned)
#define KVPAD 1056        // padded key count for spatial attn (mult of 8)
#define BSTRIDE 1152      // BIASX row stride (cols: 0=null, 1..1024=keys, rest=mask)
#define MASKB (-30000.f)  // softmax mask bias (bf16-safe, no near-inf)
#define LOG2E 1.4426950408889634f

typedef unsigned int u32;
typedef unsigned short ushort_t;
typedef __attribute__((ext_vector_type(8))) short bf16x8;
typedef __attribute__((ext_vector_type(4))) float f32x4;

__device__ inline ushort_t f2b(float x) {
    u32 u = __float_as_uint(x);
    u32 r = (u + 0x7fffu + ((u >> 16) & 1u)) >> 16;
    return (ushort_t)r;
}
__device__ inline float b2f(ushort_t u) { return __uint_as_float(((u32)u) << 16); }

__device__ inline float exp2_fast(float x) {
    float r;
    asm("v_exp_f32 %0, %1" : "=v"(r) : "v"(x));
    return r;
}

// pack two f32 -> {bf16(hi)<<16 | bf16(lo)}  (RTNE, gfx950)
__device__ inline u32 cvt_pk_bf16(float lo, float hi) {
    u32 r;
    asm("v_cvt_pk_bf16_f32 %0, %1, %2" : "=v"(r) : "v"(lo), "v"(hi));
    return r;
}

__device__ inline void gload_lds16(const void* g, void* l) {
    __builtin_amdgcn_global_load_lds(
        (const __attribute__((address_space(1))) u32*)g,
        (__attribute__((address_space(3))) u32*)l, 16, 0, 0);
}

__device__ inline float gelu_exact(float x) {
    return 0.5f * x * (1.f + erff(x * 0.70710678118654752f));
}

// counted-vmcnt helpers (immediates must be literals in the asm string)
__device__ inline void waitcnt_vm4() {
    asm volatile("s_waitcnt vmcnt(4)" ::: "memory");
    __builtin_amdgcn_sched_barrier(0);
}
__device__ inline void waitcnt_vm0() {
    asm volatile("s_waitcnt vmcnt(0)" ::: "memory");
    __builtin_amdgcn_sched_barrier(0);
}

// ---------------------------------------------------------------- CPB MLP
// 16 rows per block (w1 re-read traffic 1 GB -> 62 MB). FP order preserved.
__global__ __launch_bounds__(256) void cpb_kernel(
    const float* __restrict__ w0, const float* __restrict__ b0,
    const float* __restrict__ w1, const float* __restrict__ b1,
    const float* __restrict__ w2, const float* __restrict__ b2,
    float* __restrict__ table, int mode, int nrows)
{
    __shared__ float t0[16][256];
    __shared__ float t1[16][256];
    int r0 = blockIdx.x * 16;
    int t = threadIdx.x;
    float w0t = w0[t], b0t = b0[t];
    float w0t2 = (mode == 0) ? w0[256 + t] : 0.f;
    #pragma unroll
    for (int rr = 0; rr < 16; ++rr) {
        int r = r0 + rr; if (r >= nrows) r = nrows - 1;
        float c0, c1;
        if (mode == 0) { c0 = (float)(r / 63 - 31); c1 = (float)(r % 63 - 31); }
        else           { c0 = (float)(r - 15);      c1 = 0.f; }
        float a = c0 * w0t + b0t;
        if (mode == 0) a += c1 * w0t2;
        t0[rr][t] = a / (1.f + __expf(-a));
    }
    __syncthreads();
    float b1t = b1[t];
    float acc[16];
    #pragma unroll
    for (int rr = 0; rr < 16; ++rr) acc[rr] = b1t;
    for (int k = 0; k < 256; ++k) {
        float w = w1[k * 256 + t];
        #pragma unroll
        for (int rr = 0; rr < 16; ++rr) acc[rr] += t0[rr][k] * w;
    }
    #pragma unroll
    for (int rr = 0; rr < 16; ++rr) {
        float s = acc[rr];
        t1[rr][t] = s / (1.f + __expf(-s));
    }
    __syncthreads();
    if (t < 128) {
        int rr = t >> 3, oo = t & 7;
        int r = r0 + rr;
        if (r < nrows) {
            float o = b2[oo];
            for (int k = 0; k < 256; ++k) o += t1[rr][k] * w2[k * 8 + oo];
            table[r * 8 + oo] = o;
        }
    }
}

// ------------------------------- materialize spatial bias bf16, padded layout
// NOTE: bias is pre-scaled by LOG2E (softmax uses exp2)
__global__ __launch_bounds__(256) void bias_sp_kernel(
    const float* __restrict__ tab, const float* __restrict__ nullbias,
    ushort_t* __restrict__ out)
{
    int pi = blockIdx.x, h = blockIdx.y;
    int phi = pi >> 5, pwi = pi & 31;
    ushort_t* row = out + ((size_t)h * 1024 + pi) * BSTRIDE;
    for (int c = threadIdx.x; c < BSTRIDE; c += 256) {
        float v;
        if (c == 0) v = nullbias[h];
        else if (c <= 1024) {
            int pj = c - 1;
            int phj = pj >> 5, pwj = pj & 31;
            int idx = (phi - phj + 31) * 63 + (pwi - pwj + 31);
            v = tab[idx * 8 + h];
        } else v = MASKB;
        row[c] = f2b(v * LOG2E);
    }
}

// -------------------------------------------- KP/VT pad+null init. grid 16
__global__ __launch_bounds__(256) void kvinit_kernel(
    const float* __restrict__ nullkv, ushort_t* __restrict__ KP, ushort_t* __restrict__ VT)
{
    int f = blockIdx.x, t = threadIdx.x;
    for (int e = t; e < 32 * 64; e += 256) {
        int rr = e >> 6, d = e & 63;
        int row = (rr == 0) ? 0 : (1024 + rr);
        KP[((size_t)f * KVPAD + row) * 64 + d] = (rr == 0) ? f2b(nullkv[d]) : (ushort_t)0;
    }
    for (int e = t; e < 64 * 32; e += 256) {
        int d = e >> 5, cc = e & 31;
        int col = (cc == 0) ? 0 : (1024 + cc);
        VT[((size_t)f * 64 + d) * KVPAD + col] = (cc == 0) ? f2b(nullkv[64 + d]) : (ushort_t)0;
    }
}

// ---------------- weight convert: W[K][ldw] (col window c0) -> Bt[N][Kp] bf16
// Writes rows n < Nwrite (zeros for n >= Ncols or k >= K) — pad rows are clean.
__global__ __launch_bounds__(256) void wcvt_kernel(
    const float* __restrict__ W, int ldw, int c0,
    ushort_t* __restrict__ Bt, int Kp, int K, int Ncols,
    const float* __restrict__ gv, int Nwrite)
{
    __shared__ float tile[32][33];
    int nb = blockIdx.x * 32, kb = blockIdx.y * 32;
    int tx = threadIdx.x & 31, ty = threadIdx.x >> 5;
    #pragma unroll
    for (int it = 0; it < 4; ++it) {
        int k = kb + ty + it * 8, n = nb + tx;
        float v = (k < K && n < Ncols) ? W[(size_t)k * ldw + c0 + n] : 0.f;
        if (gv && k < K) v *= gv[k];
        tile[ty + it * 8][tx] = v;
    }
    __syncthreads();
    #pragma unroll
    for (int it = 0; it < 4; ++it) {
        int n = nb + ty + it * 8, k = kb + tx;
        if (n < Nwrite && k < Kp) Bt[(size_t)n * Kp + k] = f2b(tile[tx][ty + it * 8]);
    }
}

// ---------------------------------------------------- (C,T) -> (T,C) transpose
__global__ __launch_bounds__(256) void transpose_in_kernel(
    const float* __restrict__ x, float* __restrict__ dst)
{
    __shared__ float tile[32][33];
    int t0b = blockIdx.x * 32, c0b = blockIdx.y * 32;
    int tx = threadIdx.x & 31, ty = threadIdx.x >> 5;
    #pragma unroll
    for (int it = 0; it < 4; ++it) {
        int c = ty + it * 8;
        tile[c][tx] = x[(size_t)(c0b + c) * TOK + t0b + tx];
    }
    __syncthreads();
    #pragma unroll
    for (int it = 0; it < 4; ++it) {
        int tr = ty + it * 8;
        dst[(size_t)(t0b + tr) * DIMC + c0b + tx] = tile[tx][tr];
    }
}

// ---------------------------------------------------------------- LayerNorm → bf16
__global__ __launch_bounds__(256) void ln_bf16_kernel(
    const float* __restrict__ in, ushort_t* __restrict__ out,
    const float* __restrict__ w, const float* __restrict__ b)
{
    __shared__ float r1[4], r2[4];
    size_t base = (size_t)blockIdx.x * DIMC;
    int t = threadIdx.x;
    float x0 = in[base + t], x1 = in[base + 256 + t];
    float s = x0 + x1, s2 = x0 * x0 + x1 * x1;
    #pragma unroll
    for (int o = 32; o > 0; o >>= 1) { s += __shfl_down(s, o, 64); s2 += __shfl_down(s2, o, 64); }
    if ((t & 63) == 0) { r1[t >> 6] = s; r2[t >> 6] = s2; }
    __syncthreads();
    float mean = (r1[0] + r1[1] + r1[2] + r1[3]) * (1.f / 512.f);
    float ex2  = (r2[0] + r2[1] + r2[2] + r2[3]) * (1.f / 512.f);
    float rstd = rsqrtf(ex2 - mean * mean + 1e-5f);
    out[base + t]       = f2b((x0 - mean) * rstd * w[t] + b[t]);
    out[base + 256 + t] = f2b((x1 - mean) * rstd * w[256 + t] + b[256 + t]);
}

// LN(proj f32) + residual in place
__global__ __launch_bounds__(256) void ln_add_kernel(
    const float* __restrict__ proj, float* __restrict__ io,
    const float* __restrict__ w, const float* __restrict__ b)
{
    __shared__ float r1[4], r2[4];
    size_t base = (size_t)blockIdx.x * DIMC;
    int t = threadIdx.x;
    float x0 = proj[base + t], x1 = proj[base + 256 + t];
    float s = x0 + x1, s2 = x0 * x0 + x1 * x1;
    #pragma unroll
    for (int o = 32; o > 0; o >>= 1) { s += __shfl_down(s, o, 64); s2 += __shfl_down(s2, o, 64); }
    if ((t & 63) == 0) { r1[t >> 6] = s; r2[t >> 6] = s2; }
    __syncthreads();
    float mean = (r1[0] + r1[1] + r1[2] + r1[3]) * (1.f / 512.f);
    float ex2  = (r2[0] + r2[1] + r2[2] + r2[3]) * (1.f / 512.f);
    float rstd = rsqrtf(ex2 - mean * mean + 1e-5f);
    io[base + t]       += (x0 - mean) * rstd * w[t] + b[t];
    io[base + 256 + t] += (x1 - mean) * rstd * w[256 + t] + b[256 + t];
}

// spatial->temporal row permute (f32)
__global__ __launch_bounds__(128) void permute0_kernel(
    const float* __restrict__ src, float* __restrict__ dst)
{
    int rd = blockIdx.x;
    int rs = (rd & 15) * 1024 + (rd >> 4);
    ((float4*)(dst + (size_t)rd * DIMC))[threadIdx.x] =
        ((const float4*)(src + (size_t)rs * DIMC))[threadIdx.x];
}

// temporal->spatial permute, dual output f32 + bf16
__global__ __launch_bounds__(128) void permute1_dual_kernel(
    const float* __restrict__ src, float* __restrict__ dst, ushort_t* __restrict__ dstb)
{
    int rd = blockIdx.x;
    int rs = (rd & 1023) * 16 + (rd >> 10);
    float4 v = ((const float4*)(src + (size_t)rs * DIMC))[threadIdx.x];
    ((float4*)(dst + (size_t)rd * DIMC))[threadIdx.x] = v;
    u32 lo = (u32)f2b(v.x) | ((u32)f2b(v.y) << 16);
    u32 hi = (u32)f2b(v.z) | ((u32)f2b(v.w) << 16);
    ((uint2*)(dstb + (size_t)rd * DIMC))[threadIdx.x] = make_uint2(lo, hi);
}

// ---------------------------------------------------------------- MFMA GEMM
// 1-D grid of nx*16*8 blocks. XCD-aware swizzle: xcd = lin&7 owns m-tiles
// [xcd*16, xcd*16+16) for ALL nx n-tiles -> per-XCD L2-resident A band.
// ROUND-16: REVERT to round-5 measured-best schedule (2-buffer:
// vmcnt(4) -> s_barrier -> compute -> s_barrier -> stage(t+2)); keep only
// the hoisted incremental pointers from round 6 (VALU-only change).
// Round-6's 3-buffer/1-barrier variant measured WORSE (117.6 -> 122.5 µs).
template<int EPI>
__global__ __launch_bounds__(256) void gemm_mfma(
    const ushort_t* __restrict__ A, int lda,
    const ushort_t* __restrict__ Bt, int Kp,
    float* __restrict__ C, ushort_t* __restrict__ Cb, int ldc,
    int M, int N, int K, float scale, int nx,
    const float* __restrict__ stats, const float* __restrict__ g,
    const float* __restrict__ resid, float* __restrict__ outT,
    ushort_t* __restrict__ KPo, ushort_t* __restrict__ VTo)
{
    __shared__ __align__(16) ushort_t As[2][4 * 128 * 8];
    __shared__ __align__(16) ushort_t Bs[2][4 * 128 * 8];
    int lin = blockIdx.x;
    int xcd = lin & 7, idx = lin >> 3;
    int m0 = (xcd * 16 + (idx & 15)) * 128;
    int n0 = (idx >> 4) * 128;
    int tid = threadIdx.x, lane = tid & 63, wid = tid >> 6;
    int wy = wid >> 1, wx = wid & 1, quad = lane >> 4, l16 = lane & 15;
    bool bfull = (n0 + 128 <= N);
    f32x4 acc[4][4];
    #pragma unroll
    for (int i = 0; i < 4; ++i)
        #pragma unroll
        for (int j = 0; j < 4; ++j) { acc[i][j][0]=0.f; acc[i][j][1]=0.f; acc[i][j][2]=0.f; acc[i][j][3]=0.f; }

    if (bfull) {
        int NT = K >> 5;
        int c0 = wid * 128 + lane, c1 = wid * 128 + 64 + lane;
        const ushort_t* gA0 = A + (size_t)(m0 + (c0 & 127)) * lda + (c0 >> 7) * 8;
        const ushort_t* gA1 = A + (size_t)(m0 + (c1 & 127)) * lda + (c1 >> 7) * 8;
        const ushort_t* gB0 = Bt + (size_t)(n0 + (c0 & 127)) * Kp + (c0 >> 7) * 8;
        const ushort_t* gB1 = Bt + (size_t)(n0 + (c1 & 127)) * Kp + (c1 >> 7) * 8;
        const int lo0 = (wid * 128) * 8, lo1 = (wid * 128 + 64) * 8;
        auto stage = [&](int buf) {
            gload_lds16(gA0, &As[buf][lo0]);
            gload_lds16(gA1, &As[buf][lo1]);
            gload_lds16(gB0, &Bs[buf][lo0]);
            gload_lds16(gB1, &Bs[buf][lo1]);
            gA0 += 32; gA1 += 32; gB0 += 32; gB1 += 32;
        };
        stage(0);
        if (NT > 1) stage(1);
        for (int t = 0; t < NT; ++t) {
            if (t + 1 < NT) waitcnt_vm4(); else waitcnt_vm0();
            __builtin_amdgcn_s_barrier();
            int cur = t & 1;
            bf16x8 af[4], bfr[4];
            #pragma unroll
            for (int i = 0; i < 4; ++i) af[i] = *(bf16x8*)&As[cur][(quad * 128 + wy * 64 + i * 16 + l16) * 8];
            #pragma unroll
            for (int j = 0; j < 4; ++j) bfr[j] = *(bf16x8*)&Bs[cur][(quad * 128 + wx * 64 + j * 16 + l16) * 8];
            #pragma unroll
            for (int i = 0; i < 4; ++i)
                #pragma unroll
                for (int j = 0; j < 4; ++j)
                    acc[i][j] = __builtin_amdgcn_mfma_f32_16x16x32_bf16(af[i], bfr[j], acc[i][j], 0, 0, 0);
            if (t + 2 < NT) {
                __builtin_amdgcn_s_barrier();
                stage(cur);
            }
        }
    } else {
        // conservative fallback (not taken by current launches)
        for (int k0 = 0; k0 < K; k0 += 32) {
            if (k0) __syncthreads();
            #pragma unroll
            for (int r = 0; r < 2; ++r) {
                int c = wid * 128 + r * 64 + lane;
                const ushort_t* src = A + (size_t)(m0 + (c & 127)) * lda + k0 + (c >> 7) * 8;
                gload_lds16(src, &As[0][(wid * 128 + r * 64) * 8]);
            }
            #pragma unroll
            for (int r = 0; r < 2; ++r) {
                int c = tid + r * 256;
                int kg = c >> 7, nloc = c & 127;
                bf16x8 v;
                if (n0 + nloc < N) v = *(const bf16x8*)(Bt + (size_t)(n0 + nloc) * Kp + k0 + kg * 8);
                else { for (int e = 0; e < 8; ++e) v[e] = 0; }
                *(bf16x8*)&Bs[0][c * 8] = v;
            }
            __syncthreads();
            bf16x8 af[4], bfr[4];
            #pragma unroll
            for (int i = 0; i < 4; ++i) af[i] = *(bf16x8*)&As[0][(quad * 128 + wy * 64 + i * 16 + l16) * 8];
            #pragma unroll
            for (int j = 0; j < 4; ++j) bfr[j] = *(bf16x8*)&Bs[0][(quad * 128 + wx * 64 + j * 16 + l16) * 8];
            #pragma unroll
            for (int i = 0; i < 4; ++i)
                #pragma unroll
                for (int j = 0; j < 4; ++j)
                    acc[i][j] = __builtin_amdgcn_mfma_f32_16x16x32_bf16(af[i], bfr[j], acc[i][j], 0, 0, 0);
        }
    }
    #pragma unroll
    for (int i = 0; i < 4; ++i) {
        #pragma unroll
        for (int j = 0; j < 4; ++j) {
            #pragma unroll
            for (int r = 0; r < 4; ++r) {
                int m = m0 + wy * 64 + i * 16 + quad * 4 + r;
                int n = n0 + wx * 64 + j * 16 + l16;
                if (n >= N) continue;
                float v = acc[i][j][r] * scale;
                if (EPI == 0) {
                    C[(size_t)m * ldc + n] = v;
                } else if (EPI == 3) {
                    Cb[(size_t)m * ldc + n] = f2b(v);
                } else if (EPI == 4) {
                    int frame = m >> 10, tt = m & 1023;
                    if (n < 64) KPo[((size_t)frame * KVPAD + 1 + tt) * 64 + n] = f2b(v);
                    else        VTo[((size_t)frame * 64 + (n - 64)) * KVPAD + 1 + tt] = f2b(v);
                } else if (EPI == 5) {
                    float s0 = stats[2 * m], s1 = stats[2 * m + 1];
                    outT[(size_t)n * TOK + m] = v * s1 - s0 * g[n] + resid[(size_t)m * DIMC + n];
                }
            }
        }
    }
}

// ------------------------------------------- fused FF front GEMM (a & gate)
// 128m x 64n dual-output tile -> acc = 64 AGPR/thread. B from interleaved
// BI[2816][512] via pure global_load_lds. Grid 2816 = 8 XCD x 16 m x 22 n.
// ROUND-16: revert to round-5 schedule + hoisted incremental pointers.
__global__ __launch_bounds__(256) void ff_gemm_fused(
    const ushort_t* __restrict__ A,
    const ushort_t* __restrict__ BI,
    ushort_t* __restrict__ YS)
{
    __shared__ __align__(16) ushort_t As[2][4 * 128 * 8];
    __shared__ __align__(16) ushort_t Bs[2][4 * 2 * 64 * 8];
    int lin = blockIdx.x;
    int xcd = lin & 7, idx = lin >> 3;
    int m0 = (xcd * 16 + (idx & 15)) * 128;
    int n0 = (idx >> 4) * 64;
    int tid = threadIdx.x, lane = tid & 63, wid = tid >> 6;
    int wy = wid >> 1, wx = wid & 1, quad = lane >> 4, l16 = lane & 15;
    f32x4 aA[4][2], aG[4][2];
    #pragma unroll
    for (int i = 0; i < 4; ++i)
        #pragma unroll
        for (int j = 0; j < 2; ++j) {
            aA[i][j][0]=0.f; aA[i][j][1]=0.f; aA[i][j][2]=0.f; aA[i][j][3]=0.f;
            aG[i][j][0]=0.f; aG[i][j][1]=0.f; aG[i][j][2]=0.f; aG[i][j][3]=0.f;
        }

    int c0 = wid * 128 + lane, c1 = wid * 128 + 64 + lane;
    const ushort_t* gA0 = A + (size_t)(m0 + (c0 & 127)) * 512 + (c0 >> 7) * 8;
    const ushort_t* gA1 = A + (size_t)(m0 + (c1 & 127)) * 512 + (c1 >> 7) * 8;
    const ushort_t* gB0 = BI + (size_t)((n0 + lane) * 2 + 0) * 512 + wid * 8;
    const ushort_t* gB1 = BI + (size_t)((n0 + lane) * 2 + 1) * 512 + wid * 8;
    const int lo0 = (wid * 128) * 8, lo1 = (wid * 128 + 64) * 8;
    auto stage = [&](int buf) {
        gload_lds16(gA0, &As[buf][lo0]);
        gload_lds16(gA1, &As[buf][lo1]);
        gload_lds16(gB0, &Bs[buf][lo0]);
        gload_lds16(gB1, &Bs[buf][lo1]);
        gA0 += 32; gA1 += 32; gB0 += 32; gB1 += 32;
    };

    stage(0); stage(1);
    for (int t = 0; t < 16; ++t) {
        if (t + 1 < 16) waitcnt_vm4(); else waitcnt_vm0();
        __builtin_amdgcn_s_barrier();
        int cur = t & 1;
        bf16x8 af[4], ba[2], bg[2];
        #pragma unroll
        for (int i = 0; i < 4; ++i) af[i] = *(bf16x8*)&As[cur][(quad * 128 + wy * 64 + i * 16 + l16) * 8];
        #pragma unroll
        for (int j = 0; j < 2; ++j) {
            int nn = wx * 32 + j * 16 + l16;
            ba[j] = *(bf16x8*)&Bs[cur][(quad * 128 + nn) * 8];
            bg[j] = *(bf16x8*)&Bs[cur][(quad * 128 + 64 + nn) * 8];
        }
        #pragma unroll
        for (int i = 0; i < 4; ++i)
            #pragma unroll
            for (int j = 0; j < 2; ++j) {
                aA[i][j] = __builtin_amdgcn_mfma_f32_16x16x32_bf16(af[i], ba[j], aA[i][j], 0, 0, 0);
                aG[i][j] = __builtin_amdgcn_mfma_f32_16x16x32_bf16(af[i], bg[j], aG[i][j], 0, 0, 0);
            }
        if (t + 2 < 16) {
            __builtin_amdgcn_s_barrier();
            stage(cur);
        }
    }
    #pragma unroll
    for (int i = 0; i < 4; ++i) {
        #pragma unroll
        for (int j = 0; j < 2; ++j) {
            #pragma unroll
            for (int r = 0; r < 4; ++r) {
                int m = m0 + wy * 64 + i * 16 + quad * 4 + r;
                int n = n0 + wx * 32 + j * 16 + l16;
                if (n >= FFI) {
                    if (n < YSLD) YS[(size_t)m * YSLD + n] = 0;   // zero pad cols
                    continue;
                }
                float v = aA[i][j][r] * gelu_exact(aG[i][j][r]);
                int dr = (n < CH1) ? m : m + 1024;
                if (dr < TOK) YS[(size_t)dr * YSLD + n] = f2b(v);
                if (n >= CH1 && m < 1024) YS[(size_t)m * YSLD + n] = 0;
            }
        }
    }
}

// --------------------------------------------------- spatial attention (MFMA flash)
// Grid remap: per XCD = q-tile band (8 qt) x ALL 16 frames (bias L2-resident).
// Softmax without online-max (logits bounded, base-2 domain, mask underflows
// to 0), row-sum via MFMA ones-column (zero-shuffle epilogue), P pack via
// v_cvt_pk_bf16_f32. In-register ds_bpermute transpose.
__global__ __launch_bounds__(256) void attn_sp_mfma(
    const ushort_t* __restrict__ Q,      // [16384][512] bf16 pre-scaled by 0.125*log2e
    const ushort_t* __restrict__ KP,     // [16][1056][64]
    const ushort_t* __restrict__ VT,     // [16][64][1056]
    const ushort_t* __restrict__ BIASX,  // [8][1024][1152], pre-scaled by log2e
    ushort_t* __restrict__ O)            // [16384][512] bf16
{
    __shared__ __align__(16) ushort_t Ks[128 * 64];
    __shared__ __align__(16) ushort_t Vs[64 * 128];
    int lin = blockIdx.x;
    int xcd = lin & 7, idx = lin >> 3;
    int qt = xcd * 8 + (idx & 7);
    int frame = idx >> 3;
    int q0 = qt * 16;
    int tid = threadIdx.x, lane = tid & 63, wid = tid >> 6;
    int quad = lane >> 4, l16 = lane & 15;

    bf16x8 aQ[2][2];
    const ushort_t* brow[2];
    #pragma unroll
    for (int i = 0; i < 2; ++i) {
        int h = wid * 2 + i;
        const ushort_t* qp = Q + (size_t)(frame * 1024 + q0 + l16) * 512 + h * 64 + quad * 8;
        aQ[i][0] = *(const bf16x8*)qp;
        aQ[i][1] = *(const bf16x8*)(qp + 32);
        brow[i] = BIASX + ((size_t)h * 1024 + q0 + l16) * BSTRIDE;
    }
    f32x4 Oc[2][4];
    f32x4 Oc4[2];   // row-sum accumulator (ones-column PV)
    #pragma unroll
    for (int i = 0; i < 2; ++i) {
        #pragma unroll
        for (int nt = 0; nt < 4; ++nt) { Oc[i][nt][0]=0.f; Oc[i][nt][1]=0.f; Oc[i][nt][2]=0.f; Oc[i][nt][3]=0.f; }
        Oc4[i][0]=0.f; Oc4[i][1]=0.f; Oc4[i][2]=0.f; Oc4[i][3]=0.f;
    }
    bf16x8 vones;
    #pragma unroll
    for (int e = 0; e < 8; ++e) vones[e] = (short)0x3F80;   // bf16 1.0

    // bpermute byte-indices for the in-register P transpose:
    // target (quad,l16) word w pulls from lane (2*(quad&1)+(w>>1))*16 + l16
    int idxA = (((quad & 1) * 32) + l16) * 4;   // w = 0,1
    int idxB = idxA + 64;                       // w = 2,3
    bool hiq = (quad >= 2);                     // selects j = 2ks+1

    for (int jt = 0; jt < 9; ++jt) {
        __syncthreads();
        #pragma unroll
        for (int r = 0; r < 4; ++r) {
            int L = wid * 256 + r * 64 + lane;
            int c = L >> 3, gp = L & 7, gg = gp ^ (c & 7);
            int jj = jt * 128 + c; if (jj > KVPAD - 1) jj = KVPAD - 1;
            gload_lds16(KP + ((size_t)frame * KVPAD + jj) * 64 + gg * 8, &Ks[(wid * 256 + r * 64) * 8]);
        }
        #pragma unroll
        for (int r = 0; r < 4; ++r) {
            int L = wid * 256 + r * 64 + lane;
            int d = L >> 4, cgp = L & 15;
            int cg = (cgp & 8) | ((cgp & 7) ^ (d & 7));
            int col = jt * 128 + cg * 8; if (col > KVPAD - 8) col = KVPAD - 8;
            gload_lds16(VT + ((size_t)frame * 64 + d) * KVPAD + col, &Vs[(wid * 256 + r * 64) * 8]);
        }
        __syncthreads();

        #pragma unroll
        for (int i = 0; i < 2; ++i) {
            // ---- QK^T for this head
            f32x4 S[8];
            #pragma unroll
            for (int j = 0; j < 8; ++j) { S[j][0]=0.f; S[j][1]=0.f; S[j][2]=0.f; S[j][3]=0.f; }
            __builtin_amdgcn_s_setprio(1);
            #pragma unroll
            for (int j = 0; j < 8; ++j) {
                int c = j * 16 + l16;
                #pragma unroll
                for (int ks = 0; ks < 2; ++ks) {
                    bf16x8 kb = *(bf16x8*)&Ks[(c * 8 + ((ks * 4 + quad) ^ (c & 7))) * 8];
                    S[j] = __builtin_amdgcn_mfma_f32_16x16x32_bf16(kb, aQ[i][ks], S[j], 0, 0, 0);
                }
            }
            __builtin_amdgcn_s_setprio(0);
            // ---- bias add + direct exp2 (no max tracking: base-2 logits are
            // small/bounded; MASKB*log2e underflows exp2 to exactly 0)
            #pragma unroll
            for (int j = 0; j < 8; ++j) {
                int kbase = jt * 128 + j * 16 + quad * 4;
                uint2 bv = *(const uint2*)(brow[i] + kbase);
                S[j][0] = exp2_fast(S[j][0] + __uint_as_float(bv.x << 16));
                S[j][1] = exp2_fast(S[j][1] + __uint_as_float(bv.x & 0xffff0000u));
                S[j][2] = exp2_fast(S[j][2] + __uint_as_float(bv.y << 16));
                S[j][3] = exp2_fast(S[j][3] + __uint_as_float(bv.y & 0xffff0000u));
            }
            // ---- pack (cvt_pk) + in-register transpose (ds_bpermute) + PV
            __builtin_amdgcn_s_setprio(1);
            #pragma unroll
            for (int ks = 0; ks < 4; ++ks) {
                int jl = 2 * ks, jh = 2 * ks + 1;
                u32 pxl = cvt_pk_bf16(S[jl][0], S[jl][1]);
                u32 pyl = cvt_pk_bf16(S[jl][2], S[jl][3]);
                u32 pxh = cvt_pk_bf16(S[jh][0], S[jh][1]);
                u32 pyh = cvt_pk_bf16(S[jh][2], S[jh][3]);
                u32 a0 = (u32)__builtin_amdgcn_ds_bpermute(idxA, (int)pxl);
                u32 a1 = (u32)__builtin_amdgcn_ds_bpermute(idxA, (int)pxh);
                u32 b0 = (u32)__builtin_amdgcn_ds_bpermute(idxA, (int)pyl);
                u32 b1 = (u32)__builtin_amdgcn_ds_bpermute(idxA, (int)pyh);
                u32 c0 = (u32)__builtin_amdgcn_ds_bpermute(idxB, (int)pxl);
                u32 c1 = (u32)__builtin_amdgcn_ds_bpermute(idxB, (int)pxh);
                u32 d0 = (u32)__builtin_amdgcn_ds_bpermute(idxB, (int)pyl);
                u32 d1 = (u32)__builtin_amdgcn_ds_bpermute(idxB, (int)pyh);
                union { u32 w[4]; bf16x8 v; } pa;
                pa.w[0] = hiq ? a1 : a0;
                pa.w[1] = hiq ? b1 : b0;
                pa.w[2] = hiq ? c1 : c0;
                pa.w[3] = hiq ? d1 : d0;
                #pragma unroll
                for (int nt = 0; nt < 4; ++nt) {
                    int d = nt * 16 + l16;
                    int cg = ks * 4 + quad;
                    int phys = (cg & 8) | ((cg & 7) ^ (d & 7));
                    bf16x8 vb = *(bf16x8*)&Vs[(d * 16 + phys) * 8];
                    Oc[i][nt] = __builtin_amdgcn_mfma_f32_16x16x32_bf16(pa.v, vb, Oc[i][nt], 0, 0, 0);
                }
                // ones-column: accumulates row-sum of P in matching layout
                Oc4[i] = __builtin_amdgcn_mfma_f32_16x16x32_bf16(pa.v, vones, Oc4[i], 0, 0, 0);
            }
            __builtin_amdgcn_s_setprio(0);
        }
    }
    #pragma unroll
    for (int i = 0; i < 2; ++i) {
        int h = wid * 2 + i;
        #pragma unroll
        for (int r = 0; r < 4; ++r) {
            float linv = 1.f / Oc4[i][r];   // same (q,row) layout as Oc — no shuffle
            int ql = quad * 4 + r;
            #pragma unroll
            for (int nt = 0; nt < 4; ++nt) {
                int d = nt * 16 + l16;
                O[(size_t)(frame * 1024 + q0 + ql) * 512 + h * 64 + d] = f2b(Oc[i][nt][r] * linv);
            }
        }
    }
}

// ---------------------------------------------------------------- temporal attention
// Vectorized q load (16B), float4 LDS reads in QK and PV phases.
// FP accumulation order preserved element-wise.
__global__ __launch_bounds__(256) void attn_tp_kernel(
    const ushort_t* __restrict__ q, const ushort_t* __restrict__ kv,
    const float* __restrict__ nullkv, const float* __restrict__ nullbias,
    const float* __restrict__ table, ushort_t* __restrict__ out)
{
    __shared__ float qs[16][512];
    __shared__ float ks[17][64];
    __shared__ float vs[17][64];
    __shared__ float sc[8][16][17];
    int b = blockIdx.x;
    int t = threadIdx.x;
    for (int e = t; e < 16 * 64; e += 256) {
        int f = e >> 6, c8 = e & 63;
        uint4 v = *(const uint4*)(q + (size_t)(b * 16 + f) * 512 + c8 * 8);
        float* dst = &qs[f][c8 * 8];
        dst[0] = b2f((ushort_t)(v.x & 0xffffu)); dst[1] = b2f((ushort_t)(v.x >> 16));
        dst[2] = b2f((ushort_t)(v.y & 0xffffu)); dst[3] = b2f((ushort_t)(v.y >> 16));
        dst[4] = b2f((ushort_t)(v.z & 0xffffu)); dst[5] = b2f((ushort_t)(v.z >> 16));
        dst[6] = b2f((ushort_t)(v.w & 0xffffu)); dst[7] = b2f((ushort_t)(v.w >> 16));
    }
    for (int e = t; e < 17 * 64; e += 256) {
        int j = e >> 6, d = e & 63;
        ks[j][d] = (j == 0) ? nullkv[d]      : b2f(kv[(size_t)(b * 16 + j - 1) * 128 + d]);
        vs[j][d] = (j == 0) ? nullkv[64 + d] : b2f(kv[(size_t)(b * 16 + j - 1) * 128 + 64 + d]);
    }
    __syncthreads();
    for (int e = t; e < 8 * 16 * 17; e += 256) {
        int h = e / 272, rem = e - h * 272;
        int i = rem / 17, j = rem - i * 17;
        float acc = 0.f;
        const float4* qp = (const float4*)&qs[i][h * 64];
        const float4* kp = (const float4*)&ks[j][0];
        #pragma unroll
        for (int d4 = 0; d4 < 16; ++d4) {
            float4 qv = qp[d4], kv4 = kp[d4];
            acc += qv.x * kv4.x;
            acc += qv.y * kv4.y;
            acc += qv.z * kv4.z;
            acc += qv.w * kv4.w;
        }
        float bias = ((j == 0) ? nullbias[h] : table[(i - (j - 1) + 15) * 8 + h]) * LOG2E;
        sc[h][i][j] = acc + bias;   // q pre-scaled by 0.125*log2e -> base-2 logits
    }
    __syncthreads();
    if (t < 128) {
        int h = t >> 4, i = t & 15;
        float mx = -1e30f;
        for (int j = 0; j < 17; ++j) mx = fmaxf(mx, sc[h][i][j]);
        float s = 0.f;
        for (int j = 0; j < 17; ++j) { float p = exp2_fast(sc[h][i][j] - mx); sc[h][i][j] = p; s += p; }
        float inv = 1.f / s;
        for (int j = 0; j < 17; ++j) sc[h][i][j] *= inv;
    }
    __syncthreads();
    for (int e = t; e < 16 * 128; e += 256) {
        int i = e >> 7, c4 = e & 127;
        int h = c4 >> 4, d4 = c4 & 15;
        float ax = 0.f, ay = 0.f, az = 0.f, aw = 0.f;
        #pragma unroll
        for (int j = 0; j < 17; ++j) {
            float p = sc[h][i][j];
            float4 vv = *(const float4*)&vs[j][d4 * 4];
            ax += p * vv.x; ay += p * vv.y; az += p * vv.z; aw += p * vv.w;
        }
        u32 lo = (u32)f2b(ax) | ((u32)f2b(ay) << 16);
        u32 hi = (u32)f2b(az) | ((u32)f2b(aw) << 16);
        *(uint2*)(out + (size_t)(b * 16 + i) * 512 + c4 * 4) = make_uint2(lo, hi);
    }
}

// ------------------------- FF shift-LN row stats from bf16 YS: (mean*rstd, rstd)
__global__ __launch_bounds__(256) void rowstats_bf16_kernel(
    const ushort_t* __restrict__ YS, float* __restrict__ stats)
{
    __shared__ float r1[4], r2[4];
    int r = blockIdx.x, t = threadIdx.x;
    const ushort_t* row = YS + (size_t)r * YSLD;
    float s = 0.f, s2 = 0.f;
    for (int c = t; c < FFI; c += 256) {
        float v = b2f(row[c]);
        s += v; s2 += v * v;
    }
    #pragma unroll
    for (int o = 32; o > 0; o >>= 1) { s += __shfl_down(s, o, 64); s2 += __shfl_down(s2, o, 64); }
    if ((t & 63) == 0) { r1[t >> 6] = s; r2[t >> 6] = s2; }
    __syncthreads();
    float S  = r1[0] + r1[1] + r1[2] + r1[3];
    float S2 = r2[0] + r2[1] + r2[2] + r2[3];
    float mean = S * (1.f / 1365.f);
    float var  = S2 * (1.f / 1365.f) - mean * mean;
    float rstd = rsqrtf(fmaxf(var, 1e-5f));
    if (t == 0) { stats[2 * r] = mean * rstd; stats[2 * r + 1] = rstd; }
}

// --------------------- colsum[n] = sum_k W'[n][k]  (rows of converted W')
__global__ __launch_bounds__(64) void colsum_kernel(
    const ushort_t* __restrict__ Wt, float* __restrict__ colsum)
{
    int n = blockIdx.x, t = threadIdx.x;
    const ushort_t* row = Wt + (size_t)n * YSLD;
    float s = 0.f;
    for (int k = t; k < YSLD; k += 64) s += b2f(row[k]);
    #pragma unroll
    for (int o = 32; o > 0; o >>= 1) s += __shfl_down(s, o, 64);
    if (t == 0) colsum[n] = s;
}

// ================================================================ launcher
extern "C" void kernel_launch(void* const* d_in, const int* in_sizes, int n_in,
                              void* d_out, int out_size, void* d_ws, size_t ws_size,
                              hipStream_t stream)
{
    const float* x          = (const float*)d_in[0];
    const float* sa_ln_w    = (const float*)d_in[1];
    const float* sa_ln_b    = (const float*)d_in[2];
    const float* sa_wq      = (const float*)d_in[3];
    const float* sa_wkv     = (const float*)d_in[4];
    const float* sa_null_kv = (const float*)d_in[5];
    const float* sa_null_b  = (const float*)d_in[6];
    const float* sa_wout    = (const float*)d_in[7];
    const float* sa_oln_w   = (const float*)d_in[8];
    const float* sa_oln_b   = (const float*)d_in[9];
    const float* ta_ln_w    = (const float*)d_in[10];
    const float* ta_ln_b    = (const float*)d_in[11];
    const float* ta_wq      = (const float*)d_in[12];
    const float* ta_wkv     = (const float*)d_in[13];
    const float* ta_null_kv = (const float*)d_in[14];
    const float* ta_null_b  = (const float*)d_in[15];
    const float* ta_wout    = (const float*)d_in[16];
    const float* ta_oln_w   = (const float*)d_in[17];
    const float* ta_oln_b   = (const float*)d_in[18];
    const float* sp_w0      = (const float*)d_in[19];
    const float* sp_b0      = (const float*)d_in[20];
    const float* sp_w1      = (const float*)d_in[21];
    const float* sp_b1      = (const float*)d_in[22];
    const float* sp_w2      = (const float*)d_in[23];
    const float* sp_b2      = (const float*)d_in[24];
    const float* tp_w0      = (const float*)d_in[25];
    const float* tp_b0      = (const float*)d_in[26];
    const float* tp_w1      = (const float*)d_in[27];
    const float* tp_b1      = (const float*)d_in[28];
    const float* tp_w2      = (const float*)d_in[29];
    const float* tp_b2      = (const float*)d_in[30];
    const float* ff_win     = (const float*)d_in[31];
    const float* ff_g       = (const float*)d_in[32];
    const float* ff_wout    = (const float*)d_in[33];

    char* ws = (char*)d_ws;
    // regions (bytes)
    float*    RES   = (float*)(ws + 0);                        // residual, spatial layout
    ushort_t* XN16  = (ushort_t*)(ws + 33554432);              // xn / x2 bf16
    ushort_t* Q16   = (ushort_t*)(ws + 50331648);              // spatial Q bf16 (spatial phase)
    float*    RT    = (float*)(ws + 50331648);                 // temporal residual f32 (temporal phase)
    ushort_t* YS    = (ushort_t*)(ws + 50331648);              // FF shifted act bf16 [16384][1376]
    ushort_t* WSA   = (ushort_t*)(ws + 67108864);              // spatial weights (dead by FF)
    ushort_t* KP    = (ushort_t*)(ws + 83886080);              // 16x1056x64 bf16 (spatial)
    ushort_t* VTb   = (ushort_t*)(ws + 86048768);              // 16x64x1056 bf16 (spatial)
    ushort_t* KV16  = (ushort_t*)(ws + 83886080);              // temporal KV bf16
    ushort_t* WTA   = (ushort_t*)(ws + 90439680);              // temporal weights
    ushort_t* AO16  = (ushort_t*)(ws + 92274688);              // attn out bf16 (dead by FF)
    ushort_t* BI    = (ushort_t*)(ws + 96468992);              // FF interleaved W [2816][512]
    ushort_t* WFFB  = (ushort_t*)(ws + 99352576);              // W' = (ff_wout*g)^T [512][1376]
    ushort_t* BIAS16= (ushort_t*)(ws + 109051904);             // spatial bias bf16 (PRJ region)
    float*    PRJ   = (float*)(ws + 109051904);                // proj out f32
    ushort_t* Q16t  = (ushort_t*)(ws + 109051904);             // temporal Q bf16
    float*    STATS = (float*)(ws + 142606336);                // 16384 x (mean*rstd, rstd)
    float*    SPT   = (float*)(ws + 142737408);                // spatial CPB table (spatial phase)
    float*    COLSUM= (float*)(ws + 142737408);                // colsum[512] (FF phase, dead SPT)
    float*    TPT   = (float*)(ws + 142864448);

    ushort_t* WQ_T  = WSA;                 // [512][512]
    ushort_t* WKV_T = WSA + 262144;        // [128][512]
    ushort_t* WO_T  = WSA + 327680;        // [512][512]
    ushort_t* tWQ_T  = WTA;
    ushort_t* tWKV_T = WTA + 262144;
    ushort_t* tWO_T  = WTA + 327680;

    dim3 blk(256);
    const float QSCL = 0.125f * LOG2E;   // fold log2e into Q so softmax is exp2

    // bias tables
    cpb_kernel<<<dim3(249), blk, 0, stream>>>(sp_w0, sp_b0, sp_w1, sp_b1, sp_w2, sp_b2, SPT, 0, 3969);
    cpb_kernel<<<dim3(2),   blk, 0, stream>>>(tp_w0, tp_b0, tp_w1, tp_b1, tp_w2, tp_b2, TPT, 1, 31);
    bias_sp_kernel<<<dim3(1024, 8), blk, 0, stream>>>(SPT, sa_null_b, BIAS16);
    kvinit_kernel<<<dim3(16), blk, 0, stream>>>(sa_null_kv, KP, VTb);

    // ---------------- spatial ----------------
    wcvt_kernel<<<dim3(16, 16), blk, 0, stream>>>(sa_wq, 512, 0, WQ_T, 512, 512, 512, nullptr, 512);
    wcvt_kernel<<<dim3(4, 16),  blk, 0, stream>>>(sa_wkv, 128, 0, WKV_T, 512, 512, 128, nullptr, 128);
    wcvt_kernel<<<dim3(16, 16), blk, 0, stream>>>(sa_wout, 512, 0, WO_T, 512, 512, 512, nullptr, 512);
    transpose_in_kernel<<<dim3(512, 16), blk, 0, stream>>>(x, RES);
    ln_bf16_kernel<<<dim3(TOK), blk, 0, stream>>>(RES, XN16, sa_ln_w, sa_ln_b);
    gemm_mfma<3><<<dim3(512), blk, 0, stream>>>(XN16, 512, WQ_T, 512,
        nullptr, Q16, 512, TOK, 512, 512, QSCL, 4, nullptr, nullptr, nullptr, nullptr, nullptr, nullptr);
    gemm_mfma<4><<<dim3(128), blk, 0, stream>>>(XN16, 512, WKV_T, 512,
        nullptr, nullptr, 0, TOK, 128, 512, 1.0f, 1, nullptr, nullptr, nullptr, nullptr, KP, VTb);
    attn_sp_mfma<<<dim3(1024), blk, 0, stream>>>(Q16, KP, VTb, BIAS16, AO16);
    gemm_mfma<0><<<dim3(512), blk, 0, stream>>>(AO16, 512, WO_T, 512,
        PRJ, nullptr, 512, TOK, 512, 512, 1.0f, 4, nullptr, nullptr, nullptr, nullptr, nullptr, nullptr);
    ln_add_kernel<<<dim3(TOK), blk, 0, stream>>>(PRJ, RES, sa_oln_w, sa_oln_b);

    // ---------------- temporal ----------------
    permute0_kernel<<<dim3(TOK), dim3(128), 0, stream>>>(RES, RT);
    wcvt_kernel<<<dim3(16, 16), blk, 0, stream>>>(ta_wq, 512, 0, tWQ_T, 512, 512, 512, nullptr, 512);
    wcvt_kernel<<<dim3(4, 16),  blk, 0, stream>>>(ta_wkv, 128, 0, tWKV_T, 512, 512, 128, nullptr, 128);
    wcvt_kernel<<<dim3(16, 16), blk, 0, stream>>>(ta_wout, 512, 0, tWO_T, 512, 512, 512, nullptr, 512);
    ln_bf16_kernel<<<dim3(TOK), blk, 0, stream>>>(RT, XN16, ta_ln_w, ta_ln_b);
    gemm_mfma<3><<<dim3(512), blk, 0, stream>>>(XN16, 512, tWQ_T, 512,
        nullptr, Q16t, 512, TOK, 512, 512, QSCL, 4, nullptr, nullptr, nullptr, nullptr, nullptr, nullptr);
    gemm_mfma<3><<<dim3(128), blk, 0, stream>>>(XN16, 512, tWKV_T, 512,
        nullptr, KV16, 128, TOK, 128, 512, 1.0f, 1, nullptr, nullptr, nullptr, nullptr, nullptr, nullptr);
    attn_tp_kernel<<<dim3(1024), blk, 0, stream>>>(Q16t, KV16, ta_null_kv, ta_null_b, TPT, AO16);
    gemm_mfma<0><<<dim3(512), blk, 0, stream>>>(AO16, 512, tWO_T, 512,
        PRJ, nullptr, 512, TOK, 512, 512, 1.0f, 4, nullptr, nullptr, nullptr, nullptr, nullptr, nullptr);
    ln_add_kernel<<<dim3(TOK), blk, 0, stream>>>(PRJ, RT, ta_oln_w, ta_oln_b);
    permute1_dual_kernel<<<dim3(TOK), dim3(128), 0, stream>>>(RT, RES, XN16);

    // ---------------- feed-forward ----------------
    wcvt_kernel<<<dim3(44, 16), blk, 0, stream>>>(ff_win, 2730, 0,   BI,       1024, 512, FFI, nullptr, 1408);
    wcvt_kernel<<<dim3(44, 16), blk, 0, stream>>>(ff_win, 2730, FFI, BI + 512, 1024, 512, FFI, nullptr, 1408);
    wcvt_kernel<<<dim3(16, 43), blk, 0, stream>>>(ff_wout, 512, 0, WFFB, YSLD, FFI, 512, ff_g, 512);
    colsum_kernel<<<dim3(512), dim3(64), 0, stream>>>(WFFB, COLSUM);
    ff_gemm_fused<<<dim3(2816), blk, 0, stream>>>(XN16, BI, YS);
    rowstats_bf16_kernel<<<dim3(TOK), blk, 0, stream>>>(YS, STATS);
    gemm_mfma<5><<<dim3(512), blk, 0, stream>>>(YS, YSLD, WFFB, YSLD,
        nullptr, nullptr, 0, TOK, 512, YSLD, 1.0f, 4, STATS, COLSUM, RES, (float*)d_out, nullptr, nullptr);
}

// Round 8
// 832.730 us; speedup vs baseline: 1.0528x; 1.0273x over previous
//
#include <hip/hip_runtime.h>
#include <math.h>

#define TOK 16384
#define DIMC 512
#define FFI 1365
#define CH1 683
#define YSLD 1376         // YS row stride (bf16 elements, 16B aligned)
#define KVPAD 1056        // padded key count for spatial attn (mult of 8)
#define BSTRIDE 1152      // BIASX row stride (cols: 0=null, 1..1024=keys, rest=mask)
#define MASKB (-30000.f)  // softmax mask bias (bf16-safe, no near-inf)
#define LOG2E 1.4426950408889634f

typedef unsigned int u32;
typedef unsigned short ushort_t;
typedef __attribute__((ext_vector_type(8))) short bf16x8;
typedef __attribute__((ext_vector_type(4))) float f32x4;

__device__ inline ushort_t f2b(float x) {
    u32 u = __float_as_uint(x);
    u32 r = (u + 0x7fffu + ((u >> 16) & 1u)) >> 16;
    return (ushort_t)r;
}
__device__ inline float b2f(ushort_t u) { return __uint_as_float(((u32)u) << 16); }

__device__ inline float exp2_fast(float x) {
    float r;
    asm("v_exp_f32 %0, %1" : "=v"(r) : "v"(x));
    return r;
}

// pack two f32 -> {bf16(hi)<<16 | bf16(lo)}  (RTNE, gfx950)
__device__ inline u32 cvt_pk_bf16(float lo, float hi) {
    u32 r;
    asm("v_cvt_pk_bf16_f32 %0, %1, %2" : "=v"(r) : "v"(lo), "v"(hi));
    return r;
}

__device__ inline void gload_lds16(const void* g, void* l) {
    __builtin_amdgcn_global_load_lds(
        (const __attribute__((address_space(1))) u32*)g,
        (__attribute__((address_space(3))) u32*)l, 16, 0, 0);
}

__device__ inline float gelu_exact(float x) {
    return 0.5f * x * (1.f + erff(x * 0.70710678118654752f));
}

// counted-vmcnt helpers (immediates must be literals in the asm string)
__device__ inline void waitcnt_vm4() {
    asm volatile("s_waitcnt vmcnt(4)" ::: "memory");
    __builtin_amdgcn_sched_barrier(0);
}
__device__ inline void waitcnt_vm0() {
    asm volatile("s_waitcnt vmcnt(0)" ::: "memory");
    __builtin_amdgcn_sched_barrier(0);
}

// ---------------------------------------------------------------- CPB MLP
// 16 rows per block (w1 re-read traffic 1 GB -> 62 MB). FP order preserved.
__global__ __launch_bounds__(256) void cpb_kernel(
    const float* __restrict__ w0, const float* __restrict__ b0,
    const float* __restrict__ w1, const float* __restrict__ b1,
    const float* __restrict__ w2, const float* __restrict__ b2,
    float* __restrict__ table, int mode, int nrows)
{
    __shared__ float t0[16][256];
    __shared__ float t1[16][256];
    int r0 = blockIdx.x * 16;
    int t = threadIdx.x;
    float w0t = w0[t], b0t = b0[t];
    float w0t2 = (mode == 0) ? w0[256 + t] : 0.f;
    #pragma unroll
    for (int rr = 0; rr < 16; ++rr) {
        int r = r0 + rr; if (r >= nrows) r = nrows - 1;
        float c0, c1;
        if (mode == 0) { c0 = (float)(r / 63 - 31); c1 = (float)(r % 63 - 31); }
        else           { c0 = (float)(r - 15);      c1 = 0.f; }
        float a = c0 * w0t + b0t;
        if (mode == 0) a += c1 * w0t2;
        t0[rr][t] = a / (1.f + __expf(-a));
    }
    __syncthreads();
    float b1t = b1[t];
    float acc[16];
    #pragma unroll
    for (int rr = 0; rr < 16; ++rr) acc[rr] = b1t;
    for (int k = 0; k < 256; ++k) {
        float w = w1[k * 256 + t];
        #pragma unroll
        for (int rr = 0; rr < 16; ++rr) acc[rr] += t0[rr][k] * w;
    }
    #pragma unroll
    for (int rr = 0; rr < 16; ++rr) {
        float s = acc[rr];
        t1[rr][t] = s / (1.f + __expf(-s));
    }
    __syncthreads();
    if (t < 128) {
        int rr = t >> 3, oo = t & 7;
        int r = r0 + rr;
        if (r < nrows) {
            float o = b2[oo];
            for (int k = 0; k < 256; ++k) o += t1[rr][k] * w2[k * 8 + oo];
            table[r * 8 + oo] = o;
        }
    }
}

// ------------------------------- materialize spatial bias bf16, padded layout
// NOTE: bias is pre-scaled by LOG2E (softmax uses exp2)
__global__ __launch_bounds__(256) void bias_sp_kernel(
    const float* __restrict__ tab, const float* __restrict__ nullbias,
    ushort_t* __restrict__ out)
{
    int pi = blockIdx.x, h = blockIdx.y;
    int phi = pi >> 5, pwi = pi & 31;
    ushort_t* row = out + ((size_t)h * 1024 + pi) * BSTRIDE;
    for (int c = threadIdx.x; c < BSTRIDE; c += 256) {
        float v;
        if (c == 0) v = nullbias[h];
        else if (c <= 1024) {
            int pj = c - 1;
            int phj = pj >> 5, pwj = pj & 31;
            int idx = (phi - phj + 31) * 63 + (pwi - pwj + 31);
            v = tab[idx * 8 + h];
        } else v = MASKB;
        row[c] = f2b(v * LOG2E);
    }
}

// -------------------------------------------- KP/VT pad+null init. grid 16
__global__ __launch_bounds__(256) void kvinit_kernel(
    const float* __restrict__ nullkv, ushort_t* __restrict__ KP, ushort_t* __restrict__ VT)
{
    int f = blockIdx.x, t = threadIdx.x;
    for (int e = t; e < 32 * 64; e += 256) {
        int rr = e >> 6, d = e & 63;
        int row = (rr == 0) ? 0 : (1024 + rr);
        KP[((size_t)f * KVPAD + row) * 64 + d] = (rr == 0) ? f2b(nullkv[d]) : (ushort_t)0;
    }
    for (int e = t; e < 64 * 32; e += 256) {
        int d = e >> 5, cc = e & 31;
        int col = (cc == 0) ? 0 : (1024 + cc);
        VT[((size_t)f * 64 + d) * KVPAD + col] = (cc == 0) ? f2b(nullkv[64 + d]) : (ushort_t)0;
    }
}

// ---------------- weight convert: W[K][ldw] (col window c0) -> Bt[N][Kp] bf16
// Writes rows n < Nwrite (zeros for n >= Ncols or k >= K) — pad rows are clean.
__global__ __launch_bounds__(256) void wcvt_kernel(
    const float* __restrict__ W, int ldw, int c0,
    ushort_t* __restrict__ Bt, int Kp, int K, int Ncols,
    const float* __restrict__ gv, int Nwrite)
{
    __shared__ float tile[32][33];
    int nb = blockIdx.x * 32, kb = blockIdx.y * 32;
    int tx = threadIdx.x & 31, ty = threadIdx.x >> 5;
    #pragma unroll
    for (int it = 0; it < 4; ++it) {
        int k = kb + ty + it * 8, n = nb + tx;
        float v = (k < K && n < Ncols) ? W[(size_t)k * ldw + c0 + n] : 0.f;
        if (gv && k < K) v *= gv[k];
        tile[ty + it * 8][tx] = v;
    }
    __syncthreads();
    #pragma unroll
    for (int it = 0; it < 4; ++it) {
        int n = nb + ty + it * 8, k = kb + tx;
        if (n < Nwrite && k < Kp) Bt[(size_t)n * Kp + k] = f2b(tile[tx][ty + it * 8]);
    }
}

// ---------------------------------------------------- (C,T) -> (T,C) transpose
__global__ __launch_bounds__(256) void transpose_in_kernel(
    const float* __restrict__ x, float* __restrict__ dst)
{
    __shared__ float tile[32][33];
    int t0b = blockIdx.x * 32, c0b = blockIdx.y * 32;
    int tx = threadIdx.x & 31, ty = threadIdx.x >> 5;
    #pragma unroll
    for (int it = 0; it < 4; ++it) {
        int c = ty + it * 8;
        tile[c][tx] = x[(size_t)(c0b + c) * TOK + t0b + tx];
    }
    __syncthreads();
    #pragma unroll
    for (int it = 0; it < 4; ++it) {
        int tr = ty + it * 8;
        dst[(size_t)(t0b + tr) * DIMC + c0b + tx] = tile[tx][tr];
    }
}

// ---------------------------------------------------------------- LayerNorm → bf16
__global__ __launch_bounds__(256) void ln_bf16_kernel(
    const float* __restrict__ in, ushort_t* __restrict__ out,
    const float* __restrict__ w, const float* __restrict__ b)
{
    __shared__ float r1[4], r2[4];
    size_t base = (size_t)blockIdx.x * DIMC;
    int t = threadIdx.x;
    float x0 = in[base + t], x1 = in[base + 256 + t];
    float s = x0 + x1, s2 = x0 * x0 + x1 * x1;
    #pragma unroll
    for (int o = 32; o > 0; o >>= 1) { s += __shfl_down(s, o, 64); s2 += __shfl_down(s2, o, 64); }
    if ((t & 63) == 0) { r1[t >> 6] = s; r2[t >> 6] = s2; }
    __syncthreads();
    float mean = (r1[0] + r1[1] + r1[2] + r1[3]) * (1.f / 512.f);
    float ex2  = (r2[0] + r2[1] + r2[2] + r2[3]) * (1.f / 512.f);
    float rstd = rsqrtf(ex2 - mean * mean + 1e-5f);
    out[base + t]       = f2b((x0 - mean) * rstd * w[t] + b[t]);
    out[base + 256 + t] = f2b((x1 - mean) * rstd * w[256 + t] + b[256 + t]);
}

// LN(proj f32) + residual in place
__global__ __launch_bounds__(256) void ln_add_kernel(
    const float* __restrict__ proj, float* __restrict__ io,
    const float* __restrict__ w, const float* __restrict__ b)
{
    __shared__ float r1[4], r2[4];
    size_t base = (size_t)blockIdx.x * DIMC;
    int t = threadIdx.x;
    float x0 = proj[base + t], x1 = proj[base + 256 + t];
    float s = x0 + x1, s2 = x0 * x0 + x1 * x1;
    #pragma unroll
    for (int o = 32; o > 0; o >>= 1) { s += __shfl_down(s, o, 64); s2 += __shfl_down(s2, o, 64); }
    if ((t & 63) == 0) { r1[t >> 6] = s; r2[t >> 6] = s2; }
    __syncthreads();
    float mean = (r1[0] + r1[1] + r1[2] + r1[3]) * (1.f / 512.f);
    float ex2  = (r2[0] + r2[1] + r2[2] + r2[3]) * (1.f / 512.f);
    float rstd = rsqrtf(ex2 - mean * mean + 1e-5f);
    io[base + t]       += (x0 - mean) * rstd * w[t] + b[t];
    io[base + 256 + t] += (x1 - mean) * rstd * w[256 + t] + b[256 + t];
}

// spatial->temporal row permute (f32)
__global__ __launch_bounds__(128) void permute0_kernel(
    const float* __restrict__ src, float* __restrict__ dst)
{
    int rd = blockIdx.x;
    int rs = (rd & 15) * 1024 + (rd >> 4);
    ((float4*)(dst + (size_t)rd * DIMC))[threadIdx.x] =
        ((const float4*)(src + (size_t)rs * DIMC))[threadIdx.x];
}

// temporal->spatial permute, dual output f32 + bf16
__global__ __launch_bounds__(128) void permute1_dual_kernel(
    const float* __restrict__ src, float* __restrict__ dst, ushort_t* __restrict__ dstb)
{
    int rd = blockIdx.x;
    int rs = (rd & 1023) * 16 + (rd >> 10);
    float4 v = ((const float4*)(src + (size_t)rs * DIMC))[threadIdx.x];
    ((float4*)(dst + (size_t)rd * DIMC))[threadIdx.x] = v;
    u32 lo = (u32)f2b(v.x) | ((u32)f2b(v.y) << 16);
    u32 hi = (u32)f2b(v.z) | ((u32)f2b(v.w) << 16);
    ((uint2*)(dstb + (size_t)rd * DIMC))[threadIdx.x] = make_uint2(lo, hi);
}

// ---------------------------------------------------------------- MFMA GEMM
// 1-D grid of nx*16*8 blocks. XCD-aware swizzle: xcd = lin&7 owns m-tiles
// [xcd*16, xcd*16+16) for ALL nx n-tiles -> per-XCD L2-resident A band.
// Round-5 measured-best schedule (2-buffer: vmcnt(4) -> s_barrier -> compute
// -> s_barrier -> stage(t+2)) + hoisted incremental pointers.
template<int EPI>
__global__ __launch_bounds__(256) void gemm_mfma(
    const ushort_t* __restrict__ A, int lda,
    const ushort_t* __restrict__ Bt, int Kp,
    float* __restrict__ C, ushort_t* __restrict__ Cb, int ldc,
    int M, int N, int K, float scale, int nx,
    const float* __restrict__ stats, const float* __restrict__ g,
    const float* __restrict__ resid, float* __restrict__ outT,
    ushort_t* __restrict__ KPo, ushort_t* __restrict__ VTo)
{
    __shared__ __align__(16) ushort_t As[2][4 * 128 * 8];
    __shared__ __align__(16) ushort_t Bs[2][4 * 128 * 8];
    int lin = blockIdx.x;
    int xcd = lin & 7, idx = lin >> 3;
    int m0 = (xcd * 16 + (idx & 15)) * 128;
    int n0 = (idx >> 4) * 128;
    int tid = threadIdx.x, lane = tid & 63, wid = tid >> 6;
    int wy = wid >> 1, wx = wid & 1, quad = lane >> 4, l16 = lane & 15;
    bool bfull = (n0 + 128 <= N);
    f32x4 acc[4][4];
    #pragma unroll
    for (int i = 0; i < 4; ++i)
        #pragma unroll
        for (int j = 0; j < 4; ++j) { acc[i][j][0]=0.f; acc[i][j][1]=0.f; acc[i][j][2]=0.f; acc[i][j][3]=0.f; }

    if (bfull) {
        int NT = K >> 5;
        int c0 = wid * 128 + lane, c1 = wid * 128 + 64 + lane;
        const ushort_t* gA0 = A + (size_t)(m0 + (c0 & 127)) * lda + (c0 >> 7) * 8;
        const ushort_t* gA1 = A + (size_t)(m0 + (c1 & 127)) * lda + (c1 >> 7) * 8;
        const ushort_t* gB0 = Bt + (size_t)(n0 + (c0 & 127)) * Kp + (c0 >> 7) * 8;
        const ushort_t* gB1 = Bt + (size_t)(n0 + (c1 & 127)) * Kp + (c1 >> 7) * 8;
        const int lo0 = (wid * 128) * 8, lo1 = (wid * 128 + 64) * 8;
        auto stage = [&](int buf) {
            gload_lds16(gA0, &As[buf][lo0]);
            gload_lds16(gA1, &As[buf][lo1]);
            gload_lds16(gB0, &Bs[buf][lo0]);
            gload_lds16(gB1, &Bs[buf][lo1]);
            gA0 += 32; gA1 += 32; gB0 += 32; gB1 += 32;
        };
        stage(0);
        if (NT > 1) stage(1);
        for (int t = 0; t < NT; ++t) {
            if (t + 1 < NT) waitcnt_vm4(); else waitcnt_vm0();
            __builtin_amdgcn_s_barrier();
            int cur = t & 1;
            bf16x8 af[4], bfr[4];
            #pragma unroll
            for (int i = 0; i < 4; ++i) af[i] = *(bf16x8*)&As[cur][(quad * 128 + wy * 64 + i * 16 + l16) * 8];
            #pragma unroll
            for (int j = 0; j < 4; ++j) bfr[j] = *(bf16x8*)&Bs[cur][(quad * 128 + wx * 64 + j * 16 + l16) * 8];
            #pragma unroll
            for (int i = 0; i < 4; ++i)
                #pragma unroll
                for (int j = 0; j < 4; ++j)
                    acc[i][j] = __builtin_amdgcn_mfma_f32_16x16x32_bf16(af[i], bfr[j], acc[i][j], 0, 0, 0);
            if (t + 2 < NT) {
                __builtin_amdgcn_s_barrier();
                stage(cur);
            }
        }
    } else {
        // conservative fallback (not taken by current launches)
        for (int k0 = 0; k0 < K; k0 += 32) {
            if (k0) __syncthreads();
            #pragma unroll
            for (int r = 0; r < 2; ++r) {
                int c = wid * 128 + r * 64 + lane;
                const ushort_t* src = A + (size_t)(m0 + (c & 127)) * lda + k0 + (c >> 7) * 8;
                gload_lds16(src, &As[0][(wid * 128 + r * 64) * 8]);
            }
            #pragma unroll
            for (int r = 0; r < 2; ++r) {
                int c = tid + r * 256;
                int kg = c >> 7, nloc = c & 127;
                bf16x8 v;
                if (n0 + nloc < N) v = *(const bf16x8*)(Bt + (size_t)(n0 + nloc) * Kp + k0 + kg * 8);
                else { for (int e = 0; e < 8; ++e) v[e] = 0; }
                *(bf16x8*)&Bs[0][c * 8] = v;
            }
            __syncthreads();
            bf16x8 af[4], bfr[4];
            #pragma unroll
            for (int i = 0; i < 4; ++i) af[i] = *(bf16x8*)&As[0][(quad * 128 + wy * 64 + i * 16 + l16) * 8];
            #pragma unroll
            for (int j = 0; j < 4; ++j) bfr[j] = *(bf16x8*)&Bs[0][(quad * 128 + wx * 64 + j * 16 + l16) * 8];
            #pragma unroll
            for (int i = 0; i < 4; ++i)
                #pragma unroll
                for (int j = 0; j < 4; ++j)
                    acc[i][j] = __builtin_amdgcn_mfma_f32_16x16x32_bf16(af[i], bfr[j], acc[i][j], 0, 0, 0);
        }
    }
    #pragma unroll
    for (int i = 0; i < 4; ++i) {
        #pragma unroll
        for (int j = 0; j < 4; ++j) {
            #pragma unroll
            for (int r = 0; r < 4; ++r) {
                int m = m0 + wy * 64 + i * 16 + quad * 4 + r;
                int n = n0 + wx * 64 + j * 16 + l16;
                if (n >= N) continue;
                float v = acc[i][j][r] * scale;
                if (EPI == 0) {
                    C[(size_t)m * ldc + n] = v;
                } else if (EPI == 3) {
                    Cb[(size_t)m * ldc + n] = f2b(v);
                } else if (EPI == 4) {
                    int frame = m >> 10, tt = m & 1023;
                    if (n < 64) KPo[((size_t)frame * KVPAD + 1 + tt) * 64 + n] = f2b(v);
                    else        VTo[((size_t)frame * 64 + (n - 64)) * KVPAD + 1 + tt] = f2b(v);
                } else if (EPI == 5) {
                    float s0 = stats[2 * m], s1 = stats[2 * m + 1];
                    outT[(size_t)n * TOK + m] = v * s1 - s0 * g[n] + resid[(size_t)m * DIMC + n];
                }
            }
        }
    }
}

// ------------------------------------------- fused FF front GEMM (a & gate)
// 128m x 64n dual-output tile -> acc = 64 AGPR/thread. B from interleaved
// BI[2816][512] via pure global_load_lds. Grid 2816 = 8 XCD x 16 m x 22 n.
// Round-5 schedule + hoisted incremental pointers.
__global__ __launch_bounds__(256) void ff_gemm_fused(
    const ushort_t* __restrict__ A,
    const ushort_t* __restrict__ BI,
    ushort_t* __restrict__ YS)
{
    __shared__ __align__(16) ushort_t As[2][4 * 128 * 8];
    __shared__ __align__(16) ushort_t Bs[2][4 * 2 * 64 * 8];
    int lin = blockIdx.x;
    int xcd = lin & 7, idx = lin >> 3;
    int m0 = (xcd * 16 + (idx & 15)) * 128;
    int n0 = (idx >> 4) * 64;
    int tid = threadIdx.x, lane = tid & 63, wid = tid >> 6;
    int wy = wid >> 1, wx = wid & 1, quad = lane >> 4, l16 = lane & 15;
    f32x4 aA[4][2], aG[4][2];
    #pragma unroll
    for (int i = 0; i < 4; ++i)
        #pragma unroll
        for (int j = 0; j < 2; ++j) {
            aA[i][j][0]=0.f; aA[i][j][1]=0.f; aA[i][j][2]=0.f; aA[i][j][3]=0.f;
            aG[i][j][0]=0.f; aG[i][j][1]=0.f; aG[i][j][2]=0.f; aG[i][j][3]=0.f;
        }

    int c0 = wid * 128 + lane, c1 = wid * 128 + 64 + lane;
    const ushort_t* gA0 = A + (size_t)(m0 + (c0 & 127)) * 512 + (c0 >> 7) * 8;
    const ushort_t* gA1 = A + (size_t)(m0 + (c1 & 127)) * 512 + (c1 >> 7) * 8;
    const ushort_t* gB0 = BI + (size_t)((n0 + lane) * 2 + 0) * 512 + wid * 8;
    const ushort_t* gB1 = BI + (size_t)((n0 + lane) * 2 + 1) * 512 + wid * 8;
    const int lo0 = (wid * 128) * 8, lo1 = (wid * 128 + 64) * 8;
    auto stage = [&](int buf) {
        gload_lds16(gA0, &As[buf][lo0]);
        gload_lds16(gA1, &As[buf][lo1]);
        gload_lds16(gB0, &Bs[buf][lo0]);
        gload_lds16(gB1, &Bs[buf][lo1]);
        gA0 += 32; gA1 += 32; gB0 += 32; gB1 += 32;
    };

    stage(0); stage(1);
    for (int t = 0; t < 16; ++t) {
        if (t + 1 < 16) waitcnt_vm4(); else waitcnt_vm0();
        __builtin_amdgcn_s_barrier();
        int cur = t & 1;
        bf16x8 af[4], ba[2], bg[2];
        #pragma unroll
        for (int i = 0; i < 4; ++i) af[i] = *(bf16x8*)&As[cur][(quad * 128 + wy * 64 + i * 16 + l16) * 8];
        #pragma unroll
        for (int j = 0; j < 2; ++j) {
            int nn = wx * 32 + j * 16 + l16;
            ba[j] = *(bf16x8*)&Bs[cur][(quad * 128 + nn) * 8];
            bg[j] = *(bf16x8*)&Bs[cur][(quad * 128 + 64 + nn) * 8];
        }
        #pragma unroll
        for (int i = 0; i < 4; ++i)
            #pragma unroll
            for (int j = 0; j < 2; ++j) {
                aA[i][j] = __builtin_amdgcn_mfma_f32_16x16x32_bf16(af[i], ba[j], aA[i][j], 0, 0, 0);
                aG[i][j] = __builtin_amdgcn_mfma_f32_16x16x32_bf16(af[i], bg[j], aG[i][j], 0, 0, 0);
            }
        if (t + 2 < 16) {
            __builtin_amdgcn_s_barrier();
            stage(cur);
        }
    }
    #pragma unroll
    for (int i = 0; i < 4; ++i) {
        #pragma unroll
        for (int j = 0; j < 2; ++j) {
            #pragma unroll
            for (int r = 0; r < 4; ++r) {
                int m = m0 + wy * 64 + i * 16 + quad * 4 + r;
                int n = n0 + wx * 32 + j * 16 + l16;
                if (n >= FFI) {
                    if (n < YSLD) YS[(size_t)m * YSLD + n] = 0;   // zero pad cols
                    continue;
                }
                float v = aA[i][j][r] * gelu_exact(aG[i][j][r]);
                int dr = (n < CH1) ? m : m + 1024;
                if (dr < TOK) YS[(size_t)dr * YSLD + n] = f2b(v);
                if (n >= CH1 && m < 1024) YS[(size_t)m * YSLD + n] = 0;
            }
        }
    }
}

// --------------------------------------------------- spatial attention (MFMA flash)
// ROUND-17: QBLK=32 — each block computes TWO adjacent q-tiles (32 q-rows)
// against the same staged K/V tile. Staging + barriers per output halve;
// MFMA per k-tile per wave doubles (72 -> 144). Grid 1024 -> 512 =
// 8 xcd x 4 q-pairs x 16 frames. Softmax: no online-max (bounded base-2
// logits), row-sum via MFMA ones-column, cvt_pk pack, ds_bpermute transpose.
__global__ __launch_bounds__(256) void attn_sp_mfma(
    const ushort_t* __restrict__ Q,      // [16384][512] bf16 pre-scaled by 0.125*log2e
    const ushort_t* __restrict__ KP,     // [16][1056][64]
    const ushort_t* __restrict__ VT,     // [16][64][1056]
    const ushort_t* __restrict__ BIASX,  // [8][1024][1152], pre-scaled by log2e
    ushort_t* __restrict__ O)            // [16384][512] bf16
{
    __shared__ __align__(16) ushort_t Ks[128 * 64];
    __shared__ __align__(16) ushort_t Vs[64 * 128];
    int lin = blockIdx.x;
    int xcd = lin & 7, idx = lin >> 3;
    int qp = idx & 3;            // q-pair within this xcd's band
    int frame = idx >> 2;        // 16 frames
    int q0 = xcd * 128 + qp * 32;
    int tid = threadIdx.x, lane = tid & 63, wid = tid >> 6;
    int quad = lane >> 4, l16 = lane & 15;

    bf16x8 aQ[2][2][2];                 // [head][qtile][ks]
    const ushort_t* brow[2][2];
    #pragma unroll
    for (int i = 0; i < 2; ++i) {
        int h = wid * 2 + i;
        #pragma unroll
        for (int qq = 0; qq < 2; ++qq) {
            const ushort_t* qptr = Q + (size_t)(frame * 1024 + q0 + qq * 16 + l16) * 512 + h * 64 + quad * 8;
            aQ[i][qq][0] = *(const bf16x8*)qptr;
            aQ[i][qq][1] = *(const bf16x8*)(qptr + 32);
            brow[i][qq] = BIASX + ((size_t)h * 1024 + q0 + qq * 16 + l16) * BSTRIDE;
        }
    }
    f32x4 Oc[2][2][4];                  // [head][qtile][nt]
    f32x4 Oc4[2][2];                    // row-sum accumulator (ones-column PV)
    #pragma unroll
    for (int i = 0; i < 2; ++i)
        #pragma unroll
        for (int qq = 0; qq < 2; ++qq) {
            #pragma unroll
            for (int nt = 0; nt < 4; ++nt) { Oc[i][qq][nt][0]=0.f; Oc[i][qq][nt][1]=0.f; Oc[i][qq][nt][2]=0.f; Oc[i][qq][nt][3]=0.f; }
            Oc4[i][qq][0]=0.f; Oc4[i][qq][1]=0.f; Oc4[i][qq][2]=0.f; Oc4[i][qq][3]=0.f;
        }
    bf16x8 vones;
    #pragma unroll
    for (int e = 0; e < 8; ++e) vones[e] = (short)0x3F80;   // bf16 1.0

    // bpermute byte-indices for the in-register P transpose:
    // target (quad,l16) word w pulls from lane (2*(quad&1)+(w>>1))*16 + l16
    int idxA = (((quad & 1) * 32) + l16) * 4;   // w = 0,1
    int idxB = idxA + 64;                       // w = 2,3
    bool hiq = (quad >= 2);                     // selects j = 2ks+1

    for (int jt = 0; jt < 9; ++jt) {
        __syncthreads();
        #pragma unroll
        for (int r = 0; r < 4; ++r) {
            int L = wid * 256 + r * 64 + lane;
            int c = L >> 3, gp = L & 7, gg = gp ^ (c & 7);
            int jj = jt * 128 + c; if (jj > KVPAD - 1) jj = KVPAD - 1;
            gload_lds16(KP + ((size_t)frame * KVPAD + jj) * 64 + gg * 8, &Ks[(wid * 256 + r * 64) * 8]);
        }
        #pragma unroll
        for (int r = 0; r < 4; ++r) {
            int L = wid * 256 + r * 64 + lane;
            int d = L >> 4, cgp = L & 15;
            int cg = (cgp & 8) | ((cgp & 7) ^ (d & 7));
            int col = jt * 128 + cg * 8; if (col > KVPAD - 8) col = KVPAD - 8;
            gload_lds16(VT + ((size_t)frame * 64 + d) * KVPAD + col, &Vs[(wid * 256 + r * 64) * 8]);
        }
        __syncthreads();

        #pragma unroll
        for (int i = 0; i < 2; ++i) {
            #pragma unroll
            for (int qq = 0; qq < 2; ++qq) {
                // ---- QK^T for this head/qtile
                f32x4 S[8];
                #pragma unroll
                for (int j = 0; j < 8; ++j) { S[j][0]=0.f; S[j][1]=0.f; S[j][2]=0.f; S[j][3]=0.f; }
                __builtin_amdgcn_s_setprio(1);
                #pragma unroll
                for (int j = 0; j < 8; ++j) {
                    int c = j * 16 + l16;
                    #pragma unroll
                    for (int ks = 0; ks < 2; ++ks) {
                        bf16x8 kb = *(bf16x8*)&Ks[(c * 8 + ((ks * 4 + quad) ^ (c & 7))) * 8];
                        S[j] = __builtin_amdgcn_mfma_f32_16x16x32_bf16(kb, aQ[i][qq][ks], S[j], 0, 0, 0);
                    }
                }
                __builtin_amdgcn_s_setprio(0);
                // ---- bias add + direct exp2 (mask underflows to 0)
                #pragma unroll
                for (int j = 0; j < 8; ++j) {
                    int kbase = jt * 128 + j * 16 + quad * 4;
                    uint2 bv = *(const uint2*)(brow[i][qq] + kbase);
                    S[j][0] = exp2_fast(S[j][0] + __uint_as_float(bv.x << 16));
                    S[j][1] = exp2_fast(S[j][1] + __uint_as_float(bv.x & 0xffff0000u));
                    S[j][2] = exp2_fast(S[j][2] + __uint_as_float(bv.y << 16));
                    S[j][3] = exp2_fast(S[j][3] + __uint_as_float(bv.y & 0xffff0000u));
                }
                // ---- pack (cvt_pk) + in-register transpose (ds_bpermute) + PV
                __builtin_amdgcn_s_setprio(1);
                #pragma unroll
                for (int ks = 0; ks < 4; ++ks) {
                    int jl = 2 * ks, jh = 2 * ks + 1;
                    u32 pxl = cvt_pk_bf16(S[jl][0], S[jl][1]);
                    u32 pyl = cvt_pk_bf16(S[jl][2], S[jl][3]);
                    u32 pxh = cvt_pk_bf16(S[jh][0], S[jh][1]);
                    u32 pyh = cvt_pk_bf16(S[jh][2], S[jh][3]);
                    u32 a0 = (u32)__builtin_amdgcn_ds_bpermute(idxA, (int)pxl);
                    u32 a1 = (u32)__builtin_amdgcn_ds_bpermute(idxA, (int)pxh);
                    u32 b0 = (u32)__builtin_amdgcn_ds_bpermute(idxA, (int)pyl);
                    u32 b1 = (u32)__builtin_amdgcn_ds_bpermute(idxA, (int)pyh);
                    u32 c0 = (u32)__builtin_amdgcn_ds_bpermute(idxB, (int)pxl);
                    u32 c1 = (u32)__builtin_amdgcn_ds_bpermute(idxB, (int)pxh);
                    u32 d0 = (u32)__builtin_amdgcn_ds_bpermute(idxB, (int)pyl);
                    u32 d1 = (u32)__builtin_amdgcn_ds_bpermute(idxB, (int)pyh);
                    union { u32 w[4]; bf16x8 v; } pa;
                    pa.w[0] = hiq ? a1 : a0;
                    pa.w[1] = hiq ? b1 : b0;
                    pa.w[2] = hiq ? c1 : c0;
                    pa.w[3] = hiq ? d1 : d0;
                    #pragma unroll
                    for (int nt = 0; nt < 4; ++nt) {
                        int d = nt * 16 + l16;
                        int cg = ks * 4 + quad;
                        int phys = (cg & 8) | ((cg & 7) ^ (d & 7));
                        bf16x8 vb = *(bf16x8*)&Vs[(d * 16 + phys) * 8];
                        Oc[i][qq][nt] = __builtin_amdgcn_mfma_f32_16x16x32_bf16(pa.v, vb, Oc[i][qq][nt], 0, 0, 0);
                    }
                    // ones-column: accumulates row-sum of P in matching layout
                    Oc4[i][qq] = __builtin_amdgcn_mfma_f32_16x16x32_bf16(pa.v, vones, Oc4[i][qq], 0, 0, 0);
                }
                __builtin_amdgcn_s_setprio(0);
            }
        }
    }
    #pragma unroll
    for (int i = 0; i < 2; ++i) {
        int h = wid * 2 + i;
        #pragma unroll
        for (int qq = 0; qq < 2; ++qq) {
            #pragma unroll
            for (int r = 0; r < 4; ++r) {
                float linv = 1.f / Oc4[i][qq][r];   // same (q,row) layout as Oc — no shuffle
                int ql = qq * 16 + quad * 4 + r;
                #pragma unroll
                for (int nt = 0; nt < 4; ++nt) {
                    int d = nt * 16 + l16;
                    O[(size_t)(frame * 1024 + q0 + ql) * 512 + h * 64 + d] = f2b(Oc[i][qq][nt][r] * linv);
                }
            }
        }
    }
}

// ---------------------------------------------------------------- temporal attention
// ROUND-17: padded LDS (qs 516, ks/vs 68) to break power-of-2 row-stride
// bank conflicts on the float4 reads (17-way -> <=2-way). FP order preserved.
__global__ __launch_bounds__(256) void attn_tp_kernel(
    const ushort_t* __restrict__ q, const ushort_t* __restrict__ kv,
    const float* __restrict__ nullkv, const float* __restrict__ nullbias,
    const float* __restrict__ table, ushort_t* __restrict__ out)
{
    __shared__ float qs[16][516];
    __shared__ float ks[17][68];
    __shared__ float vs[17][68];
    __shared__ float sc[8][16][17];
    int b = blockIdx.x;
    int t = threadIdx.x;
    for (int e = t; e < 16 * 64; e += 256) {
        int f = e >> 6, c8 = e & 63;
        uint4 v = *(const uint4*)(q + (size_t)(b * 16 + f) * 512 + c8 * 8);
        float* dst = &qs[f][c8 * 8];
        dst[0] = b2f((ushort_t)(v.x & 0xffffu)); dst[1] = b2f((ushort_t)(v.x >> 16));
        dst[2] = b2f((ushort_t)(v.y & 0xffffu)); dst[3] = b2f((ushort_t)(v.y >> 16));
        dst[4] = b2f((ushort_t)(v.z & 0xffffu)); dst[5] = b2f((ushort_t)(v.z >> 16));
        dst[6] = b2f((ushort_t)(v.w & 0xffffu)); dst[7] = b2f((ushort_t)(v.w >> 16));
    }
    for (int e = t; e < 17 * 64; e += 256) {
        int j = e >> 6, d = e & 63;
        ks[j][d] = (j == 0) ? nullkv[d]      : b2f(kv[(size_t)(b * 16 + j - 1) * 128 + d]);
        vs[j][d] = (j == 0) ? nullkv[64 + d] : b2f(kv[(size_t)(b * 16 + j - 1) * 128 + 64 + d]);
    }
    __syncthreads();
    for (int e = t; e < 8 * 16 * 17; e += 256) {
        int h = e / 272, rem = e - h * 272;
        int i = rem / 17, j = rem - i * 17;
        float acc = 0.f;
        const float4* qp = (const float4*)&qs[i][h * 64];
        const float4* kp = (const float4*)&ks[j][0];
        #pragma unroll
        for (int d4 = 0; d4 < 16; ++d4) {
            float4 qv = qp[d4], kv4 = kp[d4];
            acc += qv.x * kv4.x;
            acc += qv.y * kv4.y;
            acc += qv.z * kv4.z;
            acc += qv.w * kv4.w;
        }
        float bias = ((j == 0) ? nullbias[h] : table[(i - (j - 1) + 15) * 8 + h]) * LOG2E;
        sc[h][i][j] = acc + bias;   // q pre-scaled by 0.125*log2e -> base-2 logits
    }
    __syncthreads();
    if (t < 128) {
        int h = t >> 4, i = t & 15;
        float mx = -1e30f;
        for (int j = 0; j < 17; ++j) mx = fmaxf(mx, sc[h][i][j]);
        float s = 0.f;
        for (int j = 0; j < 17; ++j) { float p = exp2_fast(sc[h][i][j] - mx); sc[h][i][j] = p; s += p; }
        float inv = 1.f / s;
        for (int j = 0; j < 17; ++j) sc[h][i][j] *= inv;
    }
    __syncthreads();
    for (int e = t; e < 16 * 128; e += 256) {
        int i = e >> 7, c4 = e & 127;
        int h = c4 >> 4, d4 = c4 & 15;
        float ax = 0.f, ay = 0.f, az = 0.f, aw = 0.f;
        #pragma unroll
        for (int j = 0; j < 17; ++j) {
            float p = sc[h][i][j];
            float4 vv = *(const float4*)&vs[j][d4 * 4];
            ax += p * vv.x; ay += p * vv.y; az += p * vv.z; aw += p * vv.w;
        }
        u32 lo = (u32)f2b(ax) | ((u32)f2b(ay) << 16);
        u32 hi = (u32)f2b(az) | ((u32)f2b(aw) << 16);
        *(uint2*)(out + (size_t)(b * 16 + i) * 512 + c4 * 4) = make_uint2(lo, hi);
    }
}

// ------------------------- FF shift-LN row stats from bf16 YS: (mean*rstd, rstd)
__global__ __launch_bounds__(256) void rowstats_bf16_kernel(
    const ushort_t* __restrict__ YS, float* __restrict__ stats)
{
    __shared__ float r1[4], r2[4];
    int r = blockIdx.x, t = threadIdx.x;
    const ushort_t* row = YS + (size_t)r * YSLD;
    float s = 0.f, s2 = 0.f;
    for (int c = t; c < FFI; c += 256) {
        float v = b2f(row[c]);
        s += v; s2 += v * v;
    }
    #pragma unroll
    for (int o = 32; o > 0; o >>= 1) { s += __shfl_down(s, o, 64); s2 += __shfl_down(s2, o, 64); }
    if ((t & 63) == 0) { r1[t >> 6] = s; r2[t >> 6] = s2; }
    __syncthreads();
    float S  = r1[0] + r1[1] + r1[2] + r1[3];
    float S2 = r2[0] + r2[1] + r2[2] + r2[3];
    float mean = S * (1.f / 1365.f);
    float var  = S2 * (1.f / 1365.f) - mean * mean;
    float rstd = rsqrtf(fmaxf(var, 1e-5f));
    if (t == 0) { stats[2 * r] = mean * rstd; stats[2 * r + 1] = rstd; }
}

// --------------------- colsum[n] = sum_k W'[n][k]  (rows of converted W')
__global__ __launch_bounds__(64) void colsum_kernel(
    const ushort_t* __restrict__ Wt, float* __restrict__ colsum)
{
    int n = blockIdx.x, t = threadIdx.x;
    const ushort_t* row = Wt + (size_t)n * YSLD;
    float s = 0.f;
    for (int k = t; k < YSLD; k += 64) s += b2f(row[k]);
    #pragma unroll
    for (int o = 32; o > 0; o >>= 1) s += __shfl_down(s, o, 64);
    if (t == 0) colsum[n] = s;
}

// ================================================================ launcher
extern "C" void kernel_launch(void* const* d_in, const int* in_sizes, int n_in,
                              void* d_out, int out_size, void* d_ws, size_t ws_size,
                              hipStream_t stream)
{
    const float* x          = (const float*)d_in[0];
    const float* sa_ln_w    = (const float*)d_in[1];
    const float* sa_ln_b    = (const float*)d_in[2];
    const float* sa_wq      = (const float*)d_in[3];
    const float* sa_wkv     = (const float*)d_in[4];
    const float* sa_null_kv = (const float*)d_in[5];
    const float* sa_null_b  = (const float*)d_in[6];
    const float* sa_wout    = (const float*)d_in[7];
    const float* sa_oln_w   = (const float*)d_in[8];
    const float* sa_oln_b   = (const float*)d_in[9];
    const float* ta_ln_w    = (const float*)d_in[10];
    const float* ta_ln_b    = (const float*)d_in[11];
    const float* ta_wq      = (const float*)d_in[12];
    const float* ta_wkv     = (const float*)d_in[13];
    const float* ta_null_kv = (const float*)d_in[14];
    const float* ta_null_b  = (const float*)d_in[15];
    const float* ta_wout    = (const float*)d_in[16];
    const float* ta_oln_w   = (const float*)d_in[17];
    const float* ta_oln_b   = (const float*)d_in[18];
    const float* sp_w0      = (const float*)d_in[19];
    const float* sp_b0      = (const float*)d_in[20];
    const float* sp_w1      = (const float*)d_in[21];
    const float* sp_b1      = (const float*)d_in[22];
    const float* sp_w2      = (const float*)d_in[23];
    const float* sp_b2      = (const float*)d_in[24];
    const float* tp_w0      = (const float*)d_in[25];
    const float* tp_b0      = (const float*)d_in[26];
    const float* tp_w1      = (const float*)d_in[27];
    const float* tp_b1      = (const float*)d_in[28];
    const float* tp_w2      = (const float*)d_in[29];
    const float* tp_b2      = (const float*)d_in[30];
    const float* ff_win     = (const float*)d_in[31];
    const float* ff_g       = (const float*)d_in[32];
    const float* ff_wout    = (const float*)d_in[33];

    char* ws = (char*)d_ws;
    // regions (bytes)
    float*    RES   = (float*)(ws + 0);                        // residual, spatial layout
    ushort_t* XN16  = (ushort_t*)(ws + 33554432);              // xn / x2 bf16
    ushort_t* Q16   = (ushort_t*)(ws + 50331648);              // spatial Q bf16 (spatial phase)
    float*    RT    = (float*)(ws + 50331648);                 // temporal residual f32 (temporal phase)
    ushort_t* YS    = (ushort_t*)(ws + 50331648);              // FF shifted act bf16 [16384][1376]
    ushort_t* WSA   = (ushort_t*)(ws + 67108864);              // spatial weights (dead by FF)
    ushort_t* KP    = (ushort_t*)(ws + 83886080);              // 16x1056x64 bf16 (spatial)
    ushort_t* VTb   = (ushort_t*)(ws + 86048768);              // 16x64x1056 bf16 (spatial)
    ushort_t* KV16  = (ushort_t*)(ws + 83886080);              // temporal KV bf16
    ushort_t* WTA   = (ushort_t*)(ws + 90439680);              // temporal weights
    ushort_t* AO16  = (ushort_t*)(ws + 92274688);              // attn out bf16 (dead by FF)
    ushort_t* BI    = (ushort_t*)(ws + 96468992);              // FF interleaved W [2816][512]
    ushort_t* WFFB  = (ushort_t*)(ws + 99352576);              // W' = (ff_wout*g)^T [512][1376]
    ushort_t* BIAS16= (ushort_t*)(ws + 109051904);             // spatial bias bf16 (PRJ region)
    float*    PRJ   = (float*)(ws + 109051904);                // proj out f32
    ushort_t* Q16t  = (ushort_t*)(ws + 109051904);             // temporal Q bf16
    float*    STATS = (float*)(ws + 142606336);                // 16384 x (mean*rstd, rstd)
    float*    SPT   = (float*)(ws + 142737408);                // spatial CPB table (spatial phase)
    float*    COLSUM= (float*)(ws + 142737408);                // colsum[512] (FF phase, dead SPT)
    float*    TPT   = (float*)(ws + 142864448);

    ushort_t* WQ_T  = WSA;                 // [512][512]
    ushort_t* WKV_T = WSA + 262144;        // [128][512]
    ushort_t* WO_T  = WSA + 327680;        // [512][512]
    ushort_t* tWQ_T  = WTA;
    ushort_t* tWKV_T = WTA + 262144;
    ushort_t* tWO_T  = WTA + 327680;

    dim3 blk(256);
    const float QSCL = 0.125f * LOG2E;   // fold log2e into Q so softmax is exp2

    // bias tables
    cpb_kernel<<<dim3(249), blk, 0, stream>>>(sp_w0, sp_b0, sp_w1, sp_b1, sp_w2, sp_b2, SPT, 0, 3969);
    cpb_kernel<<<dim3(2),   blk, 0, stream>>>(tp_w0, tp_b0, tp_w1, tp_b1, tp_w2, tp_b2, TPT, 1, 31);
    bias_sp_kernel<<<dim3(1024, 8), blk, 0, stream>>>(SPT, sa_null_b, BIAS16);
    kvinit_kernel<<<dim3(16), blk, 0, stream>>>(sa_null_kv, KP, VTb);

    // ---------------- spatial ----------------
    wcvt_kernel<<<dim3(16, 16), blk, 0, stream>>>(sa_wq, 512, 0, WQ_T, 512, 512, 512, nullptr, 512);
    wcvt_kernel<<<dim3(4, 16),  blk, 0, stream>>>(sa_wkv, 128, 0, WKV_T, 512, 512, 128, nullptr, 128);
    wcvt_kernel<<<dim3(16, 16), blk, 0, stream>>>(sa_wout, 512, 0, WO_T, 512, 512, 512, nullptr, 512);
    transpose_in_kernel<<<dim3(512, 16), blk, 0, stream>>>(x, RES);
    ln_bf16_kernel<<<dim3(TOK), blk, 0, stream>>>(RES, XN16, sa_ln_w, sa_ln_b);
    gemm_mfma<3><<<dim3(512), blk, 0, stream>>>(XN16, 512, WQ_T, 512,
        nullptr, Q16, 512, TOK, 512, 512, QSCL, 4, nullptr, nullptr, nullptr, nullptr, nullptr, nullptr);
    gemm_mfma<4><<<dim3(128), blk, 0, stream>>>(XN16, 512, WKV_T, 512,
        nullptr, nullptr, 0, TOK, 128, 512, 1.0f, 1, nullptr, nullptr, nullptr, nullptr, KP, VTb);
    attn_sp_mfma<<<dim3(512), blk, 0, stream>>>(Q16, KP, VTb, BIAS16, AO16);
    gemm_mfma<0><<<dim3(512), blk, 0, stream>>>(AO16, 512, WO_T, 512,
        PRJ, nullptr, 512, TOK, 512, 512, 1.0f, 4, nullptr, nullptr, nullptr, nullptr, nullptr, nullptr);
    ln_add_kernel<<<dim3(TOK), blk, 0, stream>>>(PRJ, RES, sa_oln_w, sa_oln_b);

    // ---------------- temporal ----------------
    permute0_kernel<<<dim3(TOK), dim3(128), 0, stream>>>(RES, RT);
    wcvt_kernel<<<dim3(16, 16), blk, 0, stream>>>(ta_wq, 512, 0, tWQ_T, 512, 512, 512, nullptr, 512);
    wcvt_kernel<<<dim3(4, 16),  blk, 0, stream>>>(ta_wkv, 128, 0, tWKV_T, 512, 512, 128, nullptr, 128);
    wcvt_kernel<<<dim3(16, 16), blk, 0, stream>>>(ta_wout, 512, 0, tWO_T, 512, 512, 512, nullptr, 512);
    ln_bf16_kernel<<<dim3(TOK), blk, 0, stream>>>(RT, XN16, ta_ln_w, ta_ln_b);
    gemm_mfma<3><<<dim3(512), blk, 0, stream>>>(XN16, 512, tWQ_T, 512,
        nullptr, Q16t, 512, TOK, 512, 512, QSCL, 4, nullptr, nullptr, nullptr, nullptr, nullptr, nullptr);
    gemm_mfma<3><<<dim3(128), blk, 0, stream>>>(XN16, 512, tWKV_T, 512,
        nullptr, KV16, 128, TOK, 128, 512, 1.0f, 1, nullptr, nullptr, nullptr, nullptr, nullptr, nullptr);
    attn_tp_kernel<<<dim3(1024), blk, 0, stream>>>(Q16t, KV16, ta_null_kv, ta_null_b, TPT, AO16);
    gemm_mfma<0><<<dim3(512), blk, 0, stream>>>(AO16, 512, tWO_T, 512,
        PRJ, nullptr, 512, TOK, 512, 512, 1.0f, 4, nullptr, nullptr, nullptr, nullptr, nullptr, nullptr);
    ln_add_kernel<<<dim3(TOK), blk, 0, stream>>>(PRJ, RT, ta_oln_w, ta_oln_b);
    permute1_dual_kernel<<<dim3(TOK), dim3(128), 0, stream>>>(RT, RES, XN16);

    // ---------------- feed-forward ----------------
    wcvt_kernel<<<dim3(44, 16), blk, 0, stream>>>(ff_win, 2730, 0,   BI,       1024, 512, FFI, nullptr, 1408);
    wcvt_kernel<<<dim3(44, 16), blk, 0, stream>>>(ff_win, 2730, FFI, BI + 512, 1024, 512, FFI, nullptr, 1408);
    wcvt_kernel<<<dim3(16, 43), blk, 0, stream>>>(ff_wout, 512, 0, WFFB, YSLD, FFI, 512, ff_g, 512);
    colsum_kernel<<<dim3(512), dim3(64), 0, stream>>>(WFFB, COLSUM);
    ff_gemm_fused<<<dim3(2816), blk, 0, stream>>>(XN16, BI, YS);
    rowstats_bf16_kernel<<<dim3(TOK), blk, 0, stream>>>(YS, STATS);
    gemm_mfma<5><<<dim3(512), blk, 0, stream>>>(YS, YSLD, WFFB, YSLD,
        nullptr, nullptr, 0, TOK, 512, YSLD, 1.0f, 4, STATS, COLSUM, RES, (float*)d_out, nullptr, nullptr);
}

// Round 9
// 800.566 us; speedup vs baseline: 1.0951x; 1.0402x over previous
//
#include <hip/hip_runtime.h>
#include <math.h>

#define TOK 16384
#define DIMC 512
#define FFI 1365
#define CH1 683
#define YSLD 1376         // YS row stride (bf16 elements, 16B aligned)
#define KVPAD 1056        // padded key count for spatial attn (mult of 8)
#define BSTRIDE 1152      // BIASX row stride (cols: 0=null, 1..1024=keys, rest=mask)
#define MASKB (-30000.f)  // softmax mask bias (bf16-safe, no near-inf)
#define LOG2E 1.4426950408889634f

typedef unsigned int u32;
typedef unsigned short ushort_t;
typedef __attribute__((ext_vector_type(8))) short bf16x8;
typedef __attribute__((ext_vector_type(4))) float f32x4;

__device__ inline ushort_t f2b(float x) {
    u32 u = __float_as_uint(x);
    u32 r = (u + 0x7fffu + ((u >> 16) & 1u)) >> 16;
    return (ushort_t)r;
}
__device__ inline float b2f(ushort_t u) { return __uint_as_float(((u32)u) << 16); }

__device__ inline float exp2_fast(float x) {
    float r;
    asm("v_exp_f32 %0, %1" : "=v"(r) : "v"(x));
    return r;
}

// pack two f32 -> {bf16(hi)<<16 | bf16(lo)}  (RTNE, gfx950)
__device__ inline u32 cvt_pk_bf16(float lo, float hi) {
    u32 r;
    asm("v_cvt_pk_bf16_f32 %0, %1, %2" : "=v"(r) : "v"(lo), "v"(hi));
    return r;
}

__device__ inline void gload_lds16(const void* g, void* l) {
    __builtin_amdgcn_global_load_lds(
        (const __attribute__((address_space(1))) u32*)g,
        (__attribute__((address_space(3))) u32*)l, 16, 0, 0);
}

__device__ inline float gelu_exact(float x) {
    return 0.5f * x * (1.f + erff(x * 0.70710678118654752f));
}

// counted-vmcnt helpers (immediates must be literals in the asm string)
__device__ inline void waitcnt_vm4() {
    asm volatile("s_waitcnt vmcnt(4)" ::: "memory");
    __builtin_amdgcn_sched_barrier(0);
}
__device__ inline void waitcnt_vm0() {
    asm volatile("s_waitcnt vmcnt(0)" ::: "memory");
    __builtin_amdgcn_sched_barrier(0);
}

// ---------------------------------------------------------------- CPB MLP
// 16 rows per block (w1 re-read traffic 1 GB -> 62 MB). FP order preserved.
__global__ __launch_bounds__(256) void cpb_kernel(
    const float* __restrict__ w0, const float* __restrict__ b0,
    const float* __restrict__ w1, const float* __restrict__ b1,
    const float* __restrict__ w2, const float* __restrict__ b2,
    float* __restrict__ table, int mode, int nrows)
{
    __shared__ float t0[16][256];
    __shared__ float t1[16][256];
    int r0 = blockIdx.x * 16;
    int t = threadIdx.x;
    float w0t = w0[t], b0t = b0[t];
    float w0t2 = (mode == 0) ? w0[256 + t] : 0.f;
    #pragma unroll
    for (int rr = 0; rr < 16; ++rr) {
        int r = r0 + rr; if (r >= nrows) r = nrows - 1;
        float c0, c1;
        if (mode == 0) { c0 = (float)(r / 63 - 31); c1 = (float)(r % 63 - 31); }
        else           { c0 = (float)(r - 15);      c1 = 0.f; }
        float a = c0 * w0t + b0t;
        if (mode == 0) a += c1 * w0t2;
        t0[rr][t] = a / (1.f + __expf(-a));
    }
    __syncthreads();
    float b1t = b1[t];
    float acc[16];
    #pragma unroll
    for (int rr = 0; rr < 16; ++rr) acc[rr] = b1t;
    for (int k = 0; k < 256; ++k) {
        float w = w1[k * 256 + t];
        #pragma unroll
        for (int rr = 0; rr < 16; ++rr) acc[rr] += t0[rr][k] * w;
    }
    #pragma unroll
    for (int rr = 0; rr < 16; ++rr) {
        float s = acc[rr];
        t1[rr][t] = s / (1.f + __expf(-s));
    }
    __syncthreads();
    if (t < 128) {
        int rr = t >> 3, oo = t & 7;
        int r = r0 + rr;
        if (r < nrows) {
            float o = b2[oo];
            for (int k = 0; k < 256; ++k) o += t1[rr][k] * w2[k * 8 + oo];
            table[r * 8 + oo] = o;
        }
    }
}

// ------------------------------- materialize spatial bias bf16, padded layout
// NOTE: bias is pre-scaled by LOG2E (softmax uses exp2)
__global__ __launch_bounds__(256) void bias_sp_kernel(
    const float* __restrict__ tab, const float* __restrict__ nullbias,
    ushort_t* __restrict__ out)
{
    int pi = blockIdx.x, h = blockIdx.y;
    int phi = pi >> 5, pwi = pi & 31;
    ushort_t* row = out + ((size_t)h * 1024 + pi) * BSTRIDE;
    for (int c = threadIdx.x; c < BSTRIDE; c += 256) {
        float v;
        if (c == 0) v = nullbias[h];
        else if (c <= 1024) {
            int pj = c - 1;
            int phj = pj >> 5, pwj = pj & 31;
            int idx = (phi - phj + 31) * 63 + (pwi - pwj + 31);
            v = tab[idx * 8 + h];
        } else v = MASKB;
        row[c] = f2b(v * LOG2E);
    }
}

// -------------------------------------------- KP/VT pad+null init. grid 16
__global__ __launch_bounds__(256) void kvinit_kernel(
    const float* __restrict__ nullkv, ushort_t* __restrict__ KP, ushort_t* __restrict__ VT)
{
    int f = blockIdx.x, t = threadIdx.x;
    for (int e = t; e < 32 * 64; e += 256) {
        int rr = e >> 6, d = e & 63;
        int row = (rr == 0) ? 0 : (1024 + rr);
        KP[((size_t)f * KVPAD + row) * 64 + d] = (rr == 0) ? f2b(nullkv[d]) : (ushort_t)0;
    }
    for (int e = t; e < 64 * 32; e += 256) {
        int d = e >> 5, cc = e & 31;
        int col = (cc == 0) ? 0 : (1024 + cc);
        VT[((size_t)f * 64 + d) * KVPAD + col] = (cc == 0) ? f2b(nullkv[64 + d]) : (ushort_t)0;
    }
}

// ---------------- weight convert: W[K][ldw] (col window c0) -> Bt[N][Kp] bf16
// Writes rows n < Nwrite (zeros for n >= Ncols or k >= K) — pad rows are clean.
__global__ __launch_bounds__(256) void wcvt_kernel(
    const float* __restrict__ W, int ldw, int c0,
    ushort_t* __restrict__ Bt, int Kp, int K, int Ncols,
    const float* __restrict__ gv, int Nwrite)
{
    __shared__ float tile[32][33];
    int nb = blockIdx.x * 32, kb = blockIdx.y * 32;
    int tx = threadIdx.x & 31, ty = threadIdx.x >> 5;
    #pragma unroll
    for (int it = 0; it < 4; ++it) {
        int k = kb + ty + it * 8, n = nb + tx;
        float v = (k < K && n < Ncols) ? W[(size_t)k * ldw + c0 + n] : 0.f;
        if (gv && k < K) v *= gv[k];
        tile[ty + it * 8][tx] = v;
    }
    __syncthreads();
    #pragma unroll
    for (int it = 0; it < 4; ++it) {
        int n = nb + ty + it * 8, k = kb + tx;
        if (n < Nwrite && k < Kp) Bt[(size_t)n * Kp + k] = f2b(tile[tx][ty + it * 8]);
    }
}

// ---------------------------------------------------- (C,T) -> (T,C) transpose
__global__ __launch_bounds__(256) void transpose_in_kernel(
    const float* __restrict__ x, float* __restrict__ dst)
{
    __shared__ float tile[32][33];
    int t0b = blockIdx.x * 32, c0b = blockIdx.y * 32;
    int tx = threadIdx.x & 31, ty = threadIdx.x >> 5;
    #pragma unroll
    for (int it = 0; it < 4; ++it) {
        int c = ty + it * 8;
        tile[c][tx] = x[(size_t)(c0b + c) * TOK + t0b + tx];
    }
    __syncthreads();
    #pragma unroll
    for (int it = 0; it < 4; ++it) {
        int tr = ty + it * 8;
        dst[(size_t)(t0b + tr) * DIMC + c0b + tx] = tile[tx][tr];
    }
}

// ---------------------------------------------------------------- LayerNorm → bf16
__global__ __launch_bounds__(256) void ln_bf16_kernel(
    const float* __restrict__ in, ushort_t* __restrict__ out,
    const float* __restrict__ w, const float* __restrict__ b)
{
    __shared__ float r1[4], r2[4];
    size_t base = (size_t)blockIdx.x * DIMC;
    int t = threadIdx.x;
    float x0 = in[base + t], x1 = in[base + 256 + t];
    float s = x0 + x1, s2 = x0 * x0 + x1 * x1;
    #pragma unroll
    for (int o = 32; o > 0; o >>= 1) { s += __shfl_down(s, o, 64); s2 += __shfl_down(s2, o, 64); }
    if ((t & 63) == 0) { r1[t >> 6] = s; r2[t >> 6] = s2; }
    __syncthreads();
    float mean = (r1[0] + r1[1] + r1[2] + r1[3]) * (1.f / 512.f);
    float ex2  = (r2[0] + r2[1] + r2[2] + r2[3]) * (1.f / 512.f);
    float rstd = rsqrtf(ex2 - mean * mean + 1e-5f);
    out[base + t]       = f2b((x0 - mean) * rstd * w[t] + b[t]);
    out[base + 256 + t] = f2b((x1 - mean) * rstd * w[256 + t] + b[256 + t]);
}

// LN(proj f32) + residual in place
__global__ __launch_bounds__(256) void ln_add_kernel(
    const float* __restrict__ proj, float* __restrict__ io,
    const float* __restrict__ w, const float* __restrict__ b)
{
    __shared__ float r1[4], r2[4];
    size_t base = (size_t)blockIdx.x * DIMC;
    int t = threadIdx.x;
    float x0 = proj[base + t], x1 = proj[base + 256 + t];
    float s = x0 + x1, s2 = x0 * x0 + x1 * x1;
    #pragma unroll
    for (int o = 32; o > 0; o >>= 1) { s += __shfl_down(s, o, 64); s2 += __shfl_down(s2, o, 64); }
    if ((t & 63) == 0) { r1[t >> 6] = s; r2[t >> 6] = s2; }
    __syncthreads();
    float mean = (r1[0] + r1[1] + r1[2] + r1[3]) * (1.f / 512.f);
    float ex2  = (r2[0] + r2[1] + r2[2] + r2[3]) * (1.f / 512.f);
    float rstd = rsqrtf(ex2 - mean * mean + 1e-5f);
    io[base + t]       += (x0 - mean) * rstd * w[t] + b[t];
    io[base + 256 + t] += (x1 - mean) * rstd * w[256 + t] + b[256 + t];
}

// spatial->temporal row permute (f32)
__global__ __launch_bounds__(128) void permute0_kernel(
    const float* __restrict__ src, float* __restrict__ dst)
{
    int rd = blockIdx.x;
    int rs = (rd & 15) * 1024 + (rd >> 4);
    ((float4*)(dst + (size_t)rd * DIMC))[threadIdx.x] =
        ((const float4*)(src + (size_t)rs * DIMC))[threadIdx.x];
}

// temporal->spatial permute, dual output f32 + bf16
__global__ __launch_bounds__(128) void permute1_dual_kernel(
    const float* __restrict__ src, float* __restrict__ dst, ushort_t* __restrict__ dstb)
{
    int rd = blockIdx.x;
    int rs = (rd & 1023) * 16 + (rd >> 10);
    float4 v = ((const float4*)(src + (size_t)rs * DIMC))[threadIdx.x];
    ((float4*)(dst + (size_t)rd * DIMC))[threadIdx.x] = v;
    u32 lo = (u32)f2b(v.x) | ((u32)f2b(v.y) << 16);
    u32 hi = (u32)f2b(v.z) | ((u32)f2b(v.w) << 16);
    ((uint2*)(dstb + (size_t)rd * DIMC))[threadIdx.x] = make_uint2(lo, hi);
}

// ---------------------------------------------------------------- MFMA GEMM
// 1-D grid of nx*16*8 blocks. XCD-aware swizzle: xcd = lin&7 owns m-tiles
// [xcd*16, xcd*16+16) for ALL nx n-tiles -> per-XCD L2-resident A band.
// Round-5 measured-best schedule (2-buffer: vmcnt(4) -> s_barrier -> compute
// -> s_barrier -> stage(t+2)) + hoisted incremental pointers.
template<int EPI>
__global__ __launch_bounds__(256) void gemm_mfma(
    const ushort_t* __restrict__ A, int lda,
    const ushort_t* __restrict__ Bt, int Kp,
    float* __restrict__ C, ushort_t* __restrict__ Cb, int ldc,
    int M, int N, int K, float scale, int nx,
    const float* __restrict__ stats, const float* __restrict__ g,
    const float* __restrict__ resid, float* __restrict__ outT,
    ushort_t* __restrict__ KPo, ushort_t* __restrict__ VTo)
{
    __shared__ __align__(16) ushort_t As[2][4 * 128 * 8];
    __shared__ __align__(16) ushort_t Bs[2][4 * 128 * 8];
    int lin = blockIdx.x;
    int xcd = lin & 7, idx = lin >> 3;
    int m0 = (xcd * 16 + (idx & 15)) * 128;
    int n0 = (idx >> 4) * 128;
    int tid = threadIdx.x, lane = tid & 63, wid = tid >> 6;
    int wy = wid >> 1, wx = wid & 1, quad = lane >> 4, l16 = lane & 15;
    bool bfull = (n0 + 128 <= N);
    f32x4 acc[4][4];
    #pragma unroll
    for (int i = 0; i < 4; ++i)
        #pragma unroll
        for (int j = 0; j < 4; ++j) { acc[i][j][0]=0.f; acc[i][j][1]=0.f; acc[i][j][2]=0.f; acc[i][j][3]=0.f; }

    if (bfull) {
        int NT = K >> 5;
        int c0 = wid * 128 + lane, c1 = wid * 128 + 64 + lane;
        const ushort_t* gA0 = A + (size_t)(m0 + (c0 & 127)) * lda + (c0 >> 7) * 8;
        const ushort_t* gA1 = A + (size_t)(m0 + (c1 & 127)) * lda + (c1 >> 7) * 8;
        const ushort_t* gB0 = Bt + (size_t)(n0 + (c0 & 127)) * Kp + (c0 >> 7) * 8;
        const ushort_t* gB1 = Bt + (size_t)(n0 + (c1 & 127)) * Kp + (c1 >> 7) * 8;
        const int lo0 = (wid * 128) * 8, lo1 = (wid * 128 + 64) * 8;
        auto stage = [&](int buf) {
            gload_lds16(gA0, &As[buf][lo0]);
            gload_lds16(gA1, &As[buf][lo1]);
            gload_lds16(gB0, &Bs[buf][lo0]);
            gload_lds16(gB1, &Bs[buf][lo1]);
            gA0 += 32; gA1 += 32; gB0 += 32; gB1 += 32;
        };
        stage(0);
        if (NT > 1) stage(1);
        for (int t = 0; t < NT; ++t) {
            if (t + 1 < NT) waitcnt_vm4(); else waitcnt_vm0();
            __builtin_amdgcn_s_barrier();
            int cur = t & 1;
            bf16x8 af[4], bfr[4];
            #pragma unroll
            for (int i = 0; i < 4; ++i) af[i] = *(bf16x8*)&As[cur][(quad * 128 + wy * 64 + i * 16 + l16) * 8];
            #pragma unroll
            for (int j = 0; j < 4; ++j) bfr[j] = *(bf16x8*)&Bs[cur][(quad * 128 + wx * 64 + j * 16 + l16) * 8];
            #pragma unroll
            for (int i = 0; i < 4; ++i)
                #pragma unroll
                for (int j = 0; j < 4; ++j)
                    acc[i][j] = __builtin_amdgcn_mfma_f32_16x16x32_bf16(af[i], bfr[j], acc[i][j], 0, 0, 0);
            if (t + 2 < NT) {
                __builtin_amdgcn_s_barrier();
                stage(cur);
            }
        }
    } else {
        // conservative fallback (not taken by current launches)
        for (int k0 = 0; k0 < K; k0 += 32) {
            if (k0) __syncthreads();
            #pragma unroll
            for (int r = 0; r < 2; ++r) {
                int c = wid * 128 + r * 64 + lane;
                const ushort_t* src = A + (size_t)(m0 + (c & 127)) * lda + k0 + (c >> 7) * 8;
                gload_lds16(src, &As[0][(wid * 128 + r * 64) * 8]);
            }
            #pragma unroll
            for (int r = 0; r < 2; ++r) {
                int c = tid + r * 256;
                int kg = c >> 7, nloc = c & 127;
                bf16x8 v;
                if (n0 + nloc < N) v = *(const bf16x8*)(Bt + (size_t)(n0 + nloc) * Kp + k0 + kg * 8);
                else { for (int e = 0; e < 8; ++e) v[e] = 0; }
                *(bf16x8*)&Bs[0][c * 8] = v;
            }
            __syncthreads();
            bf16x8 af[4], bfr[4];
            #pragma unroll
            for (int i = 0; i < 4; ++i) af[i] = *(bf16x8*)&As[0][(quad * 128 + wy * 64 + i * 16 + l16) * 8];
            #pragma unroll
            for (int j = 0; j < 4; ++j) bfr[j] = *(bf16x8*)&Bs[0][(quad * 128 + wx * 64 + j * 16 + l16) * 8];
            #pragma unroll
            for (int i = 0; i < 4; ++i)
                #pragma unroll
                for (int j = 0; j < 4; ++j)
                    acc[i][j] = __builtin_amdgcn_mfma_f32_16x16x32_bf16(af[i], bfr[j], acc[i][j], 0, 0, 0);
        }
    }
    #pragma unroll
    for (int i = 0; i < 4; ++i) {
        #pragma unroll
        for (int j = 0; j < 4; ++j) {
            #pragma unroll
            for (int r = 0; r < 4; ++r) {
                int m = m0 + wy * 64 + i * 16 + quad * 4 + r;
                int n = n0 + wx * 64 + j * 16 + l16;
                if (n >= N) continue;
                float v = acc[i][j][r] * scale;
                if (EPI == 0) {
                    C[(size_t)m * ldc + n] = v;
                } else if (EPI == 3) {
                    Cb[(size_t)m * ldc + n] = f2b(v);
                } else if (EPI == 4) {
                    int frame = m >> 10, tt = m & 1023;
                    if (n < 64) KPo[((size_t)frame * KVPAD + 1 + tt) * 64 + n] = f2b(v);
                    else        VTo[((size_t)frame * 64 + (n - 64)) * KVPAD + 1 + tt] = f2b(v);
                } else if (EPI == 5) {
                    float s0 = stats[2 * m], s1 = stats[2 * m + 1];
                    outT[(size_t)n * TOK + m] = v * s1 - s0 * g[n] + resid[(size_t)m * DIMC + n];
                }
            }
        }
    }
}

// ------------------------------------------- fused FF front GEMM (a & gate)
// 128m x 64n dual-output tile -> acc = 64 AGPR/thread. B from interleaved
// BI[2816][512] via pure global_load_lds. Grid 2816 = 8 XCD x 16 m x 22 n.
// Round-5 schedule + hoisted incremental pointers.
__global__ __launch_bounds__(256) void ff_gemm_fused(
    const ushort_t* __restrict__ A,
    const ushort_t* __restrict__ BI,
    ushort_t* __restrict__ YS)
{
    __shared__ __align__(16) ushort_t As[2][4 * 128 * 8];
    __shared__ __align__(16) ushort_t Bs[2][4 * 2 * 64 * 8];
    int lin = blockIdx.x;
    int xcd = lin & 7, idx = lin >> 3;
    int m0 = (xcd * 16 + (idx & 15)) * 128;
    int n0 = (idx >> 4) * 64;
    int tid = threadIdx.x, lane = tid & 63, wid = tid >> 6;
    int wy = wid >> 1, wx = wid & 1, quad = lane >> 4, l16 = lane & 15;
    f32x4 aA[4][2], aG[4][2];
    #pragma unroll
    for (int i = 0; i < 4; ++i)
        #pragma unroll
        for (int j = 0; j < 2; ++j) {
            aA[i][j][0]=0.f; aA[i][j][1]=0.f; aA[i][j][2]=0.f; aA[i][j][3]=0.f;
            aG[i][j][0]=0.f; aG[i][j][1]=0.f; aG[i][j][2]=0.f; aG[i][j][3]=0.f;
        }

    int c0 = wid * 128 + lane, c1 = wid * 128 + 64 + lane;
    const ushort_t* gA0 = A + (size_t)(m0 + (c0 & 127)) * 512 + (c0 >> 7) * 8;
    const ushort_t* gA1 = A + (size_t)(m0 + (c1 & 127)) * 512 + (c1 >> 7) * 8;
    const ushort_t* gB0 = BI + (size_t)((n0 + lane) * 2 + 0) * 512 + wid * 8;
    const ushort_t* gB1 = BI + (size_t)((n0 + lane) * 2 + 1) * 512 + wid * 8;
    const int lo0 = (wid * 128) * 8, lo1 = (wid * 128 + 64) * 8;
    auto stage = [&](int buf) {
        gload_lds16(gA0, &As[buf][lo0]);
        gload_lds16(gA1, &As[buf][lo1]);
        gload_lds16(gB0, &Bs[buf][lo0]);
        gload_lds16(gB1, &Bs[buf][lo1]);
        gA0 += 32; gA1 += 32; gB0 += 32; gB1 += 32;
    };

    stage(0); stage(1);
    for (int t = 0; t < 16; ++t) {
        if (t + 1 < 16) waitcnt_vm4(); else waitcnt_vm0();
        __builtin_amdgcn_s_barrier();
        int cur = t & 1;
        bf16x8 af[4], ba[2], bg[2];
        #pragma unroll
        for (int i = 0; i < 4; ++i) af[i] = *(bf16x8*)&As[cur][(quad * 128 + wy * 64 + i * 16 + l16) * 8];
        #pragma unroll
        for (int j = 0; j < 2; ++j) {
            int nn = wx * 32 + j * 16 + l16;
            ba[j] = *(bf16x8*)&Bs[cur][(quad * 128 + nn) * 8];
            bg[j] = *(bf16x8*)&Bs[cur][(quad * 128 + 64 + nn) * 8];
        }
        #pragma unroll
        for (int i = 0; i < 4; ++i)
            #pragma unroll
            for (int j = 0; j < 2; ++j) {
                aA[i][j] = __builtin_amdgcn_mfma_f32_16x16x32_bf16(af[i], ba[j], aA[i][j], 0, 0, 0);
                aG[i][j] = __builtin_amdgcn_mfma_f32_16x16x32_bf16(af[i], bg[j], aG[i][j], 0, 0, 0);
            }
        if (t + 2 < 16) {
            __builtin_amdgcn_s_barrier();
            stage(cur);
        }
    }
    #pragma unroll
    for (int i = 0; i < 4; ++i) {
        #pragma unroll
        for (int j = 0; j < 2; ++j) {
            #pragma unroll
            for (int r = 0; r < 4; ++r) {
                int m = m0 + wy * 64 + i * 16 + quad * 4 + r;
                int n = n0 + wx * 32 + j * 16 + l16;
                if (n >= FFI) {
                    if (n < YSLD) YS[(size_t)m * YSLD + n] = 0;   // zero pad cols
                    continue;
                }
                float v = aA[i][j][r] * gelu_exact(aG[i][j][r]);
                int dr = (n < CH1) ? m : m + 1024;
                if (dr < TOK) YS[(size_t)dr * YSLD + n] = f2b(v);
                if (n >= CH1 && m < 1024) YS[(size_t)m * YSLD + n] = 0;
            }
        }
    }
}

// --------------------------------------------------- spatial attention (MFMA flash)
// ROUND-18: revert to QBLK=16 (round-3 structure, measured best: 116 VGPR,
// 4 waves/SIMD). QBLK=32 (round-17) cost occupancy (140 VGPR -> 3 waves)
// and regressed 116 -> 146 µs. Grid 1024 = 8 xcd x 8 qt x 16 frames.
// Softmax: no online-max (bounded base-2 logits), row-sum via MFMA
// ones-column, cvt_pk pack, ds_bpermute in-register transpose.
__global__ __launch_bounds__(256) void attn_sp_mfma(
    const ushort_t* __restrict__ Q,      // [16384][512] bf16 pre-scaled by 0.125*log2e
    const ushort_t* __restrict__ KP,     // [16][1056][64]
    const ushort_t* __restrict__ VT,     // [16][64][1056]
    const ushort_t* __restrict__ BIASX,  // [8][1024][1152], pre-scaled by log2e
    ushort_t* __restrict__ O)            // [16384][512] bf16
{
    __shared__ __align__(16) ushort_t Ks[128 * 64];
    __shared__ __align__(16) ushort_t Vs[64 * 128];
    int lin = blockIdx.x;
    int xcd = lin & 7, idx = lin >> 3;
    int qt = xcd * 8 + (idx & 7);
    int frame = idx >> 3;
    int q0 = qt * 16;
    int tid = threadIdx.x, lane = tid & 63, wid = tid >> 6;
    int quad = lane >> 4, l16 = lane & 15;

    bf16x8 aQ[2][2];
    const ushort_t* brow[2];
    #pragma unroll
    for (int i = 0; i < 2; ++i) {
        int h = wid * 2 + i;
        const ushort_t* qp = Q + (size_t)(frame * 1024 + q0 + l16) * 512 + h * 64 + quad * 8;
        aQ[i][0] = *(const bf16x8*)qp;
        aQ[i][1] = *(const bf16x8*)(qp + 32);
        brow[i] = BIASX + ((size_t)h * 1024 + q0 + l16) * BSTRIDE;
    }
    f32x4 Oc[2][4];
    f32x4 Oc4[2];   // row-sum accumulator (ones-column PV)
    #pragma unroll
    for (int i = 0; i < 2; ++i) {
        #pragma unroll
        for (int nt = 0; nt < 4; ++nt) { Oc[i][nt][0]=0.f; Oc[i][nt][1]=0.f; Oc[i][nt][2]=0.f; Oc[i][nt][3]=0.f; }
        Oc4[i][0]=0.f; Oc4[i][1]=0.f; Oc4[i][2]=0.f; Oc4[i][3]=0.f;
    }
    bf16x8 vones;
    #pragma unroll
    for (int e = 0; e < 8; ++e) vones[e] = (short)0x3F80;   // bf16 1.0

    // bpermute byte-indices for the in-register P transpose:
    // target (quad,l16) word w pulls from lane (2*(quad&1)+(w>>1))*16 + l16
    int idxA = (((quad & 1) * 32) + l16) * 4;   // w = 0,1
    int idxB = idxA + 64;                       // w = 2,3
    bool hiq = (quad >= 2);                     // selects j = 2ks+1

    for (int jt = 0; jt < 9; ++jt) {
        __syncthreads();
        #pragma unroll
        for (int r = 0; r < 4; ++r) {
            int L = wid * 256 + r * 64 + lane;
            int c = L >> 3, gp = L & 7, gg = gp ^ (c & 7);
            int jj = jt * 128 + c; if (jj > KVPAD - 1) jj = KVPAD - 1;
            gload_lds16(KP + ((size_t)frame * KVPAD + jj) * 64 + gg * 8, &Ks[(wid * 256 + r * 64) * 8]);
        }
        #pragma unroll
        for (int r = 0; r < 4; ++r) {
            int L = wid * 256 + r * 64 + lane;
            int d = L >> 4, cgp = L & 15;
            int cg = (cgp & 8) | ((cgp & 7) ^ (d & 7));
            int col = jt * 128 + cg * 8; if (col > KVPAD - 8) col = KVPAD - 8;
            gload_lds16(VT + ((size_t)frame * 64 + d) * KVPAD + col, &Vs[(wid * 256 + r * 64) * 8]);
        }
        __syncthreads();

        #pragma unroll
        for (int i = 0; i < 2; ++i) {
            // ---- QK^T for this head
            f32x4 S[8];
            #pragma unroll
            for (int j = 0; j < 8; ++j) { S[j][0]=0.f; S[j][1]=0.f; S[j][2]=0.f; S[j][3]=0.f; }
            __builtin_amdgcn_s_setprio(1);
            #pragma unroll
            for (int j = 0; j < 8; ++j) {
                int c = j * 16 + l16;
                #pragma unroll
                for (int ks = 0; ks < 2; ++ks) {
                    bf16x8 kb = *(bf16x8*)&Ks[(c * 8 + ((ks * 4 + quad) ^ (c & 7))) * 8];
                    S[j] = __builtin_amdgcn_mfma_f32_16x16x32_bf16(kb, aQ[i][ks], S[j], 0, 0, 0);
                }
            }
            __builtin_amdgcn_s_setprio(0);
            // ---- bias add + direct exp2 (no max tracking: base-2 logits are
            // small/bounded; MASKB*log2e underflows exp2 to exactly 0)
            #pragma unroll
            for (int j = 0; j < 8; ++j) {
                int kbase = jt * 128 + j * 16 + quad * 4;
                uint2 bv = *(const uint2*)(brow[i] + kbase);
                S[j][0] = exp2_fast(S[j][0] + __uint_as_float(bv.x << 16));
                S[j][1] = exp2_fast(S[j][1] + __uint_as_float(bv.x & 0xffff0000u));
                S[j][2] = exp2_fast(S[j][2] + __uint_as_float(bv.y << 16));
                S[j][3] = exp2_fast(S[j][3] + __uint_as_float(bv.y & 0xffff0000u));
            }
            // ---- pack (cvt_pk) + in-register transpose (ds_bpermute) + PV
            __builtin_amdgcn_s_setprio(1);
            #pragma unroll
            for (int ks = 0; ks < 4; ++ks) {
                int jl = 2 * ks, jh = 2 * ks + 1;
                u32 pxl = cvt_pk_bf16(S[jl][0], S[jl][1]);
                u32 pyl = cvt_pk_bf16(S[jl][2], S[jl][3]);
                u32 pxh = cvt_pk_bf16(S[jh][0], S[jh][1]);
                u32 pyh = cvt_pk_bf16(S[jh][2], S[jh][3]);
                u32 a0 = (u32)__builtin_amdgcn_ds_bpermute(idxA, (int)pxl);
                u32 a1 = (u32)__builtin_amdgcn_ds_bpermute(idxA, (int)pxh);
                u32 b0 = (u32)__builtin_amdgcn_ds_bpermute(idxA, (int)pyl);
                u32 b1 = (u32)__builtin_amdgcn_ds_bpermute(idxA, (int)pyh);
                u32 c0 = (u32)__builtin_amdgcn_ds_bpermute(idxB, (int)pxl);
                u32 c1 = (u32)__builtin_amdgcn_ds_bpermute(idxB, (int)pxh);
                u32 d0 = (u32)__builtin_amdgcn_ds_bpermute(idxB, (int)pyl);
                u32 d1 = (u32)__builtin_amdgcn_ds_bpermute(idxB, (int)pyh);
                union { u32 w[4]; bf16x8 v; } pa;
                pa.w[0] = hiq ? a1 : a0;
                pa.w[1] = hiq ? b1 : b0;
                pa.w[2] = hiq ? c1 : c0;
                pa.w[3] = hiq ? d1 : d0;
                #pragma unroll
                for (int nt = 0; nt < 4; ++nt) {
                    int d = nt * 16 + l16;
                    int cg = ks * 4 + quad;
                    int phys = (cg & 8) | ((cg & 7) ^ (d & 7));
                    bf16x8 vb = *(bf16x8*)&Vs[(d * 16 + phys) * 8];
                    Oc[i][nt] = __builtin_amdgcn_mfma_f32_16x16x32_bf16(pa.v, vb, Oc[i][nt], 0, 0, 0);
                }
                // ones-column: accumulates row-sum of P in matching layout
                Oc4[i] = __builtin_amdgcn_mfma_f32_16x16x32_bf16(pa.v, vones, Oc4[i], 0, 0, 0);
            }
            __builtin_amdgcn_s_setprio(0);
        }
    }
    #pragma unroll
    for (int i = 0; i < 2; ++i) {
        int h = wid * 2 + i;
        #pragma unroll
        for (int r = 0; r < 4; ++r) {
            float linv = 1.f / Oc4[i][r];   // same (q,row) layout as Oc — no shuffle
            int ql = quad * 4 + r;
            #pragma unroll
            for (int nt = 0; nt < 4; ++nt) {
                int d = nt * 16 + l16;
                O[(size_t)(frame * 1024 + q0 + ql) * 512 + h * 64 + d] = f2b(Oc[i][nt][r] * linv);
            }
        }
    }
}

// ---------------------------------------------------------------- temporal attention
// Padded LDS (qs 516, ks/vs 68) to break power-of-2 row-stride bank
// conflicts on the float4 reads. FP order preserved element-wise.
__global__ __launch_bounds__(256) void attn_tp_kernel(
    const ushort_t* __restrict__ q, const ushort_t* __restrict__ kv,
    const float* __restrict__ nullkv, const float* __restrict__ nullbias,
    const float* __restrict__ table, ushort_t* __restrict__ out)
{
    __shared__ float qs[16][516];
    __shared__ float ks[17][68];
    __shared__ float vs[17][68];
    __shared__ float sc[8][16][17];
    int b = blockIdx.x;
    int t = threadIdx.x;
    for (int e = t; e < 16 * 64; e += 256) {
        int f = e >> 6, c8 = e & 63;
        uint4 v = *(const uint4*)(q + (size_t)(b * 16 + f) * 512 + c8 * 8);
        float* dst = &qs[f][c8 * 8];
        dst[0] = b2f((ushort_t)(v.x & 0xffffu)); dst[1] = b2f((ushort_t)(v.x >> 16));
        dst[2] = b2f((ushort_t)(v.y & 0xffffu)); dst[3] = b2f((ushort_t)(v.y >> 16));
        dst[4] = b2f((ushort_t)(v.z & 0xffffu)); dst[5] = b2f((ushort_t)(v.z >> 16));
        dst[6] = b2f((ushort_t)(v.w & 0xffffu)); dst[7] = b2f((ushort_t)(v.w >> 16));
    }
    for (int e = t; e < 17 * 64; e += 256) {
        int j = e >> 6, d = e & 63;
        ks[j][d] = (j == 0) ? nullkv[d]      : b2f(kv[(size_t)(b * 16 + j - 1) * 128 + d]);
        vs[j][d] = (j == 0) ? nullkv[64 + d] : b2f(kv[(size_t)(b * 16 + j - 1) * 128 + 64 + d]);
    }
    __syncthreads();
    for (int e = t; e < 8 * 16 * 17; e += 256) {
        int h = e / 272, rem = e - h * 272;
        int i = rem / 17, j = rem - i * 17;
        float acc = 0.f;
        const float4* qp = (const float4*)&qs[i][h * 64];
        const float4* kp = (const float4*)&ks[j][0];
        #pragma unroll
        for (int d4 = 0; d4 < 16; ++d4) {
            float4 qv = qp[d4], kv4 = kp[d4];
            acc += qv.x * kv4.x;
            acc += qv.y * kv4.y;
            acc += qv.z * kv4.z;
            acc += qv.w * kv4.w;
        }
        float bias = ((j == 0) ? nullbias[h] : table[(i - (j - 1) + 15) * 8 + h]) * LOG2E;
        sc[h][i][j] = acc + bias;   // q pre-scaled by 0.125*log2e -> base-2 logits
    }
    __syncthreads();
    if (t < 128) {
        int h = t >> 4, i = t & 15;
        float mx = -1e30f;
        for (int j = 0; j < 17; ++j) mx = fmaxf(mx, sc[h][i][j]);
        float s = 0.f;
        for (int j = 0; j < 17; ++j) { float p = exp2_fast(sc[h][i][j] - mx); sc[h][i][j] = p; s += p; }
        float inv = 1.f / s;
        for (int j = 0; j < 17; ++j) sc[h][i][j] *= inv;
    }
    __syncthreads();
    for (int e = t; e < 16 * 128; e += 256) {
        int i = e >> 7, c4 = e & 127;
        int h = c4 >> 4, d4 = c4 & 15;
        float ax = 0.f, ay = 0.f, az = 0.f, aw = 0.f;
        #pragma unroll
        for (int j = 0; j < 17; ++j) {
            float p = sc[h][i][j];
            float4 vv = *(const float4*)&vs[j][d4 * 4];
            ax += p * vv.x; ay += p * vv.y; az += p * vv.z; aw += p * vv.w;
        }
        u32 lo = (u32)f2b(ax) | ((u32)f2b(ay) << 16);
        u32 hi = (u32)f2b(az) | ((u32)f2b(aw) << 16);
        *(uint2*)(out + (size_t)(b * 16 + i) * 512 + c4 * 4) = make_uint2(lo, hi);
    }
}

// ------------------------- FF shift-LN row stats from bf16 YS: (mean*rstd, rstd)
__global__ __launch_bounds__(256) void rowstats_bf16_kernel(
    const ushort_t* __restrict__ YS, float* __restrict__ stats)
{
    __shared__ float r1[4], r2[4];
    int r = blockIdx.x, t = threadIdx.x;
    const ushort_t* row = YS + (size_t)r * YSLD;
    float s = 0.f, s2 = 0.f;
    for (int c = t; c < FFI; c += 256) {
        float v = b2f(row[c]);
        s += v; s2 += v * v;
    }
    #pragma unroll
    for (int o = 32; o > 0; o >>= 1) { s += __shfl_down(s, o, 64); s2 += __shfl_down(s2, o, 64); }
    if ((t & 63) == 0) { r1[t >> 6] = s; r2[t >> 6] = s2; }
    __syncthreads();
    float S  = r1[0] + r1[1] + r1[2] + r1[3];
    float S2 = r2[0] + r2[1] + r2[2] + r2[3];
    float mean = S * (1.f / 1365.f);
    float var  = S2 * (1.f / 1365.f) - mean * mean;
    float rstd = rsqrtf(fmaxf(var, 1e-5f));
    if (t == 0) { stats[2 * r] = mean * rstd; stats[2 * r + 1] = rstd; }
}

// --------------------- colsum[n] = sum_k W'[n][k]  (rows of converted W')
__global__ __launch_bounds__(64) void colsum_kernel(
    const ushort_t* __restrict__ Wt, float* __restrict__ colsum)
{
    int n = blockIdx.x, t = threadIdx.x;
    const ushort_t* row = Wt + (size_t)n * YSLD;
    float s = 0.f;
    for (int k = t; k < YSLD; k += 64) s += b2f(row[k]);
    #pragma unroll
    for (int o = 32; o > 0; o >>= 1) s += __shfl_down(s, o, 64);
    if (t == 0) colsum[n] = s;
}

// ================================================================ launcher
extern "C" void kernel_launch(void* const* d_in, const int* in_sizes, int n_in,
                              void* d_out, int out_size, void* d_ws, size_t ws_size,
                              hipStream_t stream)
{
    const float* x          = (const float*)d_in[0];
    const float* sa_ln_w    = (const float*)d_in[1];
    const float* sa_ln_b    = (const float*)d_in[2];
    const float* sa_wq      = (const float*)d_in[3];
    const float* sa_wkv     = (const float*)d_in[4];
    const float* sa_null_kv = (const float*)d_in[5];
    const float* sa_null_b  = (const float*)d_in[6];
    const float* sa_wout    = (const float*)d_in[7];
    const float* sa_oln_w   = (const float*)d_in[8];
    const float* sa_oln_b   = (const float*)d_in[9];
    const float* ta_ln_w    = (const float*)d_in[10];
    const float* ta_ln_b    = (const float*)d_in[11];
    const float* ta_wq      = (const float*)d_in[12];
    const float* ta_wkv     = (const float*)d_in[13];
    const float* ta_null_kv = (const float*)d_in[14];
    const float* ta_null_b  = (const float*)d_in[15];
    const float* ta_wout    = (const float*)d_in[16];
    const float* ta_oln_w   = (const float*)d_in[17];
    const float* ta_oln_b   = (const float*)d_in[18];
    const float* sp_w0      = (const float*)d_in[19];
    const float* sp_b0      = (const float*)d_in[20];
    const float* sp_w1      = (const float*)d_in[21];
    const float* sp_b1      = (const float*)d_in[22];
    const float* sp_w2      = (const float*)d_in[23];
    const float* sp_b2      = (const float*)d_in[24];
    const float* tp_w0      = (const float*)d_in[25];
    const float* tp_b0      = (const float*)d_in[26];
    const float* tp_w1      = (const float*)d_in[27];
    const float* tp_b1      = (const float*)d_in[28];
    const float* tp_w2      = (const float*)d_in[29];
    const float* tp_b2      = (const float*)d_in[30];
    const float* ff_win     = (const float*)d_in[31];
    const float* ff_g       = (const float*)d_in[32];
    const float* ff_wout    = (const float*)d_in[33];

    char* ws = (char*)d_ws;
    // regions (bytes)
    float*    RES   = (float*)(ws + 0);                        // residual, spatial layout
    ushort_t* XN16  = (ushort_t*)(ws + 33554432);              // xn / x2 bf16
    ushort_t* Q16   = (ushort_t*)(ws + 50331648);              // spatial Q bf16 (spatial phase)
    float*    RT    = (float*)(ws + 50331648);                 // temporal residual f32 (temporal phase)
    ushort_t* YS    = (ushort_t*)(ws + 50331648);              // FF shifted act bf16 [16384][1376]
    ushort_t* WSA   = (ushort_t*)(ws + 67108864);              // spatial weights (dead by FF)
    ushort_t* KP    = (ushort_t*)(ws + 83886080);              // 16x1056x64 bf16 (spatial)
    ushort_t* VTb   = (ushort_t*)(ws + 86048768);              // 16x64x1056 bf16 (spatial)
    ushort_t* KV16  = (ushort_t*)(ws + 83886080);              // temporal KV bf16
    ushort_t* WTA   = (ushort_t*)(ws + 90439680);              // temporal weights
    ushort_t* AO16  = (ushort_t*)(ws + 92274688);              // attn out bf16 (dead by FF)
    ushort_t* BI    = (ushort_t*)(ws + 96468992);              // FF interleaved W [2816][512]
    ushort_t* WFFB  = (ushort_t*)(ws + 99352576);              // W' = (ff_wout*g)^T [512][1376]
    ushort_t* BIAS16= (ushort_t*)(ws + 109051904);             // spatial bias bf16 (PRJ region)
    float*    PRJ   = (float*)(ws + 109051904);                // proj out f32
    ushort_t* Q16t  = (ushort_t*)(ws + 109051904);             // temporal Q bf16
    float*    STATS = (float*)(ws + 142606336);                // 16384 x (mean*rstd, rstd)
    float*    SPT   = (float*)(ws + 142737408);                // spatial CPB table (spatial phase)
    float*    COLSUM= (float*)(ws + 142737408);                // colsum[512] (FF phase, dead SPT)
    float*    TPT   = (float*)(ws + 142864448);

    ushort_t* WQ_T  = WSA;                 // [512][512]
    ushort_t* WKV_T = WSA + 262144;        // [128][512]
    ushort_t* WO_T  = WSA + 327680;        // [512][512]
    ushort_t* tWQ_T  = WTA;
    ushort_t* tWKV_T = WTA + 262144;
    ushort_t* tWO_T  = WTA + 327680;

    dim3 blk(256);
    const float QSCL = 0.125f * LOG2E;   // fold log2e into Q so softmax is exp2

    // bias tables
    cpb_kernel<<<dim3(249), blk, 0, stream>>>(sp_w0, sp_b0, sp_w1, sp_b1, sp_w2, sp_b2, SPT, 0, 3969);
    cpb_kernel<<<dim3(2),   blk, 0, stream>>>(tp_w0, tp_b0, tp_w1, tp_b1, tp_w2, tp_b2, TPT, 1, 31);
    bias_sp_kernel<<<dim3(1024, 8), blk, 0, stream>>>(SPT, sa_null_b, BIAS16);
    kvinit_kernel<<<dim3(16), blk, 0, stream>>>(sa_null_kv, KP, VTb);

    // ---------------- spatial ----------------
    wcvt_kernel<<<dim3(16, 16), blk, 0, stream>>>(sa_wq, 512, 0, WQ_T, 512, 512, 512, nullptr, 512);
    wcvt_kernel<<<dim3(4, 16),  blk, 0, stream>>>(sa_wkv, 128, 0, WKV_T, 512, 512, 128, nullptr, 128);
    wcvt_kernel<<<dim3(16, 16), blk, 0, stream>>>(sa_wout, 512, 0, WO_T, 512, 512, 512, nullptr, 512);
    transpose_in_kernel<<<dim3(512, 16), blk, 0, stream>>>(x, RES);
    ln_bf16_kernel<<<dim3(TOK), blk, 0, stream>>>(RES, XN16, sa_ln_w, sa_ln_b);
    gemm_mfma<3><<<dim3(512), blk, 0, stream>>>(XN16, 512, WQ_T, 512,
        nullptr, Q16, 512, TOK, 512, 512, QSCL, 4, nullptr, nullptr, nullptr, nullptr, nullptr, nullptr);
    gemm_mfma<4><<<dim3(128), blk, 0, stream>>>(XN16, 512, WKV_T, 512,
        nullptr, nullptr, 0, TOK, 128, 512, 1.0f, 1, nullptr, nullptr, nullptr, nullptr, KP, VTb);
    attn_sp_mfma<<<dim3(1024), blk, 0, stream>>>(Q16, KP, VTb, BIAS16, AO16);
    gemm_mfma<0><<<dim3(512), blk, 0, stream>>>(AO16, 512, WO_T, 512,
        PRJ, nullptr, 512, TOK, 512, 512, 1.0f, 4, nullptr, nullptr, nullptr, nullptr, nullptr, nullptr);
    ln_add_kernel<<<dim3(TOK), blk, 0, stream>>>(PRJ, RES, sa_oln_w, sa_oln_b);

    // ---------------- temporal ----------------
    permute0_kernel<<<dim3(TOK), dim3(128), 0, stream>>>(RES, RT);
    wcvt_kernel<<<dim3(16, 16), blk, 0, stream>>>(ta_wq, 512, 0, tWQ_T, 512, 512, 512, nullptr, 512);
    wcvt_kernel<<<dim3(4, 16),  blk, 0, stream>>>(ta_wkv, 128, 0, tWKV_T, 512, 512, 128, nullptr, 128);
    wcvt_kernel<<<dim3(16, 16), blk, 0, stream>>>(ta_wout, 512, 0, tWO_T, 512, 512, 512, nullptr, 512);
    ln_bf16_kernel<<<dim3(TOK), blk, 0, stream>>>(RT, XN16, ta_ln_w, ta_ln_b);
    gemm_mfma<3><<<dim3(512), blk, 0, stream>>>(XN16, 512, tWQ_T, 512,
        nullptr, Q16t, 512, TOK, 512, 512, QSCL, 4, nullptr, nullptr, nullptr, nullptr, nullptr, nullptr);
    gemm_mfma<3><<<dim3(128), blk, 0, stream>>>(XN16, 512, tWKV_T, 512,
        nullptr, KV16, 128, TOK, 128, 512, 1.0f, 1, nullptr, nullptr, nullptr, nullptr, nullptr, nullptr);
    attn_tp_kernel<<<dim3(1024), blk, 0, stream>>>(Q16t, KV16, ta_null_kv, ta_null_b, TPT, AO16);
    gemm_mfma<0><<<dim3(512), blk, 0, stream>>>(AO16, 512, tWO_T, 512,
        PRJ, nullptr, 512, TOK, 512, 512, 1.0f, 4, nullptr, nullptr, nullptr, nullptr, nullptr, nullptr);
    ln_add_kernel<<<dim3(TOK), blk, 0, stream>>>(PRJ, RT, ta_oln_w, ta_oln_b);
    permute1_dual_kernel<<<dim3(TOK), dim3(128), 0, stream>>>(RT, RES, XN16);

    // ---------------- feed-forward ----------------
    wcvt_kernel<<<dim3(44, 16), blk, 0, stream>>>(ff_win, 2730, 0,   BI,       1024, 512, FFI, nullptr, 1408);
    wcvt_kernel<<<dim3(44, 16), blk, 0, stream>>>(ff_win, 2730, FFI, BI + 512, 1024, 512, FFI, nullptr, 1408);
    wcvt_kernel<<<dim3(16, 43), blk, 0, stream>>>(ff_wout, 512, 0, WFFB, YSLD, FFI, 512, ff_g, 512);
    colsum_kernel<<<dim3(512), dim3(64), 0, stream>>>(WFFB, COLSUM);
    ff_gemm_fused<<<dim3(2816), blk, 0, stream>>>(XN16, BI, YS);
    rowstats_bf16_kernel<<<dim3(TOK), blk, 0, stream>>>(YS, STATS);
    gemm_mfma<5><<<dim3(512), blk, 0, stream>>>(YS, YSLD, WFFB, YSLD,
        nullptr, nullptr, 0, TOK, 512, YSLD, 1.0f, 4, STATS, COLSUM, RES, (float*)d_out, nullptr, nullptr);
}

// Round 10
// 765.956 us; speedup vs baseline: 1.1446x; 1.0452x over previous
//
#include <hip/hip_runtime.h>
#include <math.h>

#define TOK 16384
#define DIMC 512
#define FFI 1365
#define CH1 683
#define YSLD 1376         // YS row stride (bf16 elements, 16B aligned)
#define KVPAD 1056        // padded key count for spatial attn (mult of 8)
#define BSTRIDE 1152      // BIASX row stride (cols: 0=null, 1..1024=keys, rest=mask)
#define MASKB (-30000.f)  // softmax mask bias (bf16-safe, no near-inf)
#define LOG2E 1.4426950408889634f

typedef unsigned int u32;
typedef unsigned short ushort_t;
typedef __attribute__((ext_vector_type(8))) short bf16x8;
typedef __attribute__((ext_vector_type(4))) float f32x4;

__device__ inline ushort_t f2b(float x) {
    u32 u = __float_as_uint(x);
    u32 r = (u + 0x7fffu + ((u >> 16) & 1u)) >> 16;
    return (ushort_t)r;
}
__device__ inline float b2f(ushort_t u) { return __uint_as_float(((u32)u) << 16); }

__device__ inline float exp2_fast(float x) {
    float r;
    asm("v_exp_f32 %0, %1" : "=v"(r) : "v"(x));
    return r;
}

// pack two f32 -> {bf16(hi)<<16 | bf16(lo)}  (RTNE, gfx950)
__device__ inline u32 cvt_pk_bf16(float lo, float hi) {
    u32 r;
    asm("v_cvt_pk_bf16_f32 %0, %1, %2" : "=v"(r) : "v"(lo), "v"(hi));
    return r;
}

__device__ inline void gload_lds16(const void* g, void* l) {
    __builtin_amdgcn_global_load_lds(
        (const __attribute__((address_space(1))) u32*)g,
        (__attribute__((address_space(3))) u32*)l, 16, 0, 0);
}

__device__ inline float gelu_exact(float x) {
    return 0.5f * x * (1.f + erff(x * 0.70710678118654752f));
}

// counted-vmcnt helpers (immediates must be literals in the asm string)
__device__ inline void waitcnt_vm4() {
    asm volatile("s_waitcnt vmcnt(4)" ::: "memory");
    __builtin_amdgcn_sched_barrier(0);
}
__device__ inline void waitcnt_vm0() {
    asm volatile("s_waitcnt vmcnt(0)" ::: "memory");
    __builtin_amdgcn_sched_barrier(0);
}

// ---------------------------------------------------------------- CPB MLP
// 16 rows per block (w1 re-read traffic 1 GB -> 62 MB). FP order preserved.
__global__ __launch_bounds__(256) void cpb_kernel(
    const float* __restrict__ w0, const float* __restrict__ b0,
    const float* __restrict__ w1, const float* __restrict__ b1,
    const float* __restrict__ w2, const float* __restrict__ b2,
    float* __restrict__ table, int mode, int nrows)
{
    __shared__ float t0[16][256];
    __shared__ float t1[16][256];
    int r0 = blockIdx.x * 16;
    int t = threadIdx.x;
    float w0t = w0[t], b0t = b0[t];
    float w0t2 = (mode == 0) ? w0[256 + t] : 0.f;
    #pragma unroll
    for (int rr = 0; rr < 16; ++rr) {
        int r = r0 + rr; if (r >= nrows) r = nrows - 1;
        float c0, c1;
        if (mode == 0) { c0 = (float)(r / 63 - 31); c1 = (float)(r % 63 - 31); }
        else           { c0 = (float)(r - 15);      c1 = 0.f; }
        float a = c0 * w0t + b0t;
        if (mode == 0) a += c1 * w0t2;
        t0[rr][t] = a / (1.f + __expf(-a));
    }
    __syncthreads();
    float b1t = b1[t];
    float acc[16];
    #pragma unroll
    for (int rr = 0; rr < 16; ++rr) acc[rr] = b1t;
    for (int k = 0; k < 256; ++k) {
        float w = w1[k * 256 + t];
        #pragma unroll
        for (int rr = 0; rr < 16; ++rr) acc[rr] += t0[rr][k] * w;
    }
    #pragma unroll
    for (int rr = 0; rr < 16; ++rr) {
        float s = acc[rr];
        t1[rr][t] = s / (1.f + __expf(-s));
    }
    __syncthreads();
    if (t < 128) {
        int rr = t >> 3, oo = t & 7;
        int r = r0 + rr;
        if (r < nrows) {
            float o = b2[oo];
            for (int k = 0; k < 256; ++k) o += t1[rr][k] * w2[k * 8 + oo];
            table[r * 8 + oo] = o;
        }
    }
}

// ------------------------------- materialize spatial bias bf16, padded layout
// NOTE: bias is pre-scaled by LOG2E (softmax uses exp2)
__global__ __launch_bounds__(256) void bias_sp_kernel(
    const float* __restrict__ tab, const float* __restrict__ nullbias,
    ushort_t* __restrict__ out)
{
    int pi = blockIdx.x, h = blockIdx.y;
    int phi = pi >> 5, pwi = pi & 31;
    ushort_t* row = out + ((size_t)h * 1024 + pi) * BSTRIDE;
    for (int c = threadIdx.x; c < BSTRIDE; c += 256) {
        float v;
        if (c == 0) v = nullbias[h];
        else if (c <= 1024) {
            int pj = c - 1;
            int phj = pj >> 5, pwj = pj & 31;
            int idx = (phi - phj + 31) * 63 + (pwi - pwj + 31);
            v = tab[idx * 8 + h];
        } else v = MASKB;
        row[c] = f2b(v * LOG2E);
    }
}

// -------------------------------------------- KP/VT pad+null init. grid 16
__global__ __launch_bounds__(256) void kvinit_kernel(
    const float* __restrict__ nullkv, ushort_t* __restrict__ KP, ushort_t* __restrict__ VT)
{
    int f = blockIdx.x, t = threadIdx.x;
    for (int e = t; e < 32 * 64; e += 256) {
        int rr = e >> 6, d = e & 63;
        int row = (rr == 0) ? 0 : (1024 + rr);
        KP[((size_t)f * KVPAD + row) * 64 + d] = (rr == 0) ? f2b(nullkv[d]) : (ushort_t)0;
    }
    for (int e = t; e < 64 * 32; e += 256) {
        int d = e >> 5, cc = e & 31;
        int col = (cc == 0) ? 0 : (1024 + cc);
        VT[((size_t)f * 64 + d) * KVPAD + col] = (cc == 0) ? f2b(nullkv[64 + d]) : (ushort_t)0;
    }
}

// ---------------- weight convert: W[K][ldw] (col window c0) -> Bt[N][Kp] bf16
// Writes rows n < Nwrite (zeros for n >= Ncols or k >= K) — pad rows are clean.
__global__ __launch_bounds__(256) void wcvt_kernel(
    const float* __restrict__ W, int ldw, int c0,
    ushort_t* __restrict__ Bt, int Kp, int K, int Ncols,
    const float* __restrict__ gv, int Nwrite)
{
    __shared__ float tile[32][33];
    int nb = blockIdx.x * 32, kb = blockIdx.y * 32;
    int tx = threadIdx.x & 31, ty = threadIdx.x >> 5;
    #pragma unroll
    for (int it = 0; it < 4; ++it) {
        int k = kb + ty + it * 8, n = nb + tx;
        float v = (k < K && n < Ncols) ? W[(size_t)k * ldw + c0 + n] : 0.f;
        if (gv && k < K) v *= gv[k];
        tile[ty + it * 8][tx] = v;
    }
    __syncthreads();
    #pragma unroll
    for (int it = 0; it < 4; ++it) {
        int n = nb + ty + it * 8, k = kb + tx;
        if (n < Nwrite && k < Kp) Bt[(size_t)n * Kp + k] = f2b(tile[tx][ty + it * 8]);
    }
}

// ---------------------------------------------------- (C,T) -> (T,C) transpose
__global__ __launch_bounds__(256) void transpose_in_kernel(
    const float* __restrict__ x, float* __restrict__ dst)
{
    __shared__ float tile[32][33];
    int t0b = blockIdx.x * 32, c0b = blockIdx.y * 32;
    int tx = threadIdx.x & 31, ty = threadIdx.x >> 5;
    #pragma unroll
    for (int it = 0; it < 4; ++it) {
        int c = ty + it * 8;
        tile[c][tx] = x[(size_t)(c0b + c) * TOK + t0b + tx];
    }
    __syncthreads();
    #pragma unroll
    for (int it = 0; it < 4; ++it) {
        int tr = ty + it * 8;
        dst[(size_t)(t0b + tr) * DIMC + c0b + tx] = tile[tx][tr];
    }
}

// ---------------------------------------------------------------- LayerNorm → bf16
__global__ __launch_bounds__(256) void ln_bf16_kernel(
    const float* __restrict__ in, ushort_t* __restrict__ out,
    const float* __restrict__ w, const float* __restrict__ b)
{
    __shared__ float r1[4], r2[4];
    size_t base = (size_t)blockIdx.x * DIMC;
    int t = threadIdx.x;
    float x0 = in[base + t], x1 = in[base + 256 + t];
    float s = x0 + x1, s2 = x0 * x0 + x1 * x1;
    #pragma unroll
    for (int o = 32; o > 0; o >>= 1) { s += __shfl_down(s, o, 64); s2 += __shfl_down(s2, o, 64); }
    if ((t & 63) == 0) { r1[t >> 6] = s; r2[t >> 6] = s2; }
    __syncthreads();
    float mean = (r1[0] + r1[1] + r1[2] + r1[3]) * (1.f / 512.f);
    float ex2  = (r2[0] + r2[1] + r2[2] + r2[3]) * (1.f / 512.f);
    float rstd = rsqrtf(ex2 - mean * mean + 1e-5f);
    out[base + t]       = f2b((x0 - mean) * rstd * w[t] + b[t]);
    out[base + 256 + t] = f2b((x1 - mean) * rstd * w[256 + t] + b[256 + t]);
}

// ---------------- spatial LN(proj)+residual, fused spatial->temporal permute
// (ROUND-19: replaces ln_add + permute0 — RES update was dead except as
// permute0's source). Reads PRJ + RES (read-only), writes RT at permuted rows.
__global__ __launch_bounds__(256) void ln_add_sp_kernel(
    const float* __restrict__ proj, const float* __restrict__ resid,
    float* __restrict__ dstT,
    const float* __restrict__ w, const float* __restrict__ b)
{
    __shared__ float r1[4], r2[4];
    int s = blockIdx.x;
    size_t base = (size_t)s * DIMC;
    int t = threadIdx.x;
    float x0 = proj[base + t], x1 = proj[base + 256 + t];
    float sa = x0 + x1, s2 = x0 * x0 + x1 * x1;
    #pragma unroll
    for (int o = 32; o > 0; o >>= 1) { sa += __shfl_down(sa, o, 64); s2 += __shfl_down(s2, o, 64); }
    if ((t & 63) == 0) { r1[t >> 6] = sa; r2[t >> 6] = s2; }
    __syncthreads();
    float mean = (r1[0] + r1[1] + r1[2] + r1[3]) * (1.f / 512.f);
    float ex2  = (r2[0] + r2[1] + r2[2] + r2[3]) * (1.f / 512.f);
    float rstd = rsqrtf(ex2 - mean * mean + 1e-5f);
    int rd = (s & 1023) * 16 + (s >> 10);           // spatial row -> temporal row
    size_t ob = (size_t)rd * DIMC;
    dstT[ob + t]       = resid[base + t]       + (x0 - mean) * rstd * w[t] + b[t];
    dstT[ob + 256 + t] = resid[base + 256 + t] + (x1 - mean) * rstd * w[256 + t] + b[256 + t];
}

// ---------------- temporal LN(proj)+residual, fused temporal->spatial permute
// (ROUND-19: replaces ln_add + permute1_dual). Reads PRJ + RT (read-only),
// writes RES (f32) + XN16 (bf16) at permuted rows; RT becomes dead.
__global__ __launch_bounds__(256) void ln_add_tp_kernel(
    const float* __restrict__ proj, const float* __restrict__ resid,
    float* __restrict__ dstF, ushort_t* __restrict__ dstB,
    const float* __restrict__ w, const float* __restrict__ b)
{
    __shared__ float r1[4], r2[4];
    int tt = blockIdx.x;
    size_t base = (size_t)tt * DIMC;
    int t = threadIdx.x;
    float x0 = proj[base + t], x1 = proj[base + 256 + t];
    float sa = x0 + x1, s2 = x0 * x0 + x1 * x1;
    #pragma unroll
    for (int o = 32; o > 0; o >>= 1) { sa += __shfl_down(sa, o, 64); s2 += __shfl_down(s2, o, 64); }
    if ((t & 63) == 0) { r1[t >> 6] = sa; r2[t >> 6] = s2; }
    __syncthreads();
    float mean = (r1[0] + r1[1] + r1[2] + r1[3]) * (1.f / 512.f);
    float ex2  = (r2[0] + r2[1] + r2[2] + r2[3]) * (1.f / 512.f);
    float rstd = rsqrtf(ex2 - mean * mean + 1e-5f);
    float v0 = resid[base + t]       + (x0 - mean) * rstd * w[t] + b[t];
    float v1 = resid[base + 256 + t] + (x1 - mean) * rstd * w[256 + t] + b[256 + t];
    int sd = (tt & 15) * 1024 + (tt >> 4);          // temporal row -> spatial row
    size_t ob = (size_t)sd * DIMC;
    dstF[ob + t]       = v0;
    dstF[ob + 256 + t] = v1;
    dstB[ob + t]       = f2b(v0);
    dstB[ob + 256 + t] = f2b(v1);
}

// ---------------------------------------------------------------- MFMA GEMM
// 1-D grid of nx*16*8 blocks. XCD-aware swizzle: xcd = lin&7 owns m-tiles
// [xcd*16, xcd*16+16) for ALL nx n-tiles -> per-XCD L2-resident A band.
// Round-5 measured-best schedule (2-buffer: vmcnt(4) -> s_barrier -> compute
// -> s_barrier -> stage(t+2)) + hoisted incremental pointers.
template<int EPI>
__global__ __launch_bounds__(256) void gemm_mfma(
    const ushort_t* __restrict__ A, int lda,
    const ushort_t* __restrict__ Bt, int Kp,
    float* __restrict__ C, ushort_t* __restrict__ Cb, int ldc,
    int M, int N, int K, float scale, int nx,
    const float* __restrict__ stats, const float* __restrict__ g,
    const float* __restrict__ resid, float* __restrict__ outT,
    ushort_t* __restrict__ KPo, ushort_t* __restrict__ VTo)
{
    __shared__ __align__(16) ushort_t As[2][4 * 128 * 8];
    __shared__ __align__(16) ushort_t Bs[2][4 * 128 * 8];
    int lin = blockIdx.x;
    int xcd = lin & 7, idx = lin >> 3;
    int m0 = (xcd * 16 + (idx & 15)) * 128;
    int n0 = (idx >> 4) * 128;
    int tid = threadIdx.x, lane = tid & 63, wid = tid >> 6;
    int wy = wid >> 1, wx = wid & 1, quad = lane >> 4, l16 = lane & 15;
    bool bfull = (n0 + 128 <= N);
    f32x4 acc[4][4];
    #pragma unroll
    for (int i = 0; i < 4; ++i)
        #pragma unroll
        for (int j = 0; j < 4; ++j) { acc[i][j][0]=0.f; acc[i][j][1]=0.f; acc[i][j][2]=0.f; acc[i][j][3]=0.f; }

    if (bfull) {
        int NT = K >> 5;
        int c0 = wid * 128 + lane, c1 = wid * 128 + 64 + lane;
        const ushort_t* gA0 = A + (size_t)(m0 + (c0 & 127)) * lda + (c0 >> 7) * 8;
        const ushort_t* gA1 = A + (size_t)(m0 + (c1 & 127)) * lda + (c1 >> 7) * 8;
        const ushort_t* gB0 = Bt + (size_t)(n0 + (c0 & 127)) * Kp + (c0 >> 7) * 8;
        const ushort_t* gB1 = Bt + (size_t)(n0 + (c1 & 127)) * Kp + (c1 >> 7) * 8;
        const int lo0 = (wid * 128) * 8, lo1 = (wid * 128 + 64) * 8;
        auto stage = [&](int buf) {
            gload_lds16(gA0, &As[buf][lo0]);
            gload_lds16(gA1, &As[buf][lo1]);
            gload_lds16(gB0, &Bs[buf][lo0]);
            gload_lds16(gB1, &Bs[buf][lo1]);
            gA0 += 32; gA1 += 32; gB0 += 32; gB1 += 32;
        };
        stage(0);
        if (NT > 1) stage(1);
        for (int t = 0; t < NT; ++t) {
            if (t + 1 < NT) waitcnt_vm4(); else waitcnt_vm0();
            __builtin_amdgcn_s_barrier();
            int cur = t & 1;
            bf16x8 af[4], bfr[4];
            #pragma unroll
            for (int i = 0; i < 4; ++i) af[i] = *(bf16x8*)&As[cur][(quad * 128 + wy * 64 + i * 16 + l16) * 8];
            #pragma unroll
            for (int j = 0; j < 4; ++j) bfr[j] = *(bf16x8*)&Bs[cur][(quad * 128 + wx * 64 + j * 16 + l16) * 8];
            #pragma unroll
            for (int i = 0; i < 4; ++i)
                #pragma unroll
                for (int j = 0; j < 4; ++j)
                    acc[i][j] = __builtin_amdgcn_mfma_f32_16x16x32_bf16(af[i], bfr[j], acc[i][j], 0, 0, 0);
            if (t + 2 < NT) {
                __builtin_amdgcn_s_barrier();
                stage(cur);
            }
        }
    } else {
        // conservative fallback (not taken by current launches)
        for (int k0 = 0; k0 < K; k0 += 32) {
            if (k0) __syncthreads();
            #pragma unroll
            for (int r = 0; r < 2; ++r) {
                int c = wid * 128 + r * 64 + lane;
                const ushort_t* src = A + (size_t)(m0 + (c & 127)) * lda + k0 + (c >> 7) * 8;
                gload_lds16(src, &As[0][(wid * 128 + r * 64) * 8]);
            }
            #pragma unroll
            for (int r = 0; r < 2; ++r) {
                int c = tid + r * 256;
                int kg = c >> 7, nloc = c & 127;
                bf16x8 v;
                if (n0 + nloc < N) v = *(const bf16x8*)(Bt + (size_t)(n0 + nloc) * Kp + k0 + kg * 8);
                else { for (int e = 0; e < 8; ++e) v[e] = 0; }
                *(bf16x8*)&Bs[0][c * 8] = v;
            }
            __syncthreads();
            bf16x8 af[4], bfr[4];
            #pragma unroll
            for (int i = 0; i < 4; ++i) af[i] = *(bf16x8*)&As[0][(quad * 128 + wy * 64 + i * 16 + l16) * 8];
            #pragma unroll
            for (int j = 0; j < 4; ++j) bfr[j] = *(bf16x8*)&Bs[0][(quad * 128 + wx * 64 + j * 16 + l16) * 8];
            #pragma unroll
            for (int i = 0; i < 4; ++i)
                #pragma unroll
                for (int j = 0; j < 4; ++j)
                    acc[i][j] = __builtin_amdgcn_mfma_f32_16x16x32_bf16(af[i], bfr[j], acc[i][j], 0, 0, 0);
        }
    }
    #pragma unroll
    for (int i = 0; i < 4; ++i) {
        #pragma unroll
        for (int j = 0; j < 4; ++j) {
            #pragma unroll
            for (int r = 0; r < 4; ++r) {
                int m = m0 + wy * 64 + i * 16 + quad * 4 + r;
                int n = n0 + wx * 64 + j * 16 + l16;
                if (n >= N) continue;
                float v = acc[i][j][r] * scale;
                if (EPI == 0) {
                    C[(size_t)m * ldc + n] = v;
                } else if (EPI == 3) {
                    Cb[(size_t)m * ldc + n] = f2b(v);
                } else if (EPI == 4) {
                    int frame = m >> 10, tt = m & 1023;
                    if (n < 64) KPo[((size_t)frame * KVPAD + 1 + tt) * 64 + n] = f2b(v);
                    else        VTo[((size_t)frame * 64 + (n - 64)) * KVPAD + 1 + tt] = f2b(v);
                } else if (EPI == 5) {
                    float s0 = stats[2 * m], s1 = stats[2 * m + 1];
                    outT[(size_t)n * TOK + m] = v * s1 - s0 * g[n] + resid[(size_t)m * DIMC + n];
                }
            }
        }
    }
}

// ------------------------------------------- fused FF front GEMM (a & gate)
// 128m x 64n dual-output tile -> acc = 64 AGPR/thread. B from interleaved
// BI[2816][512] via pure global_load_lds. Grid 2816 = 8 XCD x 16 m x 22 n.
// Round-5 schedule + hoisted incremental pointers.
__global__ __launch_bounds__(256) void ff_gemm_fused(
    const ushort_t* __restrict__ A,
    const ushort_t* __restrict__ BI,
    ushort_t* __restrict__ YS)
{
    __shared__ __align__(16) ushort_t As[2][4 * 128 * 8];
    __shared__ __align__(16) ushort_t Bs[2][4 * 2 * 64 * 8];
    int lin = blockIdx.x;
    int xcd = lin & 7, idx = lin >> 3;
    int m0 = (xcd * 16 + (idx & 15)) * 128;
    int n0 = (idx >> 4) * 64;
    int tid = threadIdx.x, lane = tid & 63, wid = tid >> 6;
    int wy = wid >> 1, wx = wid & 1, quad = lane >> 4, l16 = lane & 15;
    f32x4 aA[4][2], aG[4][2];
    #pragma unroll
    for (int i = 0; i < 4; ++i)
        #pragma unroll
        for (int j = 0; j < 2; ++j) {
            aA[i][j][0]=0.f; aA[i][j][1]=0.f; aA[i][j][2]=0.f; aA[i][j][3]=0.f;
            aG[i][j][0]=0.f; aG[i][j][1]=0.f; aG[i][j][2]=0.f; aG[i][j][3]=0.f;
        }

    int c0 = wid * 128 + lane, c1 = wid * 128 + 64 + lane;
    const ushort_t* gA0 = A + (size_t)(m0 + (c0 & 127)) * 512 + (c0 >> 7) * 8;
    const ushort_t* gA1 = A + (size_t)(m0 + (c1 & 127)) * 512 + (c1 >> 7) * 8;
    const ushort_t* gB0 = BI + (size_t)((n0 + lane) * 2 + 0) * 512 + wid * 8;
    const ushort_t* gB1 = BI + (size_t)((n0 + lane) * 2 + 1) * 512 + wid * 8;
    const int lo0 = (wid * 128) * 8, lo1 = (wid * 128 + 64) * 8;
    auto stage = [&](int buf) {
        gload_lds16(gA0, &As[buf][lo0]);
        gload_lds16(gA1, &As[buf][lo1]);
        gload_lds16(gB0, &Bs[buf][lo0]);
        gload_lds16(gB1, &Bs[buf][lo1]);
        gA0 += 32; gA1 += 32; gB0 += 32; gB1 += 32;
    };

    stage(0); stage(1);
    for (int t = 0; t < 16; ++t) {
        if (t + 1 < 16) waitcnt_vm4(); else waitcnt_vm0();
        __builtin_amdgcn_s_barrier();
        int cur = t & 1;
        bf16x8 af[4], ba[2], bg[2];
        #pragma unroll
        for (int i = 0; i < 4; ++i) af[i] = *(bf16x8*)&As[cur][(quad * 128 + wy * 64 + i * 16 + l16) * 8];
        #pragma unroll
        for (int j = 0; j < 2; ++j) {
            int nn = wx * 32 + j * 16 + l16;
            ba[j] = *(bf16x8*)&Bs[cur][(quad * 128 + nn) * 8];
            bg[j] = *(bf16x8*)&Bs[cur][(quad * 128 + 64 + nn) * 8];
        }
        #pragma unroll
        for (int i = 0; i < 4; ++i)
            #pragma unroll
            for (int j = 0; j < 2; ++j) {
                aA[i][j] = __builtin_amdgcn_mfma_f32_16x16x32_bf16(af[i], ba[j], aA[i][j], 0, 0, 0);
                aG[i][j] = __builtin_amdgcn_mfma_f32_16x16x32_bf16(af[i], bg[j], aG[i][j], 0, 0, 0);
            }
        if (t + 2 < 16) {
            __builtin_amdgcn_s_barrier();
            stage(cur);
        }
    }
    #pragma unroll
    for (int i = 0; i < 4; ++i) {
        #pragma unroll
        for (int j = 0; j < 2; ++j) {
            #pragma unroll
            for (int r = 0; r < 4; ++r) {
                int m = m0 + wy * 64 + i * 16 + quad * 4 + r;
                int n = n0 + wx * 32 + j * 16 + l16;
                if (n >= FFI) {
                    if (n < YSLD) YS[(size_t)m * YSLD + n] = 0;   // zero pad cols
                    continue;
                }
                float v = aA[i][j][r] * gelu_exact(aG[i][j][r]);
                int dr = (n < CH1) ? m : m + 1024;
                if (dr < TOK) YS[(size_t)dr * YSLD + n] = f2b(v);
                if (n >= CH1 && m < 1024) YS[(size_t)m * YSLD + n] = 0;
            }
        }
    }
}

// --------------------------------------------------- spatial attention (MFMA flash)
// QBLK=16 (measured best: 116 VGPR, 4 waves/SIMD). Grid 1024 = 8 xcd x 8 qt
// x 16 frames. Softmax: no online-max (bounded base-2 logits), row-sum via
// MFMA ones-column, cvt_pk pack, ds_bpermute in-register transpose.
__global__ __launch_bounds__(256) void attn_sp_mfma(
    const ushort_t* __restrict__ Q,      // [16384][512] bf16 pre-scaled by 0.125*log2e
    const ushort_t* __restrict__ KP,     // [16][1056][64]
    const ushort_t* __restrict__ VT,     // [16][64][1056]
    const ushort_t* __restrict__ BIASX,  // [8][1024][1152], pre-scaled by log2e
    ushort_t* __restrict__ O)            // [16384][512] bf16
{
    __shared__ __align__(16) ushort_t Ks[128 * 64];
    __shared__ __align__(16) ushort_t Vs[64 * 128];
    int lin = blockIdx.x;
    int xcd = lin & 7, idx = lin >> 3;
    int qt = xcd * 8 + (idx & 7);
    int frame = idx >> 3;
    int q0 = qt * 16;
    int tid = threadIdx.x, lane = tid & 63, wid = tid >> 6;
    int quad = lane >> 4, l16 = lane & 15;

    bf16x8 aQ[2][2];
    const ushort_t* brow[2];
    #pragma unroll
    for (int i = 0; i < 2; ++i) {
        int h = wid * 2 + i;
        const ushort_t* qp = Q + (size_t)(frame * 1024 + q0 + l16) * 512 + h * 64 + quad * 8;
        aQ[i][0] = *(const bf16x8*)qp;
        aQ[i][1] = *(const bf16x8*)(qp + 32);
        brow[i] = BIASX + ((size_t)h * 1024 + q0 + l16) * BSTRIDE;
    }
    f32x4 Oc[2][4];
    f32x4 Oc4[2];   // row-sum accumulator (ones-column PV)
    #pragma unroll
    for (int i = 0; i < 2; ++i) {
        #pragma unroll
        for (int nt = 0; nt < 4; ++nt) { Oc[i][nt][0]=0.f; Oc[i][nt][1]=0.f; Oc[i][nt][2]=0.f; Oc[i][nt][3]=0.f; }
        Oc4[i][0]=0.f; Oc4[i][1]=0.f; Oc4[i][2]=0.f; Oc4[i][3]=0.f;
    }
    bf16x8 vones;
    #pragma unroll
    for (int e = 0; e < 8; ++e) vones[e] = (short)0x3F80;   // bf16 1.0

    // bpermute byte-indices for the in-register P transpose:
    // target (quad,l16) word w pulls from lane (2*(quad&1)+(w>>1))*16 + l16
    int idxA = (((quad & 1) * 32) + l16) * 4;   // w = 0,1
    int idxB = idxA + 64;                       // w = 2,3
    bool hiq = (quad >= 2);                     // selects j = 2ks+1

    for (int jt = 0; jt < 9; ++jt) {
        __syncthreads();
        #pragma unroll
        for (int r = 0; r < 4; ++r) {
            int L = wid * 256 + r * 64 + lane;
            int c = L >> 3, gp = L & 7, gg = gp ^ (c & 7);
            int jj = jt * 128 + c; if (jj > KVPAD - 1) jj = KVPAD - 1;
            gload_lds16(KP + ((size_t)frame * KVPAD + jj) * 64 + gg * 8, &Ks[(wid * 256 + r * 64) * 8]);
        }
        #pragma unroll
        for (int r = 0; r < 4; ++r) {
            int L = wid * 256 + r * 64 + lane;
            int d = L >> 4, cgp = L & 15;
            int cg = (cgp & 8) | ((cgp & 7) ^ (d & 7));
            int col = jt * 128 + cg * 8; if (col > KVPAD - 8) col = KVPAD - 8;
            gload_lds16(VT + ((size_t)frame * 64 + d) * KVPAD + col, &Vs[(wid * 256 + r * 64) * 8]);
        }
        __syncthreads();

        #pragma unroll
        for (int i = 0; i < 2; ++i) {
            // ---- QK^T for this head
            f32x4 S[8];
            #pragma unroll
            for (int j = 0; j < 8; ++j) { S[j][0]=0.f; S[j][1]=0.f; S[j][2]=0.f; S[j][3]=0.f; }
            __builtin_amdgcn_s_setprio(1);
            #pragma unroll
            for (int j = 0; j < 8; ++j) {
                int c = j * 16 + l16;
                #pragma unroll
                for (int ks = 0; ks < 2; ++ks) {
                    bf16x8 kb = *(bf16x8*)&Ks[(c * 8 + ((ks * 4 + quad) ^ (c & 7))) * 8];
                    S[j] = __builtin_amdgcn_mfma_f32_16x16x32_bf16(kb, aQ[i][ks], S[j], 0, 0, 0);
                }
            }
            __builtin_amdgcn_s_setprio(0);
            // ---- bias add + direct exp2 (no max tracking: base-2 logits are
            // small/bounded; MASKB*log2e underflows exp2 to exactly 0)
            #pragma unroll
            for (int j = 0; j < 8; ++j) {
                int kbase = jt * 128 + j * 16 + quad * 4;
                uint2 bv = *(const uint2*)(brow[i] + kbase);
                S[j][0] = exp2_fast(S[j][0] + __uint_as_float(bv.x << 16));
                S[j][1] = exp2_fast(S[j][1] + __uint_as_float(bv.x & 0xffff0000u));
                S[j][2] = exp2_fast(S[j][2] + __uint_as_float(bv.y << 16));
                S[j][3] = exp2_fast(S[j][3] + __uint_as_float(bv.y & 0xffff0000u));
            }
            // ---- pack (cvt_pk) + in-register transpose (ds_bpermute) + PV
            __builtin_amdgcn_s_setprio(1);
            #pragma unroll
            for (int ks = 0; ks < 4; ++ks) {
                int jl = 2 * ks, jh = 2 * ks + 1;
                u32 pxl = cvt_pk_bf16(S[jl][0], S[jl][1]);
                u32 pyl = cvt_pk_bf16(S[jl][2], S[jl][3]);
                u32 pxh = cvt_pk_bf16(S[jh][0], S[jh][1]);
                u32 pyh = cvt_pk_bf16(S[jh][2], S[jh][3]);
                u32 a0 = (u32)__builtin_amdgcn_ds_bpermute(idxA, (int)pxl);
                u32 a1 = (u32)__builtin_amdgcn_ds_bpermute(idxA, (int)pxh);
                u32 b0 = (u32)__builtin_amdgcn_ds_bpermute(idxA, (int)pyl);
                u32 b1 = (u32)__builtin_amdgcn_ds_bpermute(idxA, (int)pyh);
                u32 c0 = (u32)__builtin_amdgcn_ds_bpermute(idxB, (int)pxl);
                u32 c1 = (u32)__builtin_amdgcn_ds_bpermute(idxB, (int)pxh);
                u32 d0 = (u32)__builtin_amdgcn_ds_bpermute(idxB, (int)pyl);
                u32 d1 = (u32)__builtin_amdgcn_ds_bpermute(idxB, (int)pyh);
                union { u32 w[4]; bf16x8 v; } pa;
                pa.w[0] = hiq ? a1 : a0;
                pa.w[1] = hiq ? b1 : b0;
                pa.w[2] = hiq ? c1 : c0;
                pa.w[3] = hiq ? d1 : d0;
                #pragma unroll
                for (int nt = 0; nt < 4; ++nt) {
                    int d = nt * 16 + l16;
                    int cg = ks * 4 + quad;
                    int phys = (cg & 8) | ((cg & 7) ^ (d & 7));
                    bf16x8 vb = *(bf16x8*)&Vs[(d * 16 + phys) * 8];
                    Oc[i][nt] = __builtin_amdgcn_mfma_f32_16x16x32_bf16(pa.v, vb, Oc[i][nt], 0, 0, 0);
                }
                // ones-column: accumulates row-sum of P in matching layout
                Oc4[i] = __builtin_amdgcn_mfma_f32_16x16x32_bf16(pa.v, vones, Oc4[i], 0, 0, 0);
            }
            __builtin_amdgcn_s_setprio(0);
        }
    }
    #pragma unroll
    for (int i = 0; i < 2; ++i) {
        int h = wid * 2 + i;
        #pragma unroll
        for (int r = 0; r < 4; ++r) {
            float linv = 1.f / Oc4[i][r];   // same (q,row) layout as Oc — no shuffle
            int ql = quad * 4 + r;
            #pragma unroll
            for (int nt = 0; nt < 4; ++nt) {
                int d = nt * 16 + l16;
                O[(size_t)(frame * 1024 + q0 + ql) * 512 + h * 64 + d] = f2b(Oc[i][nt][r] * linv);
            }
        }
    }
}

// ---------------------------------------------------------------- temporal attention
// Padded LDS (qs 516, ks/vs 68) to break power-of-2 row-stride bank
// conflicts on the float4 reads. FP order preserved element-wise.
__global__ __launch_bounds__(256) void attn_tp_kernel(
    const ushort_t* __restrict__ q, const ushort_t* __restrict__ kv,
    const float* __restrict__ nullkv, const float* __restrict__ nullbias,
    const float* __restrict__ table, ushort_t* __restrict__ out)
{
    __shared__ float qs[16][516];
    __shared__ float ks[17][68];
    __shared__ float vs[17][68];
    __shared__ float sc[8][16][17];
    int b = blockIdx.x;
    int t = threadIdx.x;
    for (int e = t; e < 16 * 64; e += 256) {
        int f = e >> 6, c8 = e & 63;
        uint4 v = *(const uint4*)(q + (size_t)(b * 16 + f) * 512 + c8 * 8);
        float* dst = &qs[f][c8 * 8];
        dst[0] = b2f((ushort_t)(v.x & 0xffffu)); dst[1] = b2f((ushort_t)(v.x >> 16));
        dst[2] = b2f((ushort_t)(v.y & 0xffffu)); dst[3] = b2f((ushort_t)(v.y >> 16));
        dst[4] = b2f((ushort_t)(v.z & 0xffffu)); dst[5] = b2f((ushort_t)(v.z >> 16));
        dst[6] = b2f((ushort_t)(v.w & 0xffffu)); dst[7] = b2f((ushort_t)(v.w >> 16));
    }
    for (int e = t; e < 17 * 64; e += 256) {
        int j = e >> 6, d = e & 63;
        ks[j][d] = (j == 0) ? nullkv[d]      : b2f(kv[(size_t)(b * 16 + j - 1) * 128 + d]);
        vs[j][d] = (j == 0) ? nullkv[64 + d] : b2f(kv[(size_t)(b * 16 + j - 1) * 128 + 64 + d]);
    }
    __syncthreads();
    for (int e = t; e < 8 * 16 * 17; e += 256) {
        int h = e / 272, rem = e - h * 272;
        int i = rem / 17, j = rem - i * 17;
        float acc = 0.f;
        const float4* qp = (const float4*)&qs[i][h * 64];
        const float4* kp = (const float4*)&ks[j][0];
        #pragma unroll
        for (int d4 = 0; d4 < 16; ++d4) {
            float4 qv = qp[d4], kv4 = kp[d4];
            acc += qv.x * kv4.x;
            acc += qv.y * kv4.y;
            acc += qv.z * kv4.z;
            acc += qv.w * kv4.w;
        }
        float bias = ((j == 0) ? nullbias[h] : table[(i - (j - 1) + 15) * 8 + h]) * LOG2E;
        sc[h][i][j] = acc + bias;   // q pre-scaled by 0.125*log2e -> base-2 logits
    }
    __syncthreads();
    if (t < 128) {
        int h = t >> 4, i = t & 15;
        float mx = -1e30f;
        for (int j = 0; j < 17; ++j) mx = fmaxf(mx, sc[h][i][j]);
        float s = 0.f;
        for (int j = 0; j < 17; ++j) { float p = exp2_fast(sc[h][i][j] - mx); sc[h][i][j] = p; s += p; }
        float inv = 1.f / s;
        for (int j = 0; j < 17; ++j) sc[h][i][j] *= inv;
    }
    __syncthreads();
    for (int e = t; e < 16 * 128; e += 256) {
        int i = e >> 7, c4 = e & 127;
        int h = c4 >> 4, d4 = c4 & 15;
        float ax = 0.f, ay = 0.f, az = 0.f, aw = 0.f;
        #pragma unroll
        for (int j = 0; j < 17; ++j) {
            float p = sc[h][i][j];
            float4 vv = *(const float4*)&vs[j][d4 * 4];
            ax += p * vv.x; ay += p * vv.y; az += p * vv.z; aw += p * vv.w;
        }
        u32 lo = (u32)f2b(ax) | ((u32)f2b(ay) << 16);
        u32 hi = (u32)f2b(az) | ((u32)f2b(aw) << 16);
        *(uint2*)(out + (size_t)(b * 16 + i) * 512 + c4 * 4) = make_uint2(lo, hi);
    }
}

// ------------------------- FF shift-LN row stats from bf16 YS: (mean*rstd, rstd)
__global__ __launch_bounds__(256) void rowstats_bf16_kernel(
    const ushort_t* __restrict__ YS, float* __restrict__ stats)
{
    __shared__ float r1[4], r2[4];
    int r = blockIdx.x, t = threadIdx.x;
    const ushort_t* row = YS + (size_t)r * YSLD;
    float s = 0.f, s2 = 0.f;
    for (int c = t; c < FFI; c += 256) {
        float v = b2f(row[c]);
        s += v; s2 += v * v;
    }
    #pragma unroll
    for (int o = 32; o > 0; o >>= 1) { s += __shfl_down(s, o, 64); s2 += __shfl_down(s2, o, 64); }
    if ((t & 63) == 0) { r1[t >> 6] = s; r2[t >> 6] = s2; }
    __syncthreads();
    float S  = r1[0] + r1[1] + r1[2] + r1[3];
    float S2 = r2[0] + r2[1] + r2[2] + r2[3];
    float mean = S * (1.f / 1365.f);
    float var  = S2 * (1.f / 1365.f) - mean * mean;
    float rstd = rsqrtf(fmaxf(var, 1e-5f));
    if (t == 0) { stats[2 * r] = mean * rstd; stats[2 * r + 1] = rstd; }
}

// --------------------- colsum[n] = sum_k W'[n][k]  (rows of converted W')
__global__ __launch_bounds__(64) void colsum_kernel(
    const ushort_t* __restrict__ Wt, float* __restrict__ colsum)
{
    int n = blockIdx.x, t = threadIdx.x;
    const ushort_t* row = Wt + (size_t)n * YSLD;
    float s = 0.f;
    for (int k = t; k < YSLD; k += 64) s += b2f(row[k]);
    #pragma unroll
    for (int o = 32; o > 0; o >>= 1) s += __shfl_down(s, o, 64);
    if (t == 0) colsum[n] = s;
}

// ================================================================ launcher
extern "C" void kernel_launch(void* const* d_in, const int* in_sizes, int n_in,
                              void* d_out, int out_size, void* d_ws, size_t ws_size,
                              hipStream_t stream)
{
    const float* x          = (const float*)d_in[0];
    const float* sa_ln_w    = (const float*)d_in[1];
    const float* sa_ln_b    = (const float*)d_in[2];
    const float* sa_wq      = (const float*)d_in[3];
    const float* sa_wkv     = (const float*)d_in[4];
    const float* sa_null_kv = (const float*)d_in[5];
    const float* sa_null_b  = (const float*)d_in[6];
    const float* sa_wout    = (const float*)d_in[7];
    const float* sa_oln_w   = (const float*)d_in[8];
    const float* sa_oln_b   = (const float*)d_in[9];
    const float* ta_ln_w    = (const float*)d_in[10];
    const float* ta_ln_b    = (const float*)d_in[11];
    const float* ta_wq      = (const float*)d_in[12];
    const float* ta_wkv     = (const float*)d_in[13];
    const float* ta_null_kv = (const float*)d_in[14];
    const float* ta_null_b  = (const float*)d_in[15];
    const float* ta_wout    = (const float*)d_in[16];
    const float* ta_oln_w   = (const float*)d_in[17];
    const float* ta_oln_b   = (const float*)d_in[18];
    const float* sp_w0      = (const float*)d_in[19];
    const float* sp_b0      = (const float*)d_in[20];
    const float* sp_w1      = (const float*)d_in[21];
    const float* sp_b1      = (const float*)d_in[22];
    const float* sp_w2      = (const float*)d_in[23];
    const float* sp_b2      = (const float*)d_in[24];
    const float* tp_w0      = (const float*)d_in[25];
    const float* tp_b0      = (const float*)d_in[26];
    const float* tp_w1      = (const float*)d_in[27];
    const float* tp_b1      = (const float*)d_in[28];
    const float* tp_w2      = (const float*)d_in[29];
    const float* tp_b2      = (const float*)d_in[30];
    const float* ff_win     = (const float*)d_in[31];
    const float* ff_g       = (const float*)d_in[32];
    const float* ff_wout    = (const float*)d_in[33];

    char* ws = (char*)d_ws;
    // regions (bytes)
    float*    RES   = (float*)(ws + 0);                        // residual, spatial layout
    ushort_t* XN16  = (ushort_t*)(ws + 33554432);              // xn / x2 bf16
    ushort_t* Q16   = (ushort_t*)(ws + 50331648);              // spatial Q bf16 (spatial phase)
    float*    RT    = (float*)(ws + 50331648);                 // temporal residual f32 (temporal phase)
    ushort_t* YS    = (ushort_t*)(ws + 50331648);              // FF shifted act bf16 [16384][1376]
    ushort_t* WSA   = (ushort_t*)(ws + 67108864);              // spatial weights (dead by FF)
    ushort_t* KP    = (ushort_t*)(ws + 83886080);              // 16x1056x64 bf16 (spatial)
    ushort_t* VTb   = (ushort_t*)(ws + 86048768);              // 16x64x1056 bf16 (spatial)
    ushort_t* KV16  = (ushort_t*)(ws + 83886080);              // temporal KV bf16
    ushort_t* WTA   = (ushort_t*)(ws + 90439680);              // temporal weights
    ushort_t* AO16  = (ushort_t*)(ws + 92274688);              // attn out bf16 (dead by FF)
    ushort_t* BI    = (ushort_t*)(ws + 96468992);              // FF interleaved W [2816][512]
    ushort_t* WFFB  = (ushort_t*)(ws + 99352576);              // W' = (ff_wout*g)^T [512][1376]
    ushort_t* BIAS16= (ushort_t*)(ws + 109051904);             // spatial bias bf16 (PRJ region)
    float*    PRJ   = (float*)(ws + 109051904);                // proj out f32
    ushort_t* Q16t  = (ushort_t*)(ws + 109051904);             // temporal Q bf16
    float*    STATS = (float*)(ws + 142606336);                // 16384 x (mean*rstd, rstd)
    float*    SPT   = (float*)(ws + 142737408);                // spatial CPB table (spatial phase)
    float*    COLSUM= (float*)(ws + 142737408);                // colsum[512] (FF phase, dead SPT)
    float*    TPT   = (float*)(ws + 142864448);

    ushort_t* WQ_T  = WSA;                 // [512][512]
    ushort_t* WKV_T = WSA + 262144;        // [128][512]
    ushort_t* WO_T  = WSA + 327680;        // [512][512]
    ushort_t* tWQ_T  = WTA;
    ushort_t* tWKV_T = WTA + 262144;
    ushort_t* tWO_T  = WTA + 327680;

    dim3 blk(256);
    const float QSCL = 0.125f * LOG2E;   // fold log2e into Q so softmax is exp2

    // bias tables
    cpb_kernel<<<dim3(249), blk, 0, stream>>>(sp_w0, sp_b0, sp_w1, sp_b1, sp_w2, sp_b2, SPT, 0, 3969);
    cpb_kernel<<<dim3(2),   blk, 0, stream>>>(tp_w0, tp_b0, tp_w1, tp_b1, tp_w2, tp_b2, TPT, 1, 31);
    bias_sp_kernel<<<dim3(1024, 8), blk, 0, stream>>>(SPT, sa_null_b, BIAS16);
    kvinit_kernel<<<dim3(16), blk, 0, stream>>>(sa_null_kv, KP, VTb);

    // ---------------- spatial ----------------
    wcvt_kernel<<<dim3(16, 16), blk, 0, stream>>>(sa_wq, 512, 0, WQ_T, 512, 512, 512, nullptr, 512);
    wcvt_kernel<<<dim3(4, 16),  blk, 0, stream>>>(sa_wkv, 128, 0, WKV_T, 512, 512, 128, nullptr, 128);
    wcvt_kernel<<<dim3(16, 16), blk, 0, stream>>>(sa_wout, 512, 0, WO_T, 512, 512, 512, nullptr, 512);
    transpose_in_kernel<<<dim3(512, 16), blk, 0, stream>>>(x, RES);
    ln_bf16_kernel<<<dim3(TOK), blk, 0, stream>>>(RES, XN16, sa_ln_w, sa_ln_b);
    gemm_mfma<3><<<dim3(512), blk, 0, stream>>>(XN16, 512, WQ_T, 512,
        nullptr, Q16, 512, TOK, 512, 512, QSCL, 4, nullptr, nullptr, nullptr, nullptr, nullptr, nullptr);
    gemm_mfma<4><<<dim3(128), blk, 0, stream>>>(XN16, 512, WKV_T, 512,
        nullptr, nullptr, 0, TOK, 128, 512, 1.0f, 1, nullptr, nullptr, nullptr, nullptr, KP, VTb);
    attn_sp_mfma<<<dim3(1024), blk, 0, stream>>>(Q16, KP, VTb, BIAS16, AO16);
    gemm_mfma<0><<<dim3(512), blk, 0, stream>>>(AO16, 512, WO_T, 512,
        PRJ, nullptr, 512, TOK, 512, 512, 1.0f, 4, nullptr, nullptr, nullptr, nullptr, nullptr, nullptr);
    // fused LN+residual + spatial->temporal permute (replaces ln_add + permute0)
    ln_add_sp_kernel<<<dim3(TOK), blk, 0, stream>>>(PRJ, RES, RT, sa_oln_w, sa_oln_b);

    // ---------------- temporal ----------------
    wcvt_kernel<<<dim3(16, 16), blk, 0, stream>>>(ta_wq, 512, 0, tWQ_T, 512, 512, 512, nullptr, 512);
    wcvt_kernel<<<dim3(4, 16),  blk, 0, stream>>>(ta_wkv, 128, 0, tWKV_T, 512, 512, 128, nullptr, 128);
    wcvt_kernel<<<dim3(16, 16), blk, 0, stream>>>(ta_wout, 512, 0, tWO_T, 512, 512, 512, nullptr, 512);
    ln_bf16_kernel<<<dim3(TOK), blk, 0, stream>>>(RT, XN16, ta_ln_w, ta_ln_b);
    gemm_mfma<3><<<dim3(512), blk, 0, stream>>>(XN16, 512, tWQ_T, 512,
        nullptr, Q16t, 512, TOK, 512, 512, QSCL, 4, nullptr, nullptr, nullptr, nullptr, nullptr, nullptr);
    gemm_mfma<3><<<dim3(128), blk, 0, stream>>>(XN16, 512, tWKV_T, 512,
        nullptr, KV16, 128, TOK, 128, 512, 1.0f, 1, nullptr, nullptr, nullptr, nullptr, nullptr, nullptr);
    attn_tp_kernel<<<dim3(1024), blk, 0, stream>>>(Q16t, KV16, ta_null_kv, ta_null_b, TPT, AO16);
    gemm_mfma<0><<<dim3(512), blk, 0, stream>>>(AO16, 512, tWO_T, 512,
        PRJ, nullptr, 512, TOK, 512, 512, 1.0f, 4, nullptr, nullptr, nullptr, nullptr, nullptr, nullptr);
    // fused LN+residual + temporal->spatial permute (replaces ln_add + permute1_dual)
    ln_add_tp_kernel<<<dim3(TOK), blk, 0, stream>>>(PRJ, RT, RES, XN16, ta_oln_w, ta_oln_b);

    // ---------------- feed-forward ----------------
    wcvt_kernel<<<dim3(44, 16), blk, 0, stream>>>(ff_win, 2730, 0,   BI,       1024, 512, FFI, nullptr, 1408);
    wcvt_kernel<<<dim3(44, 16), blk, 0, stream>>>(ff_win, 2730, FFI, BI + 512, 1024, 512, FFI, nullptr, 1408);
    wcvt_kernel<<<dim3(16, 43), blk, 0, stream>>>(ff_wout, 512, 0, WFFB, YSLD, FFI, 512, ff_g, 512);
    colsum_kernel<<<dim3(512), dim3(64), 0, stream>>>(WFFB, COLSUM);
    ff_gemm_fused<<<dim3(2816), blk, 0, stream>>>(XN16, BI, YS);
    rowstats_bf16_kernel<<<dim3(TOK), blk, 0, stream>>>(YS, STATS);
    gemm_mfma<5><<<dim3(512), blk, 0, stream>>>(YS, YSLD, WFFB, YSLD,
        nullptr, nullptr, 0, TOK, 512, YSLD, 1.0f, 4, STATS, COLSUM, RES, (float*)d_out, nullptr, nullptr);
}

// Round 11
// 754.872 us; speedup vs baseline: 1.1614x; 1.0147x over previous
//
#include <hip/hip_runtime.h>
#include <math.h>

#define TOK 16384
#define DIMC 512
#define FFI 1365
#define CH1 683
#define YSLD 1376         // YS row stride (bf16 elements, 16B aligned)
#define KVPAD 1056        // padded key count for spatial attn (mult of 8)
#define BSTRIDE 1152      // BIASX row stride (cols: 0=null, 1..1024=keys, rest=mask)
#define MASKB (-30000.f)  // softmax mask bias (bf16-safe, no near-inf)
#define LOG2E 1.4426950408889634f

typedef unsigned int u32;
typedef unsigned short ushort_t;
typedef __attribute__((ext_vector_type(8))) short bf16x8;
typedef __attribute__((ext_vector_type(4))) float f32x4;

__device__ inline ushort_t f2b(float x) {
    u32 u = __float_as_uint(x);
    u32 r = (u + 0x7fffu + ((u >> 16) & 1u)) >> 16;
    return (ushort_t)r;
}
__device__ inline float b2f(ushort_t u) { return __uint_as_float(((u32)u) << 16); }

__device__ inline float exp2_fast(float x) {
    float r;
    asm("v_exp_f32 %0, %1" : "=v"(r) : "v"(x));
    return r;
}

// pack two f32 -> {bf16(hi)<<16 | bf16(lo)}  (RTNE, gfx950)
__device__ inline u32 cvt_pk_bf16(float lo, float hi) {
    u32 r;
    asm("v_cvt_pk_bf16_f32 %0, %1, %2" : "=v"(r) : "v"(lo), "v"(hi));
    return r;
}

__device__ inline void gload_lds16(const void* g, void* l) {
    __builtin_amdgcn_global_load_lds(
        (const __attribute__((address_space(1))) u32*)g,
        (__attribute__((address_space(3))) u32*)l, 16, 0, 0);
}

__device__ inline float gelu_exact(float x) {
    return 0.5f * x * (1.f + erff(x * 0.70710678118654752f));
}

// counted-vmcnt helpers (immediates must be literals in the asm string)
__device__ inline void waitcnt_vm4() {
    asm volatile("s_waitcnt vmcnt(4)" ::: "memory");
    __builtin_amdgcn_sched_barrier(0);
}
__device__ inline void waitcnt_vm0() {
    asm volatile("s_waitcnt vmcnt(0)" ::: "memory");
    __builtin_amdgcn_sched_barrier(0);
}

// ---------------------------------------------------------------- CPB MLP
// 16 rows per block (w1 re-read traffic 1 GB -> 62 MB). FP order preserved.
__global__ __launch_bounds__(256) void cpb_kernel(
    const float* __restrict__ w0, const float* __restrict__ b0,
    const float* __restrict__ w1, const float* __restrict__ b1,
    const float* __restrict__ w2, const float* __restrict__ b2,
    float* __restrict__ table, int mode, int nrows)
{
    __shared__ float t0[16][256];
    __shared__ float t1[16][256];
    int r0 = blockIdx.x * 16;
    int t = threadIdx.x;
    float w0t = w0[t], b0t = b0[t];
    float w0t2 = (mode == 0) ? w0[256 + t] : 0.f;
    #pragma unroll
    for (int rr = 0; rr < 16; ++rr) {
        int r = r0 + rr; if (r >= nrows) r = nrows - 1;
        float c0, c1;
        if (mode == 0) { c0 = (float)(r / 63 - 31); c1 = (float)(r % 63 - 31); }
        else           { c0 = (float)(r - 15);      c1 = 0.f; }
        float a = c0 * w0t + b0t;
        if (mode == 0) a += c1 * w0t2;
        t0[rr][t] = a / (1.f + __expf(-a));
    }
    __syncthreads();
    float b1t = b1[t];
    float acc[16];
    #pragma unroll
    for (int rr = 0; rr < 16; ++rr) acc[rr] = b1t;
    for (int k = 0; k < 256; ++k) {
        float w = w1[k * 256 + t];
        #pragma unroll
        for (int rr = 0; rr < 16; ++rr) acc[rr] += t0[rr][k] * w;
    }
    #pragma unroll
    for (int rr = 0; rr < 16; ++rr) {
        float s = acc[rr];
        t1[rr][t] = s / (1.f + __expf(-s));
    }
    __syncthreads();
    if (t < 128) {
        int rr = t >> 3, oo = t & 7;
        int r = r0 + rr;
        if (r < nrows) {
            float o = b2[oo];
            for (int k = 0; k < 256; ++k) o += t1[rr][k] * w2[k * 8 + oo];
            table[r * 8 + oo] = o;
        }
    }
}

// ------------------------------- materialize spatial bias bf16, padded layout
// NOTE: bias is pre-scaled by LOG2E (softmax uses exp2)
__global__ __launch_bounds__(256) void bias_sp_kernel(
    const float* __restrict__ tab, const float* __restrict__ nullbias,
    ushort_t* __restrict__ out)
{
    int pi = blockIdx.x, h = blockIdx.y;
    int phi = pi >> 5, pwi = pi & 31;
    ushort_t* row = out + ((size_t)h * 1024 + pi) * BSTRIDE;
    for (int c = threadIdx.x; c < BSTRIDE; c += 256) {
        float v;
        if (c == 0) v = nullbias[h];
        else if (c <= 1024) {
            int pj = c - 1;
            int phj = pj >> 5, pwj = pj & 31;
            int idx = (phi - phj + 31) * 63 + (pwi - pwj + 31);
            v = tab[idx * 8 + h];
        } else v = MASKB;
        row[c] = f2b(v * LOG2E);
    }
}

// -------------------------------------------- KP/VT pad+null init. grid 16
__global__ __launch_bounds__(256) void kvinit_kernel(
    const float* __restrict__ nullkv, ushort_t* __restrict__ KP, ushort_t* __restrict__ VT)
{
    int f = blockIdx.x, t = threadIdx.x;
    for (int e = t; e < 32 * 64; e += 256) {
        int rr = e >> 6, d = e & 63;
        int row = (rr == 0) ? 0 : (1024 + rr);
        KP[((size_t)f * KVPAD + row) * 64 + d] = (rr == 0) ? f2b(nullkv[d]) : (ushort_t)0;
    }
    for (int e = t; e < 64 * 32; e += 256) {
        int d = e >> 5, cc = e & 31;
        int col = (cc == 0) ? 0 : (1024 + cc);
        VT[((size_t)f * 64 + d) * KVPAD + col] = (cc == 0) ? f2b(nullkv[64 + d]) : (ushort_t)0;
    }
}

// ---------------- weight convert: W[K][ldw] (col window c0) -> Bt[N][Kp] bf16
// Writes rows n < Nwrite (zeros for n >= Ncols or k >= K) — pad rows are clean.
__global__ __launch_bounds__(256) void wcvt_kernel(
    const float* __restrict__ W, int ldw, int c0,
    ushort_t* __restrict__ Bt, int Kp, int K, int Ncols,
    const float* __restrict__ gv, int Nwrite)
{
    __shared__ float tile[32][33];
    int nb = blockIdx.x * 32, kb = blockIdx.y * 32;
    int tx = threadIdx.x & 31, ty = threadIdx.x >> 5;
    #pragma unroll
    for (int it = 0; it < 4; ++it) {
        int k = kb + ty + it * 8, n = nb + tx;
        float v = (k < K && n < Ncols) ? W[(size_t)k * ldw + c0 + n] : 0.f;
        if (gv && k < K) v *= gv[k];
        tile[ty + it * 8][tx] = v;
    }
    __syncthreads();
    #pragma unroll
    for (int it = 0; it < 4; ++it) {
        int n = nb + ty + it * 8, k = kb + tx;
        if (n < Nwrite && k < Kp) Bt[(size_t)n * Kp + k] = f2b(tile[tx][ty + it * 8]);
    }
}

// ---------------------------------------------------- (C,T) -> (T,C) transpose
__global__ __launch_bounds__(256) void transpose_in_kernel(
    const float* __restrict__ x, float* __restrict__ dst)
{
    __shared__ float tile[32][33];
    int t0b = blockIdx.x * 32, c0b = blockIdx.y * 32;
    int tx = threadIdx.x & 31, ty = threadIdx.x >> 5;
    #pragma unroll
    for (int it = 0; it < 4; ++it) {
        int c = ty + it * 8;
        tile[c][tx] = x[(size_t)(c0b + c) * TOK + t0b + tx];
    }
    __syncthreads();
    #pragma unroll
    for (int it = 0; it < 4; ++it) {
        int tr = ty + it * 8;
        dst[(size_t)(t0b + tr) * DIMC + c0b + tx] = tile[tx][tr];
    }
}

// ---------------------------------------------------------------- LayerNorm → bf16
__global__ __launch_bounds__(256) void ln_bf16_kernel(
    const float* __restrict__ in, ushort_t* __restrict__ out,
    const float* __restrict__ w, const float* __restrict__ b)
{
    __shared__ float r1[4], r2[4];
    size_t base = (size_t)blockIdx.x * DIMC;
    int t = threadIdx.x;
    float x0 = in[base + t], x1 = in[base + 256 + t];
    float s = x0 + x1, s2 = x0 * x0 + x1 * x1;
    #pragma unroll
    for (int o = 32; o > 0; o >>= 1) { s += __shfl_down(s, o, 64); s2 += __shfl_down(s2, o, 64); }
    if ((t & 63) == 0) { r1[t >> 6] = s; r2[t >> 6] = s2; }
    __syncthreads();
    float mean = (r1[0] + r1[1] + r1[2] + r1[3]) * (1.f / 512.f);
    float ex2  = (r2[0] + r2[1] + r2[2] + r2[3]) * (1.f / 512.f);
    float rstd = rsqrtf(ex2 - mean * mean + 1e-5f);
    out[base + t]       = f2b((x0 - mean) * rstd * w[t] + b[t]);
    out[base + 256 + t] = f2b((x1 - mean) * rstd * w[256 + t] + b[256 + t]);
}

// ---------------- spatial LN(proj)+residual, fused spatial->temporal permute
// + ROUND-20: fused temporal input-LN (replaces the separate ln_bf16(RT)):
// writes RT f32 (residual for temporal phase) AND XN16 = bf16(LN(v; ta_ln)).
__global__ __launch_bounds__(256) void ln_add_sp_kernel(
    const float* __restrict__ proj, const float* __restrict__ resid,
    float* __restrict__ dstT, ushort_t* __restrict__ dstB,
    const float* __restrict__ w, const float* __restrict__ b,
    const float* __restrict__ lnw, const float* __restrict__ lnb)
{
    __shared__ float r1[4], r2[4];
    int s = blockIdx.x;
    size_t base = (size_t)s * DIMC;
    int t = threadIdx.x;
    float x0 = proj[base + t], x1 = proj[base + 256 + t];
    float sa = x0 + x1, s2 = x0 * x0 + x1 * x1;
    #pragma unroll
    for (int o = 32; o > 0; o >>= 1) { sa += __shfl_down(sa, o, 64); s2 += __shfl_down(s2, o, 64); }
    if ((t & 63) == 0) { r1[t >> 6] = sa; r2[t >> 6] = s2; }
    __syncthreads();
    float mean = (r1[0] + r1[1] + r1[2] + r1[3]) * (1.f / 512.f);
    float ex2  = (r2[0] + r2[1] + r2[2] + r2[3]) * (1.f / 512.f);
    float rstd = rsqrtf(ex2 - mean * mean + 1e-5f);
    int rd = (s & 1023) * 16 + (s >> 10);           // spatial row -> temporal row
    size_t ob = (size_t)rd * DIMC;
    float v0 = resid[base + t]       + (x0 - mean) * rstd * w[t] + b[t];
    float v1 = resid[base + 256 + t] + (x1 - mean) * rstd * w[256 + t] + b[256 + t];
    dstT[ob + t]       = v0;
    dstT[ob + 256 + t] = v1;
    // second reduction: LN of v (temporal attn input), identical structure
    __syncthreads();                                 // r1/r2 reuse safety
    float sb = v0 + v1, sb2 = v0 * v0 + v1 * v1;
    #pragma unroll
    for (int o = 32; o > 0; o >>= 1) { sb += __shfl_down(sb, o, 64); sb2 += __shfl_down(sb2, o, 64); }
    if ((t & 63) == 0) { r1[t >> 6] = sb; r2[t >> 6] = sb2; }
    __syncthreads();
    float mean2 = (r1[0] + r1[1] + r1[2] + r1[3]) * (1.f / 512.f);
    float ex22  = (r2[0] + r2[1] + r2[2] + r2[3]) * (1.f / 512.f);
    float rstd2 = rsqrtf(ex22 - mean2 * mean2 + 1e-5f);
    dstB[ob + t]       = f2b((v0 - mean2) * rstd2 * lnw[t] + lnb[t]);
    dstB[ob + 256 + t] = f2b((v1 - mean2) * rstd2 * lnw[256 + t] + lnb[256 + t]);
}

// ---------------- temporal LN(proj)+residual, fused temporal->spatial permute
// Reads PRJ + RT (read-only), writes RES (f32) + XN16 (bf16) at permuted rows.
__global__ __launch_bounds__(256) void ln_add_tp_kernel(
    const float* __restrict__ proj, const float* __restrict__ resid,
    float* __restrict__ dstF, ushort_t* __restrict__ dstB,
    const float* __restrict__ w, const float* __restrict__ b)
{
    __shared__ float r1[4], r2[4];
    int tt = blockIdx.x;
    size_t base = (size_t)tt * DIMC;
    int t = threadIdx.x;
    float x0 = proj[base + t], x1 = proj[base + 256 + t];
    float sa = x0 + x1, s2 = x0 * x0 + x1 * x1;
    #pragma unroll
    for (int o = 32; o > 0; o >>= 1) { sa += __shfl_down(sa, o, 64); s2 += __shfl_down(s2, o, 64); }
    if ((t & 63) == 0) { r1[t >> 6] = sa; r2[t >> 6] = s2; }
    __syncthreads();
    float mean = (r1[0] + r1[1] + r1[2] + r1[3]) * (1.f / 512.f);
    float ex2  = (r2[0] + r2[1] + r2[2] + r2[3]) * (1.f / 512.f);
    float rstd = rsqrtf(ex2 - mean * mean + 1e-5f);
    float v0 = resid[base + t]       + (x0 - mean) * rstd * w[t] + b[t];
    float v1 = resid[base + 256 + t] + (x1 - mean) * rstd * w[256 + t] + b[256 + t];
    int sd = (tt & 15) * 1024 + (tt >> 4);          // temporal row -> spatial row
    size_t ob = (size_t)sd * DIMC;
    dstF[ob + t]       = v0;
    dstF[ob + 256 + t] = v1;
    dstB[ob + t]       = f2b(v0);
    dstB[ob + 256 + t] = f2b(v1);
}

// ---------------------------------------------------------------- MFMA GEMM
// 1-D grid of nx*16*8 blocks. XCD-aware swizzle: xcd = lin&7 owns m-tiles
// [xcd*16, xcd*16+16) for ALL nx n-tiles -> per-XCD L2-resident A band.
// Round-5 measured-best schedule (2-buffer: vmcnt(4) -> s_barrier -> compute
// -> s_barrier -> stage(t+2)) + hoisted incremental pointers.
// ROUND-20: EPI6/EPI7 merged Q+KV projections (B = [WQ; WKV] contiguous,
// N=640): n<512 -> Q (scaled), n>=512 -> KV routing (unscaled).
template<int EPI>
__global__ __launch_bounds__(256) void gemm_mfma(
    const ushort_t* __restrict__ A, int lda,
    const ushort_t* __restrict__ Bt, int Kp,
    float* __restrict__ C, ushort_t* __restrict__ Cb, int ldc,
    int M, int N, int K, float scale, int nx,
    const float* __restrict__ stats, const float* __restrict__ g,
    const float* __restrict__ resid, float* __restrict__ outT,
    ushort_t* __restrict__ KPo, ushort_t* __restrict__ VTo)
{
    __shared__ __align__(16) ushort_t As[2][4 * 128 * 8];
    __shared__ __align__(16) ushort_t Bs[2][4 * 128 * 8];
    int lin = blockIdx.x;
    int xcd = lin & 7, idx = lin >> 3;
    int m0 = (xcd * 16 + (idx & 15)) * 128;
    int n0 = (idx >> 4) * 128;
    int tid = threadIdx.x, lane = tid & 63, wid = tid >> 6;
    int wy = wid >> 1, wx = wid & 1, quad = lane >> 4, l16 = lane & 15;
    bool bfull = (n0 + 128 <= N);
    f32x4 acc[4][4];
    #pragma unroll
    for (int i = 0; i < 4; ++i)
        #pragma unroll
        for (int j = 0; j < 4; ++j) { acc[i][j][0]=0.f; acc[i][j][1]=0.f; acc[i][j][2]=0.f; acc[i][j][3]=0.f; }

    if (bfull) {
        int NT = K >> 5;
        int c0 = wid * 128 + lane, c1 = wid * 128 + 64 + lane;
        const ushort_t* gA0 = A + (size_t)(m0 + (c0 & 127)) * lda + (c0 >> 7) * 8;
        const ushort_t* gA1 = A + (size_t)(m0 + (c1 & 127)) * lda + (c1 >> 7) * 8;
        const ushort_t* gB0 = Bt + (size_t)(n0 + (c0 & 127)) * Kp + (c0 >> 7) * 8;
        const ushort_t* gB1 = Bt + (size_t)(n0 + (c1 & 127)) * Kp + (c1 >> 7) * 8;
        const int lo0 = (wid * 128) * 8, lo1 = (wid * 128 + 64) * 8;
        auto stage = [&](int buf) {
            gload_lds16(gA0, &As[buf][lo0]);
            gload_lds16(gA1, &As[buf][lo1]);
            gload_lds16(gB0, &Bs[buf][lo0]);
            gload_lds16(gB1, &Bs[buf][lo1]);
            gA0 += 32; gA1 += 32; gB0 += 32; gB1 += 32;
        };
        stage(0);
        if (NT > 1) stage(1);
        for (int t = 0; t < NT; ++t) {
            if (t + 1 < NT) waitcnt_vm4(); else waitcnt_vm0();
            __builtin_amdgcn_s_barrier();
            int cur = t & 1;
            bf16x8 af[4], bfr[4];
            #pragma unroll
            for (int i = 0; i < 4; ++i) af[i] = *(bf16x8*)&As[cur][(quad * 128 + wy * 64 + i * 16 + l16) * 8];
            #pragma unroll
            for (int j = 0; j < 4; ++j) bfr[j] = *(bf16x8*)&Bs[cur][(quad * 128 + wx * 64 + j * 16 + l16) * 8];
            #pragma unroll
            for (int i = 0; i < 4; ++i)
                #pragma unroll
                for (int j = 0; j < 4; ++j)
                    acc[i][j] = __builtin_amdgcn_mfma_f32_16x16x32_bf16(af[i], bfr[j], acc[i][j], 0, 0, 0);
            if (t + 2 < NT) {
                __builtin_amdgcn_s_barrier();
                stage(cur);
            }
        }
    } else {
        // conservative fallback (not taken by current launches)
        for (int k0 = 0; k0 < K; k0 += 32) {
            if (k0) __syncthreads();
            #pragma unroll
            for (int r = 0; r < 2; ++r) {
                int c = wid * 128 + r * 64 + lane;
                const ushort_t* src = A + (size_t)(m0 + (c & 127)) * lda + k0 + (c >> 7) * 8;
                gload_lds16(src, &As[0][(wid * 128 + r * 64) * 8]);
            }
            #pragma unroll
            for (int r = 0; r < 2; ++r) {
                int c = tid + r * 256;
                int kg = c >> 7, nloc = c & 127;
                bf16x8 v;
                if (n0 + nloc < N) v = *(const bf16x8*)(Bt + (size_t)(n0 + nloc) * Kp + k0 + kg * 8);
                else { for (int e = 0; e < 8; ++e) v[e] = 0; }
                *(bf16x8*)&Bs[0][c * 8] = v;
            }
            __syncthreads();
            bf16x8 af[4], bfr[4];
            #pragma unroll
            for (int i = 0; i < 4; ++i) af[i] = *(bf16x8*)&As[0][(quad * 128 + wy * 64 + i * 16 + l16) * 8];
            #pragma unroll
            for (int j = 0; j < 4; ++j) bfr[j] = *(bf16x8*)&Bs[0][(quad * 128 + wx * 64 + j * 16 + l16) * 8];
            #pragma unroll
            for (int i = 0; i < 4; ++i)
                #pragma unroll
                for (int j = 0; j < 4; ++j)
                    acc[i][j] = __builtin_amdgcn_mfma_f32_16x16x32_bf16(af[i], bfr[j], acc[i][j], 0, 0, 0);
        }
    }
    #pragma unroll
    for (int i = 0; i < 4; ++i) {
        #pragma unroll
        for (int j = 0; j < 4; ++j) {
            #pragma unroll
            for (int r = 0; r < 4; ++r) {
                int m = m0 + wy * 64 + i * 16 + quad * 4 + r;
                int n = n0 + wx * 64 + j * 16 + l16;
                if (n >= N) continue;
                float raw = acc[i][j][r];
                float v = raw * scale;
                if (EPI == 0) {
                    C[(size_t)m * ldc + n] = v;
                } else if (EPI == 3) {
                    Cb[(size_t)m * ldc + n] = f2b(v);
                } else if (EPI == 5) {
                    float s0 = stats[2 * m], s1 = stats[2 * m + 1];
                    outT[(size_t)n * TOK + m] = v * s1 - s0 * g[n] + resid[(size_t)m * DIMC + n];
                } else if (EPI == 6) {
                    // merged spatial: n<512 -> Q16 (scaled); else KP/VT (raw)
                    if (n < 512) {
                        Cb[(size_t)m * 512 + n] = f2b(v);
                    } else {
                        int frame = m >> 10, tt = m & 1023;
                        int d = n - 512;
                        if (d < 64) KPo[((size_t)frame * KVPAD + 1 + tt) * 64 + d] = f2b(raw);
                        else        VTo[((size_t)frame * 64 + (d - 64)) * KVPAD + 1 + tt] = f2b(raw);
                    }
                } else if (EPI == 7) {
                    // merged temporal: n<512 -> Q16t (scaled); else KV16 (raw)
                    if (n < 512) Cb[(size_t)m * 512 + n] = f2b(v);
                    else         KPo[(size_t)m * 128 + (n - 512)] = f2b(raw);
                }
            }
        }
    }
}

// ------------------------------------------- fused FF front GEMM (a & gate)
// 128m x 64n dual-output tile -> acc = 64 AGPR/thread. B from interleaved
// BI[2816][512] via pure global_load_lds. Grid 2816 = 8 XCD x 16 m x 22 n.
// Round-5 schedule + hoisted incremental pointers.
__global__ __launch_bounds__(256) void ff_gemm_fused(
    const ushort_t* __restrict__ A,
    const ushort_t* __restrict__ BI,
    ushort_t* __restrict__ YS)
{
    __shared__ __align__(16) ushort_t As[2][4 * 128 * 8];
    __shared__ __align__(16) ushort_t Bs[2][4 * 2 * 64 * 8];
    int lin = blockIdx.x;
    int xcd = lin & 7, idx = lin >> 3;
    int m0 = (xcd * 16 + (idx & 15)) * 128;
    int n0 = (idx >> 4) * 64;
    int tid = threadIdx.x, lane = tid & 63, wid = tid >> 6;
    int wy = wid >> 1, wx = wid & 1, quad = lane >> 4, l16 = lane & 15;
    f32x4 aA[4][2], aG[4][2];
    #pragma unroll
    for (int i = 0; i < 4; ++i)
        #pragma unroll
        for (int j = 0; j < 2; ++j) {
            aA[i][j][0]=0.f; aA[i][j][1]=0.f; aA[i][j][2]=0.f; aA[i][j][3]=0.f;
            aG[i][j][0]=0.f; aG[i][j][1]=0.f; aG[i][j][2]=0.f; aG[i][j][3]=0.f;
        }

    int c0 = wid * 128 + lane, c1 = wid * 128 + 64 + lane;
    const ushort_t* gA0 = A + (size_t)(m0 + (c0 & 127)) * 512 + (c0 >> 7) * 8;
    const ushort_t* gA1 = A + (size_t)(m0 + (c1 & 127)) * 512 + (c1 >> 7) * 8;
    const ushort_t* gB0 = BI + (size_t)((n0 + lane) * 2 + 0) * 512 + wid * 8;
    const ushort_t* gB1 = BI + (size_t)((n0 + lane) * 2 + 1) * 512 + wid * 8;
    const int lo0 = (wid * 128) * 8, lo1 = (wid * 128 + 64) * 8;
    auto stage = [&](int buf) {
        gload_lds16(gA0, &As[buf][lo0]);
        gload_lds16(gA1, &As[buf][lo1]);
        gload_lds16(gB0, &Bs[buf][lo0]);
        gload_lds16(gB1, &Bs[buf][lo1]);
        gA0 += 32; gA1 += 32; gB0 += 32; gB1 += 32;
    };

    stage(0); stage(1);
    for (int t = 0; t < 16; ++t) {
        if (t + 1 < 16) waitcnt_vm4(); else waitcnt_vm0();
        __builtin_amdgcn_s_barrier();
        int cur = t & 1;
        bf16x8 af[4], ba[2], bg[2];
        #pragma unroll
        for (int i = 0; i < 4; ++i) af[i] = *(bf16x8*)&As[cur][(quad * 128 + wy * 64 + i * 16 + l16) * 8];
        #pragma unroll
        for (int j = 0; j < 2; ++j) {
            int nn = wx * 32 + j * 16 + l16;
            ba[j] = *(bf16x8*)&Bs[cur][(quad * 128 + nn) * 8];
            bg[j] = *(bf16x8*)&Bs[cur][(quad * 128 + 64 + nn) * 8];
        }
        #pragma unroll
        for (int i = 0; i < 4; ++i)
            #pragma unroll
            for (int j = 0; j < 2; ++j) {
                aA[i][j] = __builtin_amdgcn_mfma_f32_16x16x32_bf16(af[i], ba[j], aA[i][j], 0, 0, 0);
                aG[i][j] = __builtin_amdgcn_mfma_f32_16x16x32_bf16(af[i], bg[j], aG[i][j], 0, 0, 0);
            }
        if (t + 2 < 16) {
            __builtin_amdgcn_s_barrier();
            stage(cur);
        }
    }
    #pragma unroll
    for (int i = 0; i < 4; ++i) {
        #pragma unroll
        for (int j = 0; j < 2; ++j) {
            #pragma unroll
            for (int r = 0; r < 4; ++r) {
                int m = m0 + wy * 64 + i * 16 + quad * 4 + r;
                int n = n0 + wx * 32 + j * 16 + l16;
                if (n >= FFI) {
                    if (n < YSLD) YS[(size_t)m * YSLD + n] = 0;   // zero pad cols
                    continue;
                }
                float v = aA[i][j][r] * gelu_exact(aG[i][j][r]);
                int dr = (n < CH1) ? m : m + 1024;
                if (dr < TOK) YS[(size_t)dr * YSLD + n] = f2b(v);
                if (n >= CH1 && m < 1024) YS[(size_t)m * YSLD + n] = 0;
            }
        }
    }
}

// --------------------------------------------------- spatial attention (MFMA flash)
// QBLK=16 (measured best: 116 VGPR, 4 waves/SIMD). Grid 1024 = 8 xcd x 8 qt
// x 16 frames. Softmax: no online-max (bounded base-2 logits), row-sum via
// MFMA ones-column, cvt_pk pack, ds_bpermute in-register transpose.
__global__ __launch_bounds__(256) void attn_sp_mfma(
    const ushort_t* __restrict__ Q,      // [16384][512] bf16 pre-scaled by 0.125*log2e
    const ushort_t* __restrict__ KP,     // [16][1056][64]
    const ushort_t* __restrict__ VT,     // [16][64][1056]
    const ushort_t* __restrict__ BIASX,  // [8][1024][1152], pre-scaled by log2e
    ushort_t* __restrict__ O)            // [16384][512] bf16
{
    __shared__ __align__(16) ushort_t Ks[128 * 64];
    __shared__ __align__(16) ushort_t Vs[64 * 128];
    int lin = blockIdx.x;
    int xcd = lin & 7, idx = lin >> 3;
    int qt = xcd * 8 + (idx & 7);
    int frame = idx >> 3;
    int q0 = qt * 16;
    int tid = threadIdx.x, lane = tid & 63, wid = tid >> 6;
    int quad = lane >> 4, l16 = lane & 15;

    bf16x8 aQ[2][2];
    const ushort_t* brow[2];
    #pragma unroll
    for (int i = 0; i < 2; ++i) {
        int h = wid * 2 + i;
        const ushort_t* qp = Q + (size_t)(frame * 1024 + q0 + l16) * 512 + h * 64 + quad * 8;
        aQ[i][0] = *(const bf16x8*)qp;
        aQ[i][1] = *(const bf16x8*)(qp + 32);
        brow[i] = BIASX + ((size_t)h * 1024 + q0 + l16) * BSTRIDE;
    }
    f32x4 Oc[2][4];
    f32x4 Oc4[2];   // row-sum accumulator (ones-column PV)
    #pragma unroll
    for (int i = 0; i < 2; ++i) {
        #pragma unroll
        for (int nt = 0; nt < 4; ++nt) { Oc[i][nt][0]=0.f; Oc[i][nt][1]=0.f; Oc[i][nt][2]=0.f; Oc[i][nt][3]=0.f; }
        Oc4[i][0]=0.f; Oc4[i][1]=0.f; Oc4[i][2]=0.f; Oc4[i][3]=0.f;
    }
    bf16x8 vones;
    #pragma unroll
    for (int e = 0; e < 8; ++e) vones[e] = (short)0x3F80;   // bf16 1.0

    // bpermute byte-indices for the in-register P transpose:
    // target (quad,l16) word w pulls from lane (2*(quad&1)+(w>>1))*16 + l16
    int idxA = (((quad & 1) * 32) + l16) * 4;   // w = 0,1
    int idxB = idxA + 64;                       // w = 2,3
    bool hiq = (quad >= 2);                     // selects j = 2ks+1

    for (int jt = 0; jt < 9; ++jt) {
        __syncthreads();
        #pragma unroll
        for (int r = 0; r < 4; ++r) {
            int L = wid * 256 + r * 64 + lane;
            int c = L >> 3, gp = L & 7, gg = gp ^ (c & 7);
            int jj = jt * 128 + c; if (jj > KVPAD - 1) jj = KVPAD - 1;
            gload_lds16(KP + ((size_t)frame * KVPAD + jj) * 64 + gg * 8, &Ks[(wid * 256 + r * 64) * 8]);
        }
        #pragma unroll
        for (int r = 0; r < 4; ++r) {
            int L = wid * 256 + r * 64 + lane;
            int d = L >> 4, cgp = L & 15;
            int cg = (cgp & 8) | ((cgp & 7) ^ (d & 7));
            int col = jt * 128 + cg * 8; if (col > KVPAD - 8) col = KVPAD - 8;
            gload_lds16(VT + ((size_t)frame * 64 + d) * KVPAD + col, &Vs[(wid * 256 + r * 64) * 8]);
        }
        __syncthreads();

        #pragma unroll
        for (int i = 0; i < 2; ++i) {
            // ---- QK^T for this head
            f32x4 S[8];
            #pragma unroll
            for (int j = 0; j < 8; ++j) { S[j][0]=0.f; S[j][1]=0.f; S[j][2]=0.f; S[j][3]=0.f; }
            __builtin_amdgcn_s_setprio(1);
            #pragma unroll
            for (int j = 0; j < 8; ++j) {
                int c = j * 16 + l16;
                #pragma unroll
                for (int ks = 0; ks < 2; ++ks) {
                    bf16x8 kb = *(bf16x8*)&Ks[(c * 8 + ((ks * 4 + quad) ^ (c & 7))) * 8];
                    S[j] = __builtin_amdgcn_mfma_f32_16x16x32_bf16(kb, aQ[i][ks], S[j], 0, 0, 0);
                }
            }
            __builtin_amdgcn_s_setprio(0);
            // ---- bias add + direct exp2 (no max tracking: base-2 logits are
            // small/bounded; MASKB*log2e underflows exp2 to exactly 0)
            #pragma unroll
            for (int j = 0; j < 8; ++j) {
                int kbase = jt * 128 + j * 16 + quad * 4;
                uint2 bv = *(const uint2*)(brow[i] + kbase);
                S[j][0] = exp2_fast(S[j][0] + __uint_as_float(bv.x << 16));
                S[j][1] = exp2_fast(S[j][1] + __uint_as_float(bv.x & 0xffff0000u));
                S[j][2] = exp2_fast(S[j][2] + __uint_as_float(bv.y << 16));
                S[j][3] = exp2_fast(S[j][3] + __uint_as_float(bv.y & 0xffff0000u));
            }
            // ---- pack (cvt_pk) + in-register transpose (ds_bpermute) + PV
            __builtin_amdgcn_s_setprio(1);
            #pragma unroll
            for (int ks = 0; ks < 4; ++ks) {
                int jl = 2 * ks, jh = 2 * ks + 1;
                u32 pxl = cvt_pk_bf16(S[jl][0], S[jl][1]);
                u32 pyl = cvt_pk_bf16(S[jl][2], S[jl][3]);
                u32 pxh = cvt_pk_bf16(S[jh][0], S[jh][1]);
                u32 pyh = cvt_pk_bf16(S[jh][2], S[jh][3]);
                u32 a0 = (u32)__builtin_amdgcn_ds_bpermute(idxA, (int)pxl);
                u32 a1 = (u32)__builtin_amdgcn_ds_bpermute(idxA, (int)pxh);
                u32 b0 = (u32)__builtin_amdgcn_ds_bpermute(idxA, (int)pyl);
                u32 b1 = (u32)__builtin_amdgcn_ds_bpermute(idxA, (int)pyh);
                u32 c0 = (u32)__builtin_amdgcn_ds_bpermute(idxB, (int)pxl);
                u32 c1 = (u32)__builtin_amdgcn_ds_bpermute(idxB, (int)pxh);
                u32 d0 = (u32)__builtin_amdgcn_ds_bpermute(idxB, (int)pyl);
                u32 d1 = (u32)__builtin_amdgcn_ds_bpermute(idxB, (int)pyh);
                union { u32 w[4]; bf16x8 v; } pa;
                pa.w[0] = hiq ? a1 : a0;
                pa.w[1] = hiq ? b1 : b0;
                pa.w[2] = hiq ? c1 : c0;
                pa.w[3] = hiq ? d1 : d0;
                #pragma unroll
                for (int nt = 0; nt < 4; ++nt) {
                    int d = nt * 16 + l16;
                    int cg = ks * 4 + quad;
                    int phys = (cg & 8) | ((cg & 7) ^ (d & 7));
                    bf16x8 vb = *(bf16x8*)&Vs[(d * 16 + phys) * 8];
                    Oc[i][nt] = __builtin_amdgcn_mfma_f32_16x16x32_bf16(pa.v, vb, Oc[i][nt], 0, 0, 0);
                }
                // ones-column: accumulates row-sum of P in matching layout
                Oc4[i] = __builtin_amdgcn_mfma_f32_16x16x32_bf16(pa.v, vones, Oc4[i], 0, 0, 0);
            }
            __builtin_amdgcn_s_setprio(0);
        }
    }
    #pragma unroll
    for (int i = 0; i < 2; ++i) {
        int h = wid * 2 + i;
        #pragma unroll
        for (int r = 0; r < 4; ++r) {
            float linv = 1.f / Oc4[i][r];   // same (q,row) layout as Oc — no shuffle
            int ql = quad * 4 + r;
            #pragma unroll
            for (int nt = 0; nt < 4; ++nt) {
                int d = nt * 16 + l16;
                O[(size_t)(frame * 1024 + q0 + ql) * 512 + h * 64 + d] = f2b(Oc[i][nt][r] * linv);
            }
        }
    }
}

// ---------------------------------------------------------------- temporal attention
// Padded LDS (qs 516, ks/vs 68) to break power-of-2 row-stride bank
// conflicts on the float4 reads. FP order preserved element-wise.
__global__ __launch_bounds__(256) void attn_tp_kernel(
    const ushort_t* __restrict__ q, const ushort_t* __restrict__ kv,
    const float* __restrict__ nullkv, const float* __restrict__ nullbias,
    const float* __restrict__ table, ushort_t* __restrict__ out)
{
    __shared__ float qs[16][516];
    __shared__ float ks[17][68];
    __shared__ float vs[17][68];
    __shared__ float sc[8][16][17];
    int b = blockIdx.x;
    int t = threadIdx.x;
    for (int e = t; e < 16 * 64; e += 256) {
        int f = e >> 6, c8 = e & 63;
        uint4 v = *(const uint4*)(q + (size_t)(b * 16 + f) * 512 + c8 * 8);
        float* dst = &qs[f][c8 * 8];
        dst[0] = b2f((ushort_t)(v.x & 0xffffu)); dst[1] = b2f((ushort_t)(v.x >> 16));
        dst[2] = b2f((ushort_t)(v.y & 0xffffu)); dst[3] = b2f((ushort_t)(v.y >> 16));
        dst[4] = b2f((ushort_t)(v.z & 0xffffu)); dst[5] = b2f((ushort_t)(v.z >> 16));
        dst[6] = b2f((ushort_t)(v.w & 0xffffu)); dst[7] = b2f((ushort_t)(v.w >> 16));
    }
    for (int e = t; e < 17 * 64; e += 256) {
        int j = e >> 6, d = e & 63;
        ks[j][d] = (j == 0) ? nullkv[d]      : b2f(kv[(size_t)(b * 16 + j - 1) * 128 + d]);
        vs[j][d] = (j == 0) ? nullkv[64 + d] : b2f(kv[(size_t)(b * 16 + j - 1) * 128 + 64 + d]);
    }
    __syncthreads();
    for (int e = t; e < 8 * 16 * 17; e += 256) {
        int h = e / 272, rem = e - h * 272;
        int i = rem / 17, j = rem - i * 17;
        float acc = 0.f;
        const float4* qp = (const float4*)&qs[i][h * 64];
        const float4* kp = (const float4*)&ks[j][0];
        #pragma unroll
        for (int d4 = 0; d4 < 16; ++d4) {
            float4 qv = qp[d4], kv4 = kp[d4];
            acc += qv.x * kv4.x;
            acc += qv.y * kv4.y;
            acc += qv.z * kv4.z;
            acc += qv.w * kv4.w;
        }
        float bias = ((j == 0) ? nullbias[h] : table[(i - (j - 1) + 15) * 8 + h]) * LOG2E;
        sc[h][i][j] = acc + bias;   // q pre-scaled by 0.125*log2e -> base-2 logits
    }
    __syncthreads();
    if (t < 128) {
        int h = t >> 4, i = t & 15;
        float mx = -1e30f;
        for (int j = 0; j < 17; ++j) mx = fmaxf(mx, sc[h][i][j]);
        float s = 0.f;
        for (int j = 0; j < 17; ++j) { float p = exp2_fast(sc[h][i][j] - mx); sc[h][i][j] = p; s += p; }
        float inv = 1.f / s;
        for (int j = 0; j < 17; ++j) sc[h][i][j] *= inv;
    }
    __syncthreads();
    for (int e = t; e < 16 * 128; e += 256) {
        int i = e >> 7, c4 = e & 127;
        int h = c4 >> 4, d4 = c4 & 15;
        float ax = 0.f, ay = 0.f, az = 0.f, aw = 0.f;
        #pragma unroll
        for (int j = 0; j < 17; ++j) {
            float p = sc[h][i][j];
            float4 vv = *(const float4*)&vs[j][d4 * 4];
            ax += p * vv.x; ay += p * vv.y; az += p * vv.z; aw += p * vv.w;
        }
        u32 lo = (u32)f2b(ax) | ((u32)f2b(ay) << 16);
        u32 hi = (u32)f2b(az) | ((u32)f2b(aw) << 16);
        *(uint2*)(out + (size_t)(b * 16 + i) * 512 + c4 * 4) = make_uint2(lo, hi);
    }
}

// ------------------------- FF shift-LN row stats from bf16 YS: (mean*rstd, rstd)
__global__ __launch_bounds__(256) void rowstats_bf16_kernel(
    const ushort_t* __restrict__ YS, float* __restrict__ stats)
{
    __shared__ float r1[4], r2[4];
    int r = blockIdx.x, t = threadIdx.x;
    const ushort_t* row = YS + (size_t)r * YSLD;
    float s = 0.f, s2 = 0.f;
    for (int c = t; c < FFI; c += 256) {
        float v = b2f(row[c]);
        s += v; s2 += v * v;
    }
    #pragma unroll
    for (int o = 32; o > 0; o >>= 1) { s += __shfl_down(s, o, 64); s2 += __shfl_down(s2, o, 64); }
    if ((t & 63) == 0) { r1[t >> 6] = s; r2[t >> 6] = s2; }
    __syncthreads();
    float S  = r1[0] + r1[1] + r1[2] + r1[3];
    float S2 = r2[0] + r2[1] + r2[2] + r2[3];
    float mean = S * (1.f / 1365.f);
    float var  = S2 * (1.f / 1365.f) - mean * mean;
    float rstd = rsqrtf(fmaxf(var, 1e-5f));
    if (t == 0) { stats[2 * r] = mean * rstd; stats[2 * r + 1] = rstd; }
}

// --------------------- colsum[n] = sum_k W'[n][k]  (rows of converted W')
__global__ __launch_bounds__(64) void colsum_kernel(
    const ushort_t* __restrict__ Wt, float* __restrict__ colsum)
{
    int n = blockIdx.x, t = threadIdx.x;
    const ushort_t* row = Wt + (size_t)n * YSLD;
    float s = 0.f;
    for (int k = t; k < YSLD; k += 64) s += b2f(row[k]);
    #pragma unroll
    for (int o = 32; o > 0; o >>= 1) s += __shfl_down(s, o, 64);
    if (t == 0) colsum[n] = s;
}

// ================================================================ launcher
extern "C" void kernel_launch(void* const* d_in, const int* in_sizes, int n_in,
                              void* d_out, int out_size, void* d_ws, size_t ws_size,
                              hipStream_t stream)
{
    const float* x          = (const float*)d_in[0];
    const float* sa_ln_w    = (const float*)d_in[1];
    const float* sa_ln_b    = (const float*)d_in[2];
    const float* sa_wq      = (const float*)d_in[3];
    const float* sa_wkv     = (const float*)d_in[4];
    const float* sa_null_kv = (const float*)d_in[5];
    const float* sa_null_b  = (const float*)d_in[6];
    const float* sa_wout    = (const float*)d_in[7];
    const float* sa_oln_w   = (const float*)d_in[8];
    const float* sa_oln_b   = (const float*)d_in[9];
    const float* ta_ln_w    = (const float*)d_in[10];
    const float* ta_ln_b    = (const float*)d_in[11];
    const float* ta_wq      = (const float*)d_in[12];
    const float* ta_wkv     = (const float*)d_in[13];
    const float* ta_null_kv = (const float*)d_in[14];
    const float* ta_null_b  = (const float*)d_in[15];
    const float* ta_wout    = (const float*)d_in[16];
    const float* ta_oln_w   = (const float*)d_in[17];
    const float* ta_oln_b   = (const float*)d_in[18];
    const float* sp_w0      = (const float*)d_in[19];
    const float* sp_b0      = (const float*)d_in[20];
    const float* sp_w1      = (const float*)d_in[21];
    const float* sp_b1      = (const float*)d_in[22];
    const float* sp_w2      = (const float*)d_in[23];
    const float* sp_b2      = (const float*)d_in[24];
    const float* tp_w0      = (const float*)d_in[25];
    const float* tp_b0      = (const float*)d_in[26];
    const float* tp_w1      = (const float*)d_in[27];
    const float* tp_b1      = (const float*)d_in[28];
    const float* tp_w2      = (const float*)d_in[29];
    const float* tp_b2      = (const float*)d_in[30];
    const float* ff_win     = (const float*)d_in[31];
    const float* ff_g       = (const float*)d_in[32];
    const float* ff_wout    = (const float*)d_in[33];

    char* ws = (char*)d_ws;
    // regions (bytes)
    float*    RES   = (float*)(ws + 0);                        // residual, spatial layout
    ushort_t* XN16  = (ushort_t*)(ws + 33554432);              // xn / x2 bf16
    ushort_t* Q16   = (ushort_t*)(ws + 50331648);              // spatial Q bf16 (spatial phase)
    float*    RT    = (float*)(ws + 50331648);                 // temporal residual f32 (temporal phase)
    ushort_t* YS    = (ushort_t*)(ws + 50331648);              // FF shifted act bf16 [16384][1376]
    ushort_t* WSA   = (ushort_t*)(ws + 67108864);              // spatial weights (dead by FF)
    ushort_t* KP    = (ushort_t*)(ws + 83886080);              // 16x1056x64 bf16 (spatial)
    ushort_t* VTb   = (ushort_t*)(ws + 86048768);              // 16x64x1056 bf16 (spatial)
    ushort_t* KV16  = (ushort_t*)(ws + 83886080);              // temporal KV bf16
    ushort_t* WTA   = (ushort_t*)(ws + 90439680);              // temporal weights
    ushort_t* AO16  = (ushort_t*)(ws + 92274688);              // attn out bf16 (dead by FF)
    ushort_t* BI    = (ushort_t*)(ws + 96468992);              // FF interleaved W [2816][512]
    ushort_t* WFFB  = (ushort_t*)(ws + 99352576);              // W' = (ff_wout*g)^T [512][1376]
    ushort_t* BIAS16= (ushort_t*)(ws + 109051904);             // spatial bias bf16 (PRJ region)
    float*    PRJ   = (float*)(ws + 109051904);                // proj out f32
    ushort_t* Q16t  = (ushort_t*)(ws + 109051904);             // temporal Q bf16
    float*    STATS = (float*)(ws + 142606336);                // 16384 x (mean*rstd, rstd)
    float*    SPT   = (float*)(ws + 142737408);                // spatial CPB table (spatial phase)
    float*    COLSUM= (float*)(ws + 142737408);                // colsum[512] (FF phase, dead SPT)
    float*    TPT   = (float*)(ws + 142864448);

    ushort_t* WQ_T  = WSA;                 // [512][512]  (WKV_T contiguous after -> merged B [640][512])
    ushort_t* WKV_T = WSA + 262144;        // [128][512]
    ushort_t* WO_T  = WSA + 327680;        // [512][512]
    ushort_t* tWQ_T  = WTA;
    ushort_t* tWKV_T = WTA + 262144;
    ushort_t* tWO_T  = WTA + 327680;

    dim3 blk(256);
    const float QSCL = 0.125f * LOG2E;   // fold log2e into Q so softmax is exp2

    // bias tables
    cpb_kernel<<<dim3(249), blk, 0, stream>>>(sp_w0, sp_b0, sp_w1, sp_b1, sp_w2, sp_b2, SPT, 0, 3969);
    cpb_kernel<<<dim3(2),   blk, 0, stream>>>(tp_w0, tp_b0, tp_w1, tp_b1, tp_w2, tp_b2, TPT, 1, 31);
    bias_sp_kernel<<<dim3(1024, 8), blk, 0, stream>>>(SPT, sa_null_b, BIAS16);
    kvinit_kernel<<<dim3(16), blk, 0, stream>>>(sa_null_kv, KP, VTb);

    // ---------------- spatial ----------------
    wcvt_kernel<<<dim3(16, 16), blk, 0, stream>>>(sa_wq, 512, 0, WQ_T, 512, 512, 512, nullptr, 512);
    wcvt_kernel<<<dim3(4, 16),  blk, 0, stream>>>(sa_wkv, 128, 0, WKV_T, 512, 512, 128, nullptr, 128);
    wcvt_kernel<<<dim3(16, 16), blk, 0, stream>>>(sa_wout, 512, 0, WO_T, 512, 512, 512, nullptr, 512);
    transpose_in_kernel<<<dim3(512, 16), blk, 0, stream>>>(x, RES);
    ln_bf16_kernel<<<dim3(TOK), blk, 0, stream>>>(RES, XN16, sa_ln_w, sa_ln_b);
    // merged Q + KV projection (N=640: B = [WQ_T; WKV_T] contiguous)
    gemm_mfma<6><<<dim3(640), blk, 0, stream>>>(XN16, 512, WQ_T, 512,
        nullptr, Q16, 512, TOK, 640, 512, QSCL, 5, nullptr, nullptr, nullptr, nullptr, KP, VTb);
    attn_sp_mfma<<<dim3(1024), blk, 0, stream>>>(Q16, KP, VTb, BIAS16, AO16);
    gemm_mfma<0><<<dim3(512), blk, 0, stream>>>(AO16, 512, WO_T, 512,
        PRJ, nullptr, 512, TOK, 512, 512, 1.0f, 4, nullptr, nullptr, nullptr, nullptr, nullptr, nullptr);
    // fused LN+residual + spatial->temporal permute + temporal input-LN
    ln_add_sp_kernel<<<dim3(TOK), blk, 0, stream>>>(PRJ, RES, RT, XN16, sa_oln_w, sa_oln_b, ta_ln_w, ta_ln_b);

    // ---------------- temporal ----------------
    wcvt_kernel<<<dim3(16, 16), blk, 0, stream>>>(ta_wq, 512, 0, tWQ_T, 512, 512, 512, nullptr, 512);
    wcvt_kernel<<<dim3(4, 16),  blk, 0, stream>>>(ta_wkv, 128, 0, tWKV_T, 512, 512, 128, nullptr, 128);
    wcvt_kernel<<<dim3(16, 16), blk, 0, stream>>>(ta_wout, 512, 0, tWO_T, 512, 512, 512, nullptr, 512);
    // merged Q + KV projection (temporal)
    gemm_mfma<7><<<dim3(640), blk, 0, stream>>>(XN16, 512, tWQ_T, 512,
        nullptr, Q16t, 512, TOK, 640, 512, QSCL, 5, nullptr, nullptr, nullptr, nullptr, KV16, nullptr);
    attn_tp_kernel<<<dim3(1024), blk, 0, stream>>>(Q16t, KV16, ta_null_kv, ta_null_b, TPT, AO16);
    gemm_mfma<0><<<dim3(512), blk, 0, stream>>>(AO16, 512, tWO_T, 512,
        PRJ, nullptr, 512, TOK, 512, 512, 1.0f, 4, nullptr, nullptr, nullptr, nullptr, nullptr, nullptr);
    // fused LN+residual + temporal->spatial permute (writes RES f32 + XN16 bf16)
    ln_add_tp_kernel<<<dim3(TOK), blk, 0, stream>>>(PRJ, RT, RES, XN16, ta_oln_w, ta_oln_b);

    // ---------------- feed-forward ----------------
    wcvt_kernel<<<dim3(44, 16), blk, 0, stream>>>(ff_win, 2730, 0,   BI,       1024, 512, FFI, nullptr, 1408);
    wcvt_kernel<<<dim3(44, 16), blk, 0, stream>>>(ff_win, 2730, FFI, BI + 512, 1024, 512, FFI, nullptr, 1408);
    wcvt_kernel<<<dim3(16, 43), blk, 0, stream>>>(ff_wout, 512, 0, WFFB, YSLD, FFI, 512, ff_g, 512);
    colsum_kernel<<<dim3(512), dim3(64), 0, stream>>>(WFFB, COLSUM);
    ff_gemm_fused<<<dim3(2816), blk, 0, stream>>>(XN16, BI, YS);
    rowstats_bf16_kernel<<<dim3(TOK), blk, 0, stream>>>(YS, STATS);
    gemm_mfma<5><<<dim3(512), blk, 0, stream>>>(YS, YSLD, WFFB, YSLD,
        nullptr, nullptr, 0, TOK, 512, YSLD, 1.0f, 4, STATS, COLSUM, RES, (float*)d_out, nullptr, nullptr);
}